// Round 12
// baseline (8723.925 us; speedup 1.0000x reference)
//
#include <hip/hip_runtime.h>
#include <cstddef>
#include <cstdint>

#define NBATCH 8
#define NPTS   2048
#define KNN    20

typedef __attribute__((ext_vector_type(8))) short short8;
typedef __attribute__((ext_vector_type(4))) float f32x4;

__device__ __forceinline__ unsigned short f2bf(float f) {
  unsigned u = __float_as_uint(f);
  u += 0x7fff + ((u >> 16) & 1);   // round-to-nearest-even
  return (unsigned short)(u >> 16);
}
__device__ __forceinline__ float bf2f(unsigned short h) {
  return __uint_as_float(((unsigned)h) << 16);
}

// ---------------------------------------------------------------------------
// wave-level exact top-20 over 2048 candidates: lane holds 32 values,
// global index of v[slot] on lane l is slot*64 + l. One wave per row.
// Tie-break: lowest index (ascending slot strict >, explicit idx compares).
// ---------------------------------------------------------------------------
__device__ __forceinline__ void wave_top20(float (&v)[32], int lane,
                                           int* __restrict__ row_out) {
  float bv = v[0];
  int bl = 0;
#pragma unroll
  for (int i = 1; i < 32; i++)
    if (v[i] > bv) { bv = v[i]; bl = i; }

  int keep = 0;
  for (int k = 0; k < KNN; k++) {
    float rv = bv;
    int ri = bl * 64 + lane;
#pragma unroll
    for (int off = 32; off > 0; off >>= 1) {
      float ov = __shfl_down(rv, off);
      int oi = __shfl_down(ri, off);
      if (ov > rv || (ov == rv && oi < ri)) { rv = ov; ri = oi; }
    }
    int wi = __shfl(ri, 0);
    if (lane == k) keep = wi;
    if ((wi & 63) == lane) {
      int slot = wi >> 6;
#pragma unroll
      for (int i = 0; i < 32; i++)
        if (i == slot) v[i] = -3.0e38f;
      bv = v[0]; bl = 0;
#pragma unroll
      for (int i = 1; i < 32; i++)
        if (v[i] > bv) { bv = v[i]; bl = i; }
    }
  }
  if (lane < KNN) row_out[lane] = keep;
}

// ---------------------------------------------------------------------------
// transpose (B,3,N) -> (B,N,3)
// ---------------------------------------------------------------------------
__global__ void k_transpose(const float* __restrict__ x, float* __restrict__ h0) {
  int i = blockIdx.x * 256 + threadIdx.x;
  if (i >= NBATCH * NPTS * 3) return;
  int c = i % 3;
  int n = (i / 3) % NPTS;
  int b = i / (3 * NPTS);
  h0[i] = x[((size_t)b * 3 + c) * NPTS + n];
}

// ---------------------------------------------------------------------------
// pairwise "distance" pd = 2*dot - sq_n - sq_m. blockIdx.z = batch in group.
// 128x128 tile per block, 8x8 microtile (16x16 thread grid), K-chunked TK=32.
// LDS layout off(c4,m) = c4*580 + m*4 + (m>>3)*4 words: 580 = 4 (mod 32) and
// the every-8-rows pad keeps staging writes / ra (4 broadcast addrs) / cb
// (2-way) at the LDS bank minimum; all float4 accesses 16B-aligned.
// Accumulation order (c ascending, x/y/z/w) and sq order are BIT-IDENTICAL
// to the previous kernel -> zero kNN-selection risk.
// ---------------------------------------------------------------------------
template <int C>
__global__ __launch_bounds__(256, 4) void k_dist(const float* __restrict__ xg,
                                                 float* __restrict__ dist) {
  constexpr int TK = 32;
  constexpr int NC4 = TK / 4;   // 8
  constexpr int CST = 580;      // words per c4 slice
  __shared__ __attribute__((aligned(16))) float rs[NC4 * CST];
  __shared__ __attribute__((aligned(16))) float cs[NC4 * CST];
  __shared__ float sqr[128];
  __shared__ float sqc[128];

  const float* xb = xg + (size_t)blockIdx.z * NPTS * C;
  float* db = dist + (size_t)blockIdx.z * NPTS * NPTS;
  const int rt = blockIdx.y, ct = blockIdx.x;
  const int tid = threadIdx.x;
  const int tx = tid & 15, ty = tid >> 4;

  float acc[8][8] = {};
  float sreg = 0.f;   // tid<128: sq of row tid; else sq of col tid-128

  for (int kt = 0; kt < C; kt += TK) {
    if (kt) __syncthreads();   // all reads of previous chunk done
    // stage: c4-fast lane mapping (coalesced global), 4 passes of 32 rows
#pragma unroll
    for (int p = 0; p < 4; p++) {
      int c4 = tid & 7;
      int m = (tid >> 3) + p * 32;
      int o = c4 * CST + m * 4 + (m >> 3) * 4;
      *(float4*)&rs[o] = *(const float4*)&xb[(size_t)(rt * 128 + m) * C + kt + c4 * 4];
      *(float4*)&cs[o] = *(const float4*)&xb[(size_t)(ct * 128 + m) * C + kt + c4 * 4];
    }
    __syncthreads();

    // sq partial (ascending c within chunk -- same order as a straight c-loop)
    {
      int m = tid & 127;
      const float* base = (tid < 128) ? rs : cs;
#pragma unroll
      for (int c4 = 0; c4 < NC4; c4++) {
        float4 v = *(const float4*)&base[c4 * CST + m * 4 + (m >> 3) * 4];
        sreg += v.x * v.x; sreg += v.y * v.y; sreg += v.z * v.z; sreg += v.w * v.w;
      }
    }

    // 8x8 microtile MACs
#pragma unroll
    for (int c4 = 0; c4 < NC4; c4++) {
      float4 ra[8];
#pragma unroll
      for (int i = 0; i < 8; i++) {
        int m = ty * 8 + i;
        ra[i] = *(const float4*)&rs[c4 * CST + m * 4 + ty * 4];
      }
#pragma unroll
      for (int j = 0; j < 8; j++) {
        int n = tx + 16 * j;
        float4 cb = *(const float4*)&cs[c4 * CST + n * 4 + (n >> 3) * 4];
#pragma unroll
        for (int i = 0; i < 8; i++)
          acc[i][j] += ra[i].x * cb.x + ra[i].y * cb.y +
                       ra[i].z * cb.z + ra[i].w * cb.w;
      }
    }
  }

  __syncthreads();
  if (tid < 128) sqr[tid] = sreg;
  else           sqc[tid - 128] = sreg;
  __syncthreads();

#pragma unroll
  for (int i = 0; i < 8; i++) {
    float sr = sqr[ty * 8 + i];
#pragma unroll
    for (int j = 0; j < 8; j++) {
      int n = tx + 16 * j;
      db[(size_t)(rt * 128 + ty * 8 + i) * NPTS + ct * 128 + n] =
          2.f * acc[i][j] - sr - sqc[n];
    }
  }
}

// ---------------------------------------------------------------------------
// top-20 per row from materialized dist. One wave per row, 4 rows per block.
// ---------------------------------------------------------------------------
__global__ __launch_bounds__(256) void k_topk(const float* __restrict__ dist,
                                              int* __restrict__ idx_out) {
  const int wid = threadIdx.x >> 6;
  const int lane = threadIdx.x & 63;
  const int n = blockIdx.x * 4 + wid;
  const int z = blockIdx.y;
  const float* drow = dist + ((size_t)z * NPTS + n) * NPTS;
  int* row_out = idx_out + ((size_t)z * NPTS + n) * KNN;

  float v[32];
#pragma unroll
  for (int i = 0; i < 32; i++) v[i] = drow[i * 64 + lane];

  wave_top20(v, lane, row_out);
}

// ---------------------------------------------------------------------------
// conv1 fused kNN (C=3): one wave per row, register recompute + wave_top20.
// ---------------------------------------------------------------------------
__global__ __launch_bounds__(256) void k_knn3(const float* __restrict__ x,
                                              int* __restrict__ idx_out) {
  const int wid = threadIdx.x >> 6;
  const int lane = threadIdx.x & 63;
  const int n = blockIdx.x * 4 + wid;
  const int b = blockIdx.y;
  const float* xb = x + (size_t)b * NPTS * 3;
  int* row_out = idx_out + ((size_t)b * NPTS + n) * KNN;

  const float qx = xb[n * 3 + 0], qy = xb[n * 3 + 1], qz = xb[n * 3 + 2];
  float qsq = 0.f;
  qsq += qx * qx; qsq += qy * qy; qsq += qz * qz;

  float v[32];
#pragma unroll
  for (int i = 0; i < 32; i++) {
    int m = i * 64 + lane;
    float cx = xb[m * 3 + 0], cy = xb[m * 3 + 1], cz = xb[m * 3 + 2];
    float csq = 0.f;
    csq += cx * cx; csq += cy * cy; csq += cz * cz;
    float acc = 0.f;
    acc += qx * cx; acc += qy * cy; acc += qz * cz;
    v[i] = 2.f * acc - qsq - csq;
  }

  wave_top20(v, lane, row_out);
}

// ---------------------------------------------------------------------------
// t0 GEMM: t0buf[n, o] = sum_c x[n, c] * w[C+c, o]   (center @ w_hi)
// ---------------------------------------------------------------------------
template <int C, int O>
__global__ __launch_bounds__(256) void k_t0(const float* __restrict__ x,
                                            const float* __restrict__ w,
                                            float* __restrict__ t0buf) {
  constexpr int TM = 128, TN = 64, TK = 16;
  __shared__ __attribute__((aligned(16))) float As[TK][TM + 4];
  __shared__ __attribute__((aligned(16))) float Bs[TK][TN + 4];
  const int mt = blockIdx.x, nt = blockIdx.y;
  const int tid = threadIdx.x;
  const int tx = tid & 15, ty = tid >> 4;
  const size_t m0 = (size_t)mt * TM;
  const int n0 = nt * TN;
  float acc[8][4] = {};

  for (int kt = 0; kt < C; kt += TK) {
#pragma unroll
    for (int e = 0; e < 8; e++) {
      int idx = tid + e * 256;
      int m = idx >> 4, k = idx & 15;
      As[k][m] = x[(m0 + m) * C + kt + k];
    }
#pragma unroll
    for (int e = 0; e < 4; e++) {
      int idx = tid + e * 256;
      int k = idx >> 6, nn = idx & 63;
      Bs[k][nn] = w[(size_t)(C + kt + k) * O + n0 + nn];
    }
    __syncthreads();
#pragma unroll
    for (int kk = 0; kk < TK; kk++) {
      float4 a0 = *(const float4*)&As[kk][ty * 8];
      float4 a1 = *(const float4*)&As[kk][ty * 8 + 4];
      float4 b0 = *(const float4*)&Bs[kk][tx * 4];
      float av[8] = {a0.x, a0.y, a0.z, a0.w, a1.x, a1.y, a1.z, a1.w};
      float bb[4] = {b0.x, b0.y, b0.z, b0.w};
#pragma unroll
      for (int i = 0; i < 8; i++)
#pragma unroll
        for (int j = 0; j < 4; j++) acc[i][j] += av[i] * bb[j];
    }
    __syncthreads();
  }
#pragma unroll
  for (int i = 0; i < 8; i++)
#pragma unroll
    for (int j = 0; j < 4; j++)
      t0buf[(m0 + ty * 8 + i) * O + n0 + tx * 4 + j] = acc[i][j];
}

// ---------------------------------------------------------------------------
// weight -> bf16 hi/lo split in 16x16x32 B-fragment order.
// ---------------------------------------------------------------------------
template <int C, int O>
__global__ void k_wprep(const float* __restrict__ w,
                        unsigned short* __restrict__ whi,
                        unsigned short* __restrict__ wlo) {
  int e = blockIdx.x * 256 + threadIdx.x;
  if (e >= C * O) return;
  constexpr int NT = O / 16;
  int j = e & 7;
  int slot = e >> 3;
  int lane = slot & 63;
  int t2 = slot >> 6;
  int nt = t2 % NT, kb = t2 / NT;
  int k = kb * 32 + ((lane >> 4) & 3) * 8 + j;
  int n = nt * 16 + (lane & 15);
  float v = w[(size_t)k * O + n];
  unsigned short h = f2bf(v);
  unsigned short l = f2bf(v - bf2f(h));
  whi[e] = h;
  wlo[e] = l;
}

// ---------------------------------------------------------------------------
// feature matrix -> bf16 hi/lo split in 16x16x32 A-fragment order for mlp5.
// ---------------------------------------------------------------------------
__global__ void k_aprep(const float* __restrict__ x1, const float* __restrict__ x2,
                        const float* __restrict__ x3, const float* __restrict__ x4,
                        unsigned short* __restrict__ ah, unsigned short* __restrict__ al) {
  int e8 = blockIdx.x * 256 + threadIdx.x;   // 16 kb * 1024 mtg * 64 lanes
  if (e8 >= 16 * 1024 * 64) return;
  int lane = e8 & 63;
  int mtg = (e8 >> 6) & 1023;
  int kb = e8 >> 16;
  int m = mtg * 16 + (lane & 15);
  int k0 = kb * 32 + ((lane >> 4) & 3) * 8;
  const float* p;
  if (k0 < 64)       p = &x1[(size_t)m * 64 + k0];
  else if (k0 < 128) p = &x2[(size_t)m * 64 + (k0 - 64)];
  else if (k0 < 256) p = &x3[(size_t)m * 128 + (k0 - 128)];
  else               p = &x4[(size_t)m * 256 + (k0 - 256)];
  float4 f0 = *(const float4*)p;
  float4 f1 = *(const float4*)(p + 4);
  float fv[8] = {f0.x, f0.y, f0.z, f0.w, f1.x, f1.y, f1.z, f1.w};
  short8 h8, l8;
#pragma unroll
  for (int j = 0; j < 8; j++) {
    unsigned short h = f2bf(fv[j]);
    unsigned short l = f2bf(fv[j] - bf2f(h));
    h8[j] = (short)h;
    l8[j] = (short)l;
  }
  *(short8*)&ah[(size_t)e8 * 8] = h8;
  *(short8*)&al[(size_t)e8 * 8] = l8;
}

// ---------------------------------------------------------------------------
// MFMA edge conv (C in {64,128}): per block 2 points, 32 padded neighbor rows.
// Split bf16: D ~= AhBh + AhBl + AlBh.
// ---------------------------------------------------------------------------
template <int C, int O>
__global__ __launch_bounds__(256) void k_edge_mfma(
    const float* __restrict__ x, const int* __restrict__ knn,
    const unsigned short* __restrict__ whi, const unsigned short* __restrict__ wlo,
    const float* __restrict__ t0buf, const float* __restrict__ g,
    const float* __restrict__ bta, float* __restrict__ out) {
  constexpr int KB = C / 32;
  constexpr int NT = O / 16;
  constexpr int NTW = NT / 2;
  __shared__ unsigned short Ah[2 * 2 * KB * 512];
  __shared__ unsigned short Al[2 * 2 * KB * 512];

  const int blk = blockIdx.x;
  const int b = blk / (NPTS / 2);
  const int n0 = (blk % (NPTS / 2)) * 2;
  const int tid = threadIdx.x;
  const int lane = tid & 63;
  const int wid = tid >> 6;
  const int pt = wid >> 1;
  const int nsl = wid & 1;
  const int ptg = b * NPTS + n0 + pt;
  const float* xb = x + (size_t)b * NPTS * C;
  const int kbase = ptg * KNN;

  if constexpr (C == 128) {
    const float2 ctr2 = *(const float2*)&xb[(size_t)(n0 + pt) * C + lane * 2];
    const int kb = lane >> 4;
    const int q = (lane >> 2) & 3;
    const int j2 = 2 * (lane & 3);
#pragma unroll
    for (int i = 0; i < 16; i++) {
      int r = 2 * i + nsl;
      unsigned hp = 0, lp = 0;
      if (r < KNN) {
        int m = knn[kbase + r];
        float2 v = *(const float2*)&xb[(size_t)m * C + lane * 2];
        float d0 = v.x - ctr2.x, d1 = v.y - ctr2.y;
        unsigned short h0 = f2bf(d0), h1 = f2bf(d1);
        unsigned short l0 = f2bf(d0 - bf2f(h0)), l1 = f2bf(d1 - bf2f(h1));
        hp = (unsigned)h0 | ((unsigned)h1 << 16);
        lp = (unsigned)l0 | ((unsigned)l1 << 16);
      }
      int mt = r >> 4, row = r & 15;
      int L = row + 16 * q;
      int phys = L ^ ((4 * kb + q) & 15);
      int idx = ((pt * 2 + mt) * KB + kb) * 512 + phys * 8 + j2;
      *(unsigned*)&Ah[idx] = hp;
      *(unsigned*)&Al[idx] = lp;
    }
  } else {
    const float ctrv = xb[(size_t)(n0 + pt) * C + lane];
    const int kb = lane >> 5;
    const int q = (lane >> 3) & 3;
    const int j = lane & 7;
#pragma unroll
    for (int i = 0; i < 16; i++) {
      int r = 2 * i + nsl;
      unsigned short h = 0, l = 0;
      if (r < KNN) {
        int m = knn[kbase + r];
        float d = xb[(size_t)m * C + lane] - ctrv;
        h = f2bf(d);
        l = f2bf(d - bf2f(h));
      }
      int mt = r >> 4, row = r & 15;
      int L = row + 16 * q;
      int phys = L ^ ((4 * kb + q) & 15);
      int idx = ((pt * 2 + mt) * KB + kb) * 512 + phys * 8 + j;
      Ah[idx] = h;
      Al[idx] = l;
    }
  }
  __syncthreads();

  f32x4 acc[2][NTW];
#pragma unroll
  for (int mt = 0; mt < 2; mt++)
#pragma unroll
    for (int t = 0; t < NTW; t++) acc[mt][t] = (f32x4){0.f, 0.f, 0.f, 0.f};

#pragma unroll
  for (int kb = 0; kb < KB; kb++) {
    int phys = lane ^ ((4 * kb + (lane >> 4)) & 15);
    short8 ah[2], al[2];
#pragma unroll
    for (int mt = 0; mt < 2; mt++) {
      int idx = ((pt * 2 + mt) * KB + kb) * 512 + phys * 8;
      ah[mt] = *(const short8*)&Ah[idx];
      al[mt] = *(const short8*)&Al[idx];
    }
#pragma unroll
    for (int t = 0; t < NTW; t++) {
      int nt = nsl * NTW + t;
      size_t widx = ((size_t)(kb * NT + nt) * 64 + lane) * 8;
      short8 bh = *(const short8*)&whi[widx];
      short8 bl = *(const short8*)&wlo[widx];
#pragma unroll
      for (int mt = 0; mt < 2; mt++) {
        acc[mt][t] = __builtin_amdgcn_mfma_f32_16x16x32_bf16(ah[mt], bh, acc[mt][t], 0, 0, 0);
        acc[mt][t] = __builtin_amdgcn_mfma_f32_16x16x32_bf16(ah[mt], bl, acc[mt][t], 0, 0, 0);
        acc[mt][t] = __builtin_amdgcn_mfma_f32_16x16x32_bf16(al[mt], bh, acc[mt][t], 0, 0, 0);
      }
    }
  }

#pragma unroll
  for (int t = 0; t < NTW; t++) {
    int o = (nsl * NTW + t) * 16 + (lane & 15);
    float tv = t0buf[(size_t)ptg * O + o];
    float gv = g[o], bv = bta[o];
    float m = -3.0e38f;
#pragma unroll
    for (int mt = 0; mt < 2; mt++)
#pragma unroll
      for (int r = 0; r < 4; r++) {
        float h = (acc[mt][t][r] + tv) * gv + bv;
        h = (h >= 0.f) ? h : 0.2f * h;
        m = fmaxf(m, h);
      }
    m = fmaxf(m, __shfl_xor(m, 16));
    m = fmaxf(m, __shfl_xor(m, 32));
    if (lane < 16) out[(size_t)ptg * O + o] = m;
  }
}

// ---------------------------------------------------------------------------
// fp32 edge conv -- retained for conv1 (C=3) only.
// ---------------------------------------------------------------------------
template <int C, int O>
__global__ __launch_bounds__(256) void k_edge(const float* __restrict__ x,
                                              const int* __restrict__ knn,
                                              const float* __restrict__ w,
                                              const float* __restrict__ g,
                                              const float* __restrict__ bta,
                                              float* __restrict__ out) {
  constexpr int JO = O / 64;
  constexpr int NPB = 4;
  __shared__ __attribute__((aligned(16))) float nbd[NPB * KNN * C];

  const int blk = blockIdx.x;
  const int b = blk / (NPTS / NPB);
  const int n0 = (blk % (NPTS / NPB)) * NPB;
  const int tid = threadIdx.x;
  const int lane = tid & 63;
  const int p = tid >> 6;
  const float* xb = x + (size_t)b * NPTS * C;

  const int kbase = (b * NPTS + n0 + p) * KNN;
  float* nb_p = nbd + p * KNN * C;
  int midx[KNN];
#pragma unroll
  for (int k = 0; k < KNN; k++) midx[k] = knn[kbase + k];

  float cv0 = 0.f;
  if (lane < C) cv0 = xb[(size_t)(n0 + p) * C + lane];
  float vv[KNN];
#pragma unroll
  for (int k = 0; k < KNN; k++)
    vv[k] = (lane < C) ? xb[(size_t)midx[k] * C + lane] : 0.f;
#pragma unroll
  for (int k = 0; k < KNN; k++)
    if (lane < C) nb_p[k * C + lane] = vv[k] - cv0;

  float acc[KNN][JO];
  {
    float t0[JO];
#pragma unroll
    for (int j = 0; j < JO; j++) t0[j] = 0.f;
    for (int c = 0; c < C; c++) {
      float cc = __shfl(cv0, c);
#pragma unroll
      for (int j = 0; j < JO; j++)
        t0[j] += cc * w[(size_t)(C + c) * O + j * 64 + lane];
    }
#pragma unroll
    for (int k = 0; k < KNN; k++)
#pragma unroll
      for (int j = 0; j < JO; j++) acc[k][j] = t0[j];
  }

  for (int c = 0; c < C; c++) {
    float wv[JO];
#pragma unroll
    for (int j = 0; j < JO; j++) wv[j] = w[(size_t)c * O + j * 64 + lane];
#pragma unroll
    for (int k = 0; k < KNN; k++) {
      float f = nb_p[k * C + c];
#pragma unroll
      for (int j = 0; j < JO; j++) acc[k][j] += f * wv[j];
    }
  }

#pragma unroll
  for (int j = 0; j < JO; j++) {
    const float gv = g[j * 64 + lane], bv = bta[j * 64 + lane];
    float mx = -3.0e38f;
#pragma unroll
    for (int k = 0; k < KNN; k++) {
      float h = acc[k][j] * gv + bv;
      h = (h >= 0.f) ? h : 0.2f * h;
      mx = fmaxf(mx, h);
    }
    out[(size_t)(b * NPTS + n0 + p) * O + j * 64 + lane] = mx;
  }
}

// ---------------------------------------------------------------------------
// point MLP 512->1024 as split-bf16 MFMA GEMM, no LDS, no barriers.
// ---------------------------------------------------------------------------
__global__ __launch_bounds__(256) void k_mlp5(const unsigned short* __restrict__ a5h,
                                              const unsigned short* __restrict__ a5l,
                                              const unsigned short* __restrict__ w5h,
                                              const unsigned short* __restrict__ w5l,
                                              const float* __restrict__ g5,
                                              const float* __restrict__ b5,
                                              float* __restrict__ pmax,
                                              float* __restrict__ psum) {
  const int mtb = blockIdx.x;   // 0..127
  const int ntb = blockIdx.y;   // 0..7
  const int tid = threadIdx.x;
  const int lane = tid & 63;
  const int nsl = tid >> 6;     // wave id 0..3

  f32x4 acc[8][2];
#pragma unroll
  for (int mt = 0; mt < 8; mt++)
#pragma unroll
    for (int t = 0; t < 2; t++) acc[mt][t] = (f32x4){0.f, 0.f, 0.f, 0.f};

  for (int kb = 0; kb < 16; kb++) {
    short8 bh[2], bl[2];
#pragma unroll
    for (int t = 0; t < 2; t++) {
      int ntg = ntb * 8 + nsl * 2 + t;
      size_t widx = ((size_t)(kb * 64 + ntg) * 64 + lane) * 8;
      bh[t] = *(const short8*)&w5h[widx];
      bl[t] = *(const short8*)&w5l[widx];
    }
#pragma unroll
    for (int mt = 0; mt < 8; mt++) {
      size_t aidx = (((size_t)kb * 1024 + mtb * 8 + mt) * 64 + lane) * 8;
      short8 ah = *(const short8*)&a5h[aidx];
      short8 al = *(const short8*)&a5l[aidx];
#pragma unroll
      for (int t = 0; t < 2; t++) {
        acc[mt][t] = __builtin_amdgcn_mfma_f32_16x16x32_bf16(ah, bh[t], acc[mt][t], 0, 0, 0);
        acc[mt][t] = __builtin_amdgcn_mfma_f32_16x16x32_bf16(ah, bl[t], acc[mt][t], 0, 0, 0);
        acc[mt][t] = __builtin_amdgcn_mfma_f32_16x16x32_bf16(al, bh[t], acc[mt][t], 0, 0, 0);
      }
    }
  }

#pragma unroll
  for (int t = 0; t < 2; t++) {
    int o = ntb * 128 + (nsl * 2 + t) * 16 + (lane & 15);
    float gv = g5[o], bv = b5[o];
    float mx = -3.0e38f, sm = 0.f;
#pragma unroll
    for (int mt = 0; mt < 8; mt++)
#pragma unroll
      for (int r = 0; r < 4; r++) {
        float h = acc[mt][t][r] * gv + bv;
        h = (h >= 0.f) ? h : 0.2f * h;
        mx = fmaxf(mx, h);
        sm += h;
      }
    mx = fmaxf(mx, __shfl_xor(mx, 16));
    mx = fmaxf(mx, __shfl_xor(mx, 32));
    sm += __shfl_xor(sm, 16);
    sm += __shfl_xor(sm, 32);
    if (lane < 16) {
      pmax[(size_t)mtb * 1024 + o] = mx;
      psum[(size_t)mtb * 1024 + o] = sm;
    }
  }
}

// ---------------------------------------------------------------------------
// reduce tile partials -> pooled (B, 2048) = [max(1024), mean(1024)]
// ---------------------------------------------------------------------------
__global__ void k_pool(const float* __restrict__ pmax, const float* __restrict__ psum,
                       float* __restrict__ pooled) {
  int i = blockIdx.x * 256 + threadIdx.x;
  if (i >= NBATCH * 1024) return;
  int b = i / 1024, e = i - b * 1024;
  constexpr int NT = NPTS / 128;
  float mx = -3.0e38f, sm = 0.f;
  for (int t = 0; t < NT; t++) {
    mx = fmaxf(mx, pmax[((size_t)b * NT + t) * 1024 + e]);
    sm += psum[((size_t)b * NT + t) * 1024 + e];
  }
  pooled[(size_t)b * 2048 + e] = mx;
  pooled[(size_t)b * 2048 + 1024 + e] = sm * (1.0f / NPTS);
}

// ---------------------------------------------------------------------------
// FC head: 2048->512 (leaky, affine) -> 256 (bias, leaky, affine) -> 40 (+bias)
// ---------------------------------------------------------------------------
__global__ __launch_bounds__(256) void k_head(const float* __restrict__ pooled,
                                              const float* __restrict__ wl1,
                                              const float* __restrict__ g6,
                                              const float* __restrict__ b6,
                                              const float* __restrict__ wl2,
                                              const float* __restrict__ bl2,
                                              const float* __restrict__ g7,
                                              const float* __restrict__ b7,
                                              const float* __restrict__ wl3,
                                              const float* __restrict__ bl3,
                                              float* __restrict__ out) {
  const int b = blockIdx.x;
  const int tid = threadIdx.x;
  __shared__ float pl[2048];
  __shared__ float h1[512];
  __shared__ float h2[256];

  for (int i = tid; i < 2048; i += 256) pl[i] = pooled[(size_t)b * 2048 + i];
  __syncthreads();

  for (int o = tid; o < 512; o += 256) {
    float a = 0.f;
    for (int c = 0; c < 2048; c++) a += pl[c] * wl1[(size_t)c * 512 + o];
    a = a * g6[o] + b6[o];
    h1[o] = (a >= 0.f) ? a : 0.2f * a;
  }
  __syncthreads();

  {
    float a = 0.f;
    for (int c = 0; c < 512; c++) a += h1[c] * wl2[(size_t)c * 256 + tid];
    a = (a + bl2[tid]) * g7[tid] + b7[tid];
    h2[tid] = (a >= 0.f) ? a : 0.2f * a;
  }
  __syncthreads();

  if (tid < 40) {
    float a = bl3[tid];
    for (int c = 0; c < 256; c++) a += h2[c] * wl3[(size_t)c * 40 + tid];
    out[(size_t)b * 40 + tid] = a;
  }
}

// ---------------------------------------------------------------------------
extern "C" void kernel_launch(void* const* d_in, const int* in_sizes, int n_in,
                              void* d_out, int out_size, void* d_ws, size_t ws_size,
                              hipStream_t stream) {
  (void)in_sizes; (void)n_in; (void)out_size;
  const float* x   = (const float*)d_in[0];
  const float* w1  = (const float*)d_in[1];
  const float* g1  = (const float*)d_in[2];
  const float* b1  = (const float*)d_in[3];
  const float* w2  = (const float*)d_in[4];
  const float* g2  = (const float*)d_in[5];
  const float* b2  = (const float*)d_in[6];
  const float* w3  = (const float*)d_in[7];
  const float* g3  = (const float*)d_in[8];
  const float* b3  = (const float*)d_in[9];
  const float* w4  = (const float*)d_in[10];
  const float* g4  = (const float*)d_in[11];
  const float* b4  = (const float*)d_in[12];
  const float* w5  = (const float*)d_in[13];
  const float* g5  = (const float*)d_in[14];
  const float* b5  = (const float*)d_in[15];
  const float* wl1 = (const float*)d_in[16];
  const float* g6  = (const float*)d_in[17];
  const float* b6  = (const float*)d_in[18];
  const float* wl2 = (const float*)d_in[19];
  const float* bl2 = (const float*)d_in[20];
  const float* g7  = (const float*)d_in[21];
  const float* b7  = (const float*)d_in[22];
  const float* wl3 = (const float*)d_in[23];
  const float* bl3 = (const float*)d_in[24];

  float* ws = (float*)d_ws;
  size_t off = 0;
  float* h0 = ws + off;   off += (size_t)NBATCH * NPTS * 3;
  float* x1 = ws + off;   off += (size_t)NBATCH * NPTS * 64;
  float* x2 = ws + off;   off += (size_t)NBATCH * NPTS * 64;
  float* x3 = ws + off;   off += (size_t)NBATCH * NPTS * 128;
  float* x4 = ws + off;   off += (size_t)NBATCH * NPTS * 256;
  int* knn = (int*)(ws + off); off += (size_t)NBATCH * NPTS * KNN;
  float* pmax = ws + off; off += (size_t)(NPTS / 128) * NBATCH * 1024;
  float* psum = ws + off; off += (size_t)(NPTS / 128) * NBATCH * 1024;
  float* pooled = ws + off; off += (size_t)NBATCH * 2048;
  float* t0buf = ws + off;  off += (size_t)NBATCH * NPTS * 256;  // max O
  unsigned short* w2h = (unsigned short*)(ws + off); off += 64 * 64 / 2 * 2;
  unsigned short* w2l = w2h + 64 * 64;
  unsigned short* w3h = (unsigned short*)(ws + off); off += 64 * 128 / 2 * 2;
  unsigned short* w3l = w3h + 64 * 128;
  unsigned short* w4h = (unsigned short*)(ws + off); off += 128 * 256 / 2 * 2;
  unsigned short* w4l = w4h + 128 * 256;
  unsigned short* w5h = (unsigned short*)(ws + off); off += 512 * 1024 / 2 * 2;
  unsigned short* w5l = w5h + 512 * 1024;
  unsigned short* a5h = (unsigned short*)(ws + off); off += (size_t)16384 * 512 / 2 * 2;
  unsigned short* a5l = a5h + (size_t)16384 * 512;
  float* dist = ws + off;  // adaptive: nb_grp * NPTS * NPTS floats, placed last

  size_t avail = ws_size / 4 - off;
  int nb_grp = 8;
  while (nb_grp > 1 && (size_t)nb_grp * NPTS * NPTS > avail) nb_grp >>= 1;

  k_transpose<<<(NBATCH * NPTS * 3 + 255) / 256, 256, 0, stream>>>(x, h0);

  // weight hi/lo fragment prep (depends only on inputs -- run up front)
  k_wprep<64, 64><<<(64 * 64 + 255) / 256, 256, 0, stream>>>(w2, w2h, w2l);
  k_wprep<64, 128><<<(64 * 128 + 255) / 256, 256, 0, stream>>>(w3, w3h, w3l);
  k_wprep<128, 256><<<(128 * 256 + 255) / 256, 256, 0, stream>>>(w4, w4h, w4l);
  k_wprep<512, 1024><<<(512 * 1024 + 255) / 256, 256, 0, stream>>>(w5, w5h, w5l);

  // ---- edge conv 1 (C=3 -> O=64): fused register kNN (wave/row) + fp32 edge
  k_knn3<<<dim3(NPTS / 4, NBATCH), 256, 0, stream>>>(h0, knn);
  k_edge<3, 64><<<NBATCH * NPTS / 4, 256, 0, stream>>>(h0, knn, w1, g1, b1, x1);

  // ---- edge conv 2 (C=64 -> O=64)
  for (int b0 = 0; b0 < NBATCH; b0 += nb_grp) {
    k_dist<64><<<dim3(NPTS / 128, NPTS / 128, nb_grp), 256, 0, stream>>>(
        x1 + (size_t)b0 * NPTS * 64, dist);
    k_topk<<<dim3(NPTS / 4, nb_grp), 256, 0, stream>>>(dist,
                                                       knn + (size_t)b0 * NPTS * KNN);
  }
  k_t0<64, 64><<<dim3(NBATCH * NPTS / 128, 1), 256, 0, stream>>>(x1, w2, t0buf);
  k_edge_mfma<64, 64><<<NBATCH * NPTS / 2, 256, 0, stream>>>(x1, knn, w2h, w2l, t0buf,
                                                             g2, b2, x2);

  // ---- edge conv 3 (C=64 -> O=128)
  for (int b0 = 0; b0 < NBATCH; b0 += nb_grp) {
    k_dist<64><<<dim3(NPTS / 128, NPTS / 128, nb_grp), 256, 0, stream>>>(
        x2 + (size_t)b0 * NPTS * 64, dist);
    k_topk<<<dim3(NPTS / 4, nb_grp), 256, 0, stream>>>(dist,
                                                       knn + (size_t)b0 * NPTS * KNN);
  }
  k_t0<64, 128><<<dim3(NBATCH * NPTS / 128, 2), 256, 0, stream>>>(x2, w3, t0buf);
  k_edge_mfma<64, 128><<<NBATCH * NPTS / 2, 256, 0, stream>>>(x2, knn, w3h, w3l, t0buf,
                                                              g3, b3, x3);

  // ---- edge conv 4 (C=128 -> O=256)
  for (int b0 = 0; b0 < NBATCH; b0 += nb_grp) {
    k_dist<128><<<dim3(NPTS / 128, NPTS / 128, nb_grp), 256, 0, stream>>>(
        x3 + (size_t)b0 * NPTS * 128, dist);
    k_topk<<<dim3(NPTS / 4, nb_grp), 256, 0, stream>>>(dist,
                                                       knn + (size_t)b0 * NPTS * KNN);
  }
  k_t0<128, 256><<<dim3(NBATCH * NPTS / 128, 4), 256, 0, stream>>>(x3, w4, t0buf);
  k_edge_mfma<128, 256><<<NBATCH * NPTS / 2, 256, 0, stream>>>(x3, knn, w4h, w4l, t0buf,
                                                               g4, b4, x4);

  // ---- point MLP (split-bf16 MFMA GEMM) + pooling + head
  k_aprep<<<(16 * 1024 * 64 + 255) / 256, 256, 0, stream>>>(x1, x2, x3, x4, a5h, a5l);
  k_mlp5<<<dim3(NBATCH * NPTS / 128, 8), 256, 0, stream>>>(a5h, a5l, w5h, w5l, g5, b5,
                                                           pmax, psum);
  k_pool<<<(NBATCH * 1024 + 255) / 256, 256, 0, stream>>>(pmax, psum, pooled);
  k_head<<<NBATCH, 256, 0, stream>>>(pooled, wl1, g6, b6, wl2, bl2, g7, b7, wl3, bl3,
                                     (float*)d_out);
}

// Round 13
// 3018.399 us; speedup vs baseline: 2.8902x; 2.8902x over previous
//
#include <hip/hip_runtime.h>
#include <cstddef>
#include <cstdint>

#define NBATCH 8
#define NPTS   2048
#define KNN    20

typedef __attribute__((ext_vector_type(8))) short short8;
typedef __attribute__((ext_vector_type(4))) float f32x4;

__device__ __forceinline__ unsigned short f2bf(float f) {
  unsigned u = __float_as_uint(f);
  u += 0x7fff + ((u >> 16) & 1);   // round-to-nearest-even
  return (unsigned short)(u >> 16);
}
__device__ __forceinline__ float bf2f(unsigned short h) {
  return __uint_as_float(((unsigned)h) << 16);
}

// ---------------------------------------------------------------------------
// wave-level exact top-20 over 2048 candidates: lane holds 32 values,
// global index of v[slot] on lane l is slot*64 + l. One wave per row.
// Tie-break: lowest index (ascending slot strict >, explicit idx compares).
// ---------------------------------------------------------------------------
__device__ __forceinline__ void wave_top20(float (&v)[32], int lane,
                                           int* __restrict__ row_out) {
  float bv = v[0];
  int bl = 0;
#pragma unroll
  for (int i = 1; i < 32; i++)
    if (v[i] > bv) { bv = v[i]; bl = i; }

  int keep = 0;
  for (int k = 0; k < KNN; k++) {
    float rv = bv;
    int ri = bl * 64 + lane;
#pragma unroll
    for (int off = 32; off > 0; off >>= 1) {
      float ov = __shfl_down(rv, off);
      int oi = __shfl_down(ri, off);
      if (ov > rv || (ov == rv && oi < ri)) { rv = ov; ri = oi; }
    }
    int wi = __shfl(ri, 0);
    if (lane == k) keep = wi;
    if ((wi & 63) == lane) {
      int slot = wi >> 6;
#pragma unroll
      for (int i = 0; i < 32; i++)
        if (i == slot) v[i] = -3.0e38f;
      bv = v[0]; bl = 0;
#pragma unroll
      for (int i = 1; i < 32; i++)
        if (v[i] > bv) { bv = v[i]; bl = i; }
    }
  }
  if (lane < KNN) row_out[lane] = keep;
}

// ---------------------------------------------------------------------------
// transpose (B,3,N) -> (B,N,3)
// ---------------------------------------------------------------------------
__global__ void k_transpose(const float* __restrict__ x, float* __restrict__ h0) {
  int i = blockIdx.x * 256 + threadIdx.x;
  if (i >= NBATCH * NPTS * 3) return;
  int c = i % 3;
  int n = (i / 3) % NPTS;
  int b = i / (3 * NPTS);
  h0[i] = x[((size_t)b * 3 + c) * NPTS + n];
}

// ---------------------------------------------------------------------------
// pairwise "distance" pd = 2*dot - sq_n - sq_m. blockIdx.z = batch in group.
// 128x128 tile per block, 8x8 microtile (16x16 thread grid), K-chunked TK=32.
// LDS layout off(c4,m) = c4*580 + m*4 + (m>>3)*4 words: 580 = 4 (mod 32) and
// the every-8-rows pad keeps staging writes / ra (broadcast) / cb (2-way) at
// the LDS bank minimum; all float4 accesses 16B-aligned.
// NOTE: no waves/EU pin -- __launch_bounds__(256,4) capped VGPRs at ~128 and
// spilled acc[8][8] to scratch (6.9 GB writes/dispatch, R12 regression).
// Accumulation order (c ascending, x/y/z/w) and sq order are BIT-IDENTICAL
// to the R10 kernel -> zero kNN-selection risk.
// ---------------------------------------------------------------------------
template <int C>
__global__ __launch_bounds__(256) void k_dist(const float* __restrict__ xg,
                                              float* __restrict__ dist) {
  constexpr int TK = 32;
  constexpr int NC4 = TK / 4;   // 8
  constexpr int CST = 580;      // words per c4 slice
  __shared__ __attribute__((aligned(16))) float rs[NC4 * CST];
  __shared__ __attribute__((aligned(16))) float cs[NC4 * CST];
  __shared__ float sqr[128];
  __shared__ float sqc[128];

  const float* xb = xg + (size_t)blockIdx.z * NPTS * C;
  float* db = dist + (size_t)blockIdx.z * NPTS * NPTS;
  const int rt = blockIdx.y, ct = blockIdx.x;
  const int tid = threadIdx.x;
  const int tx = tid & 15, ty = tid >> 4;

  float acc[8][8] = {};
  float sreg = 0.f;   // tid<128: sq of row tid; else sq of col tid-128

  for (int kt = 0; kt < C; kt += TK) {
    if (kt) __syncthreads();   // all reads of previous chunk done
    // stage: c4-fast lane mapping (coalesced global), 4 passes of 32 rows
#pragma unroll
    for (int p = 0; p < 4; p++) {
      int c4 = tid & 7;
      int m = (tid >> 3) + p * 32;
      int o = c4 * CST + m * 4 + (m >> 3) * 4;
      *(float4*)&rs[o] = *(const float4*)&xb[(size_t)(rt * 128 + m) * C + kt + c4 * 4];
      *(float4*)&cs[o] = *(const float4*)&xb[(size_t)(ct * 128 + m) * C + kt + c4 * 4];
    }
    __syncthreads();

    // sq partial (ascending c within chunk -- same order as a straight c-loop)
    {
      int m = tid & 127;
      const float* base = (tid < 128) ? rs : cs;
#pragma unroll
      for (int c4 = 0; c4 < NC4; c4++) {
        float4 v = *(const float4*)&base[c4 * CST + m * 4 + (m >> 3) * 4];
        sreg += v.x * v.x; sreg += v.y * v.y; sreg += v.z * v.z; sreg += v.w * v.w;
      }
    }

    // 8x8 microtile MACs
#pragma unroll
    for (int c4 = 0; c4 < NC4; c4++) {
      float4 ra[8];
#pragma unroll
      for (int i = 0; i < 8; i++) {
        int m = ty * 8 + i;
        ra[i] = *(const float4*)&rs[c4 * CST + m * 4 + ty * 4];
      }
#pragma unroll
      for (int j = 0; j < 8; j++) {
        int n = tx + 16 * j;
        float4 cb = *(const float4*)&cs[c4 * CST + n * 4 + (n >> 3) * 4];
#pragma unroll
        for (int i = 0; i < 8; i++)
          acc[i][j] += ra[i].x * cb.x + ra[i].y * cb.y +
                       ra[i].z * cb.z + ra[i].w * cb.w;
      }
    }
  }

  __syncthreads();
  if (tid < 128) sqr[tid] = sreg;
  else           sqc[tid - 128] = sreg;
  __syncthreads();

#pragma unroll
  for (int i = 0; i < 8; i++) {
    float sr = sqr[ty * 8 + i];
#pragma unroll
    for (int j = 0; j < 8; j++) {
      int n = tx + 16 * j;
      db[(size_t)(rt * 128 + ty * 8 + i) * NPTS + ct * 128 + n] =
          2.f * acc[i][j] - sr - sqc[n];
    }
  }
}

// ---------------------------------------------------------------------------
// top-20 per row from materialized dist. One wave per row, 4 rows per block.
// ---------------------------------------------------------------------------
__global__ __launch_bounds__(256) void k_topk(const float* __restrict__ dist,
                                              int* __restrict__ idx_out) {
  const int wid = threadIdx.x >> 6;
  const int lane = threadIdx.x & 63;
  const int n = blockIdx.x * 4 + wid;
  const int z = blockIdx.y;
  const float* drow = dist + ((size_t)z * NPTS + n) * NPTS;
  int* row_out = idx_out + ((size_t)z * NPTS + n) * KNN;

  float v[32];
#pragma unroll
  for (int i = 0; i < 32; i++) v[i] = drow[i * 64 + lane];

  wave_top20(v, lane, row_out);
}

// ---------------------------------------------------------------------------
// conv1 fused kNN (C=3): one wave per row, register recompute + wave_top20.
// ---------------------------------------------------------------------------
__global__ __launch_bounds__(256) void k_knn3(const float* __restrict__ x,
                                              int* __restrict__ idx_out) {
  const int wid = threadIdx.x >> 6;
  const int lane = threadIdx.x & 63;
  const int n = blockIdx.x * 4 + wid;
  const int b = blockIdx.y;
  const float* xb = x + (size_t)b * NPTS * 3;
  int* row_out = idx_out + ((size_t)b * NPTS + n) * KNN;

  const float qx = xb[n * 3 + 0], qy = xb[n * 3 + 1], qz = xb[n * 3 + 2];
  float qsq = 0.f;
  qsq += qx * qx; qsq += qy * qy; qsq += qz * qz;

  float v[32];
#pragma unroll
  for (int i = 0; i < 32; i++) {
    int m = i * 64 + lane;
    float cx = xb[m * 3 + 0], cy = xb[m * 3 + 1], cz = xb[m * 3 + 2];
    float csq = 0.f;
    csq += cx * cx; csq += cy * cy; csq += cz * cz;
    float acc = 0.f;
    acc += qx * cx; acc += qy * cy; acc += qz * cz;
    v[i] = 2.f * acc - qsq - csq;
  }

  wave_top20(v, lane, row_out);
}

// ---------------------------------------------------------------------------
// t0 GEMM: t0buf[n, o] = sum_c x[n, c] * w[C+c, o]   (center @ w_hi)
// ---------------------------------------------------------------------------
template <int C, int O>
__global__ __launch_bounds__(256) void k_t0(const float* __restrict__ x,
                                            const float* __restrict__ w,
                                            float* __restrict__ t0buf) {
  constexpr int TM = 128, TN = 64, TK = 16;
  __shared__ __attribute__((aligned(16))) float As[TK][TM + 4];
  __shared__ __attribute__((aligned(16))) float Bs[TK][TN + 4];
  const int mt = blockIdx.x, nt = blockIdx.y;
  const int tid = threadIdx.x;
  const int tx = tid & 15, ty = tid >> 4;
  const size_t m0 = (size_t)mt * TM;
  const int n0 = nt * TN;
  float acc[8][4] = {};

  for (int kt = 0; kt < C; kt += TK) {
#pragma unroll
    for (int e = 0; e < 8; e++) {
      int idx = tid + e * 256;
      int m = idx >> 4, k = idx & 15;
      As[k][m] = x[(m0 + m) * C + kt + k];
    }
#pragma unroll
    for (int e = 0; e < 4; e++) {
      int idx = tid + e * 256;
      int k = idx >> 6, nn = idx & 63;
      Bs[k][nn] = w[(size_t)(C + kt + k) * O + n0 + nn];
    }
    __syncthreads();
#pragma unroll
    for (int kk = 0; kk < TK; kk++) {
      float4 a0 = *(const float4*)&As[kk][ty * 8];
      float4 a1 = *(const float4*)&As[kk][ty * 8 + 4];
      float4 b0 = *(const float4*)&Bs[kk][tx * 4];
      float av[8] = {a0.x, a0.y, a0.z, a0.w, a1.x, a1.y, a1.z, a1.w};
      float bb[4] = {b0.x, b0.y, b0.z, b0.w};
#pragma unroll
      for (int i = 0; i < 8; i++)
#pragma unroll
        for (int j = 0; j < 4; j++) acc[i][j] += av[i] * bb[j];
    }
    __syncthreads();
  }
#pragma unroll
  for (int i = 0; i < 8; i++)
#pragma unroll
    for (int j = 0; j < 4; j++)
      t0buf[(m0 + ty * 8 + i) * O + n0 + tx * 4 + j] = acc[i][j];
}

// ---------------------------------------------------------------------------
// weight -> bf16 hi/lo split in 16x16x32 B-fragment order.
// ---------------------------------------------------------------------------
template <int C, int O>
__global__ void k_wprep(const float* __restrict__ w,
                        unsigned short* __restrict__ whi,
                        unsigned short* __restrict__ wlo) {
  int e = blockIdx.x * 256 + threadIdx.x;
  if (e >= C * O) return;
  constexpr int NT = O / 16;
  int j = e & 7;
  int slot = e >> 3;
  int lane = slot & 63;
  int t2 = slot >> 6;
  int nt = t2 % NT, kb = t2 / NT;
  int k = kb * 32 + ((lane >> 4) & 3) * 8 + j;
  int n = nt * 16 + (lane & 15);
  float v = w[(size_t)k * O + n];
  unsigned short h = f2bf(v);
  unsigned short l = f2bf(v - bf2f(h));
  whi[e] = h;
  wlo[e] = l;
}

// ---------------------------------------------------------------------------
// feature matrix -> bf16 hi/lo split in 16x16x32 A-fragment order for mlp5.
// ---------------------------------------------------------------------------
__global__ void k_aprep(const float* __restrict__ x1, const float* __restrict__ x2,
                        const float* __restrict__ x3, const float* __restrict__ x4,
                        unsigned short* __restrict__ ah, unsigned short* __restrict__ al) {
  int e8 = blockIdx.x * 256 + threadIdx.x;   // 16 kb * 1024 mtg * 64 lanes
  if (e8 >= 16 * 1024 * 64) return;
  int lane = e8 & 63;
  int mtg = (e8 >> 6) & 1023;
  int kb = e8 >> 16;
  int m = mtg * 16 + (lane & 15);
  int k0 = kb * 32 + ((lane >> 4) & 3) * 8;
  const float* p;
  if (k0 < 64)       p = &x1[(size_t)m * 64 + k0];
  else if (k0 < 128) p = &x2[(size_t)m * 64 + (k0 - 64)];
  else if (k0 < 256) p = &x3[(size_t)m * 128 + (k0 - 128)];
  else               p = &x4[(size_t)m * 256 + (k0 - 256)];
  float4 f0 = *(const float4*)p;
  float4 f1 = *(const float4*)(p + 4);
  float fv[8] = {f0.x, f0.y, f0.z, f0.w, f1.x, f1.y, f1.z, f1.w};
  short8 h8, l8;
#pragma unroll
  for (int j = 0; j < 8; j++) {
    unsigned short h = f2bf(fv[j]);
    unsigned short l = f2bf(fv[j] - bf2f(h));
    h8[j] = (short)h;
    l8[j] = (short)l;
  }
  *(short8*)&ah[(size_t)e8 * 8] = h8;
  *(short8*)&al[(size_t)e8 * 8] = l8;
}

// ---------------------------------------------------------------------------
// MFMA edge conv (C in {64,128}): per block 2 points, 32 padded neighbor rows.
// Split bf16: D ~= AhBh + AhBl + AlBh.
// ---------------------------------------------------------------------------
template <int C, int O>
__global__ __launch_bounds__(256) void k_edge_mfma(
    const float* __restrict__ x, const int* __restrict__ knn,
    const unsigned short* __restrict__ whi, const unsigned short* __restrict__ wlo,
    const float* __restrict__ t0buf, const float* __restrict__ g,
    const float* __restrict__ bta, float* __restrict__ out) {
  constexpr int KB = C / 32;
  constexpr int NT = O / 16;
  constexpr int NTW = NT / 2;
  __shared__ unsigned short Ah[2 * 2 * KB * 512];
  __shared__ unsigned short Al[2 * 2 * KB * 512];

  const int blk = blockIdx.x;
  const int b = blk / (NPTS / 2);
  const int n0 = (blk % (NPTS / 2)) * 2;
  const int tid = threadIdx.x;
  const int lane = tid & 63;
  const int wid = tid >> 6;
  const int pt = wid >> 1;
  const int nsl = wid & 1;
  const int ptg = b * NPTS + n0 + pt;
  const float* xb = x + (size_t)b * NPTS * C;
  const int kbase = ptg * KNN;

  if constexpr (C == 128) {
    const float2 ctr2 = *(const float2*)&xb[(size_t)(n0 + pt) * C + lane * 2];
    const int kb = lane >> 4;
    const int q = (lane >> 2) & 3;
    const int j2 = 2 * (lane & 3);
#pragma unroll
    for (int i = 0; i < 16; i++) {
      int r = 2 * i + nsl;
      unsigned hp = 0, lp = 0;
      if (r < KNN) {
        int m = knn[kbase + r];
        float2 v = *(const float2*)&xb[(size_t)m * C + lane * 2];
        float d0 = v.x - ctr2.x, d1 = v.y - ctr2.y;
        unsigned short h0 = f2bf(d0), h1 = f2bf(d1);
        unsigned short l0 = f2bf(d0 - bf2f(h0)), l1 = f2bf(d1 - bf2f(h1));
        hp = (unsigned)h0 | ((unsigned)h1 << 16);
        lp = (unsigned)l0 | ((unsigned)l1 << 16);
      }
      int mt = r >> 4, row = r & 15;
      int L = row + 16 * q;
      int phys = L ^ ((4 * kb + q) & 15);
      int idx = ((pt * 2 + mt) * KB + kb) * 512 + phys * 8 + j2;
      *(unsigned*)&Ah[idx] = hp;
      *(unsigned*)&Al[idx] = lp;
    }
  } else {
    const float ctrv = xb[(size_t)(n0 + pt) * C + lane];
    const int kb = lane >> 5;
    const int q = (lane >> 3) & 3;
    const int j = lane & 7;
#pragma unroll
    for (int i = 0; i < 16; i++) {
      int r = 2 * i + nsl;
      unsigned short h = 0, l = 0;
      if (r < KNN) {
        int m = knn[kbase + r];
        float d = xb[(size_t)m * C + lane] - ctrv;
        h = f2bf(d);
        l = f2bf(d - bf2f(h));
      }
      int mt = r >> 4, row = r & 15;
      int L = row + 16 * q;
      int phys = L ^ ((4 * kb + q) & 15);
      int idx = ((pt * 2 + mt) * KB + kb) * 512 + phys * 8 + j;
      Ah[idx] = h;
      Al[idx] = l;
    }
  }
  __syncthreads();

  f32x4 acc[2][NTW];
#pragma unroll
  for (int mt = 0; mt < 2; mt++)
#pragma unroll
    for (int t = 0; t < NTW; t++) acc[mt][t] = (f32x4){0.f, 0.f, 0.f, 0.f};

#pragma unroll
  for (int kb = 0; kb < KB; kb++) {
    int phys = lane ^ ((4 * kb + (lane >> 4)) & 15);
    short8 ah[2], al[2];
#pragma unroll
    for (int mt = 0; mt < 2; mt++) {
      int idx = ((pt * 2 + mt) * KB + kb) * 512 + phys * 8;
      ah[mt] = *(const short8*)&Ah[idx];
      al[mt] = *(const short8*)&Al[idx];
    }
#pragma unroll
    for (int t = 0; t < NTW; t++) {
      int nt = nsl * NTW + t;
      size_t widx = ((size_t)(kb * NT + nt) * 64 + lane) * 8;
      short8 bh = *(const short8*)&whi[widx];
      short8 bl = *(const short8*)&wlo[widx];
#pragma unroll
      for (int mt = 0; mt < 2; mt++) {
        acc[mt][t] = __builtin_amdgcn_mfma_f32_16x16x32_bf16(ah[mt], bh, acc[mt][t], 0, 0, 0);
        acc[mt][t] = __builtin_amdgcn_mfma_f32_16x16x32_bf16(ah[mt], bl, acc[mt][t], 0, 0, 0);
        acc[mt][t] = __builtin_amdgcn_mfma_f32_16x16x32_bf16(al[mt], bh, acc[mt][t], 0, 0, 0);
      }
    }
  }

#pragma unroll
  for (int t = 0; t < NTW; t++) {
    int o = (nsl * NTW + t) * 16 + (lane & 15);
    float tv = t0buf[(size_t)ptg * O + o];
    float gv = g[o], bv = bta[o];
    float m = -3.0e38f;
#pragma unroll
    for (int mt = 0; mt < 2; mt++)
#pragma unroll
      for (int r = 0; r < 4; r++) {
        float h = (acc[mt][t][r] + tv) * gv + bv;
        h = (h >= 0.f) ? h : 0.2f * h;
        m = fmaxf(m, h);
      }
    m = fmaxf(m, __shfl_xor(m, 16));
    m = fmaxf(m, __shfl_xor(m, 32));
    if (lane < 16) out[(size_t)ptg * O + o] = m;
  }
}

// ---------------------------------------------------------------------------
// fp32 edge conv -- retained for conv1 (C=3) only.
// ---------------------------------------------------------------------------
template <int C, int O>
__global__ __launch_bounds__(256) void k_edge(const float* __restrict__ x,
                                              const int* __restrict__ knn,
                                              const float* __restrict__ w,
                                              const float* __restrict__ g,
                                              const float* __restrict__ bta,
                                              float* __restrict__ out) {
  constexpr int JO = O / 64;
  constexpr int NPB = 4;
  __shared__ __attribute__((aligned(16))) float nbd[NPB * KNN * C];

  const int blk = blockIdx.x;
  const int b = blk / (NPTS / NPB);
  const int n0 = (blk % (NPTS / NPB)) * NPB;
  const int tid = threadIdx.x;
  const int lane = tid & 63;
  const int p = tid >> 6;
  const float* xb = x + (size_t)b * NPTS * C;

  const int kbase = (b * NPTS + n0 + p) * KNN;
  float* nb_p = nbd + p * KNN * C;
  int midx[KNN];
#pragma unroll
  for (int k = 0; k < KNN; k++) midx[k] = knn[kbase + k];

  float cv0 = 0.f;
  if (lane < C) cv0 = xb[(size_t)(n0 + p) * C + lane];
  float vv[KNN];
#pragma unroll
  for (int k = 0; k < KNN; k++)
    vv[k] = (lane < C) ? xb[(size_t)midx[k] * C + lane] : 0.f;
#pragma unroll
  for (int k = 0; k < KNN; k++)
    if (lane < C) nb_p[k * C + lane] = vv[k] - cv0;

  float acc[KNN][JO];
  {
    float t0[JO];
#pragma unroll
    for (int j = 0; j < JO; j++) t0[j] = 0.f;
    for (int c = 0; c < C; c++) {
      float cc = __shfl(cv0, c);
#pragma unroll
      for (int j = 0; j < JO; j++)
        t0[j] += cc * w[(size_t)(C + c) * O + j * 64 + lane];
    }
#pragma unroll
    for (int k = 0; k < KNN; k++)
#pragma unroll
      for (int j = 0; j < JO; j++) acc[k][j] = t0[j];
  }

  for (int c = 0; c < C; c++) {
    float wv[JO];
#pragma unroll
    for (int j = 0; j < JO; j++) wv[j] = w[(size_t)c * O + j * 64 + lane];
#pragma unroll
    for (int k = 0; k < KNN; k++) {
      float f = nb_p[k * C + c];
#pragma unroll
      for (int j = 0; j < JO; j++) acc[k][j] += f * wv[j];
    }
  }

#pragma unroll
  for (int j = 0; j < JO; j++) {
    const float gv = g[j * 64 + lane], bv = bta[j * 64 + lane];
    float mx = -3.0e38f;
#pragma unroll
    for (int k = 0; k < KNN; k++) {
      float h = acc[k][j] * gv + bv;
      h = (h >= 0.f) ? h : 0.2f * h;
      mx = fmaxf(mx, h);
    }
    out[(size_t)(b * NPTS + n0 + p) * O + j * 64 + lane] = mx;
  }
}

// ---------------------------------------------------------------------------
// point MLP 512->1024 as split-bf16 MFMA GEMM, no LDS, no barriers.
// ---------------------------------------------------------------------------
__global__ __launch_bounds__(256) void k_mlp5(const unsigned short* __restrict__ a5h,
                                              const unsigned short* __restrict__ a5l,
                                              const unsigned short* __restrict__ w5h,
                                              const unsigned short* __restrict__ w5l,
                                              const float* __restrict__ g5,
                                              const float* __restrict__ b5,
                                              float* __restrict__ pmax,
                                              float* __restrict__ psum) {
  const int mtb = blockIdx.x;   // 0..127
  const int ntb = blockIdx.y;   // 0..7
  const int tid = threadIdx.x;
  const int lane = tid & 63;
  const int nsl = tid >> 6;     // wave id 0..3

  f32x4 acc[8][2];
#pragma unroll
  for (int mt = 0; mt < 8; mt++)
#pragma unroll
    for (int t = 0; t < 2; t++) acc[mt][t] = (f32x4){0.f, 0.f, 0.f, 0.f};

  for (int kb = 0; kb < 16; kb++) {
    short8 bh[2], bl[2];
#pragma unroll
    for (int t = 0; t < 2; t++) {
      int ntg = ntb * 8 + nsl * 2 + t;
      size_t widx = ((size_t)(kb * 64 + ntg) * 64 + lane) * 8;
      bh[t] = *(const short8*)&w5h[widx];
      bl[t] = *(const short8*)&w5l[widx];
    }
#pragma unroll
    for (int mt = 0; mt < 8; mt++) {
      size_t aidx = (((size_t)kb * 1024 + mtb * 8 + mt) * 64 + lane) * 8;
      short8 ah = *(const short8*)&a5h[aidx];
      short8 al = *(const short8*)&a5l[aidx];
#pragma unroll
      for (int t = 0; t < 2; t++) {
        acc[mt][t] = __builtin_amdgcn_mfma_f32_16x16x32_bf16(ah, bh[t], acc[mt][t], 0, 0, 0);
        acc[mt][t] = __builtin_amdgcn_mfma_f32_16x16x32_bf16(ah, bl[t], acc[mt][t], 0, 0, 0);
        acc[mt][t] = __builtin_amdgcn_mfma_f32_16x16x32_bf16(al, bh[t], acc[mt][t], 0, 0, 0);
      }
    }
  }

#pragma unroll
  for (int t = 0; t < 2; t++) {
    int o = ntb * 128 + (nsl * 2 + t) * 16 + (lane & 15);
    float gv = g5[o], bv = b5[o];
    float mx = -3.0e38f, sm = 0.f;
#pragma unroll
    for (int mt = 0; mt < 8; mt++)
#pragma unroll
      for (int r = 0; r < 4; r++) {
        float h = acc[mt][t][r] * gv + bv;
        h = (h >= 0.f) ? h : 0.2f * h;
        mx = fmaxf(mx, h);
        sm += h;
      }
    mx = fmaxf(mx, __shfl_xor(mx, 16));
    mx = fmaxf(mx, __shfl_xor(mx, 32));
    sm += __shfl_xor(sm, 16);
    sm += __shfl_xor(sm, 32);
    if (lane < 16) {
      pmax[(size_t)mtb * 1024 + o] = mx;
      psum[(size_t)mtb * 1024 + o] = sm;
    }
  }
}

// ---------------------------------------------------------------------------
// reduce tile partials -> pooled (B, 2048) = [max(1024), mean(1024)]
// ---------------------------------------------------------------------------
__global__ void k_pool(const float* __restrict__ pmax, const float* __restrict__ psum,
                       float* __restrict__ pooled) {
  int i = blockIdx.x * 256 + threadIdx.x;
  if (i >= NBATCH * 1024) return;
  int b = i / 1024, e = i - b * 1024;
  constexpr int NT = NPTS / 128;
  float mx = -3.0e38f, sm = 0.f;
  for (int t = 0; t < NT; t++) {
    mx = fmaxf(mx, pmax[((size_t)b * NT + t) * 1024 + e]);
    sm += psum[((size_t)b * NT + t) * 1024 + e];
  }
  pooled[(size_t)b * 2048 + e] = mx;
  pooled[(size_t)b * 2048 + 1024 + e] = sm * (1.0f / NPTS);
}

// ---------------------------------------------------------------------------
// FC head: 2048->512 (leaky, affine) -> 256 (bias, leaky, affine) -> 40 (+bias)
// ---------------------------------------------------------------------------
__global__ __launch_bounds__(256) void k_head(const float* __restrict__ pooled,
                                              const float* __restrict__ wl1,
                                              const float* __restrict__ g6,
                                              const float* __restrict__ b6,
                                              const float* __restrict__ wl2,
                                              const float* __restrict__ bl2,
                                              const float* __restrict__ g7,
                                              const float* __restrict__ b7,
                                              const float* __restrict__ wl3,
                                              const float* __restrict__ bl3,
                                              float* __restrict__ out) {
  const int b = blockIdx.x;
  const int tid = threadIdx.x;
  __shared__ float pl[2048];
  __shared__ float h1[512];
  __shared__ float h2[256];

  for (int i = tid; i < 2048; i += 256) pl[i] = pooled[(size_t)b * 2048 + i];
  __syncthreads();

  for (int o = tid; o < 512; o += 256) {
    float a = 0.f;
    for (int c = 0; c < 2048; c++) a += pl[c] * wl1[(size_t)c * 512 + o];
    a = a * g6[o] + b6[o];
    h1[o] = (a >= 0.f) ? a : 0.2f * a;
  }
  __syncthreads();

  {
    float a = 0.f;
    for (int c = 0; c < 512; c++) a += h1[c] * wl2[(size_t)c * 256 + tid];
    a = (a + bl2[tid]) * g7[tid] + b7[tid];
    h2[tid] = (a >= 0.f) ? a : 0.2f * a;
  }
  __syncthreads();

  if (tid < 40) {
    float a = bl3[tid];
    for (int c = 0; c < 256; c++) a += h2[c] * wl3[(size_t)c * 40 + tid];
    out[(size_t)b * 40 + tid] = a;
  }
}

// ---------------------------------------------------------------------------
extern "C" void kernel_launch(void* const* d_in, const int* in_sizes, int n_in,
                              void* d_out, int out_size, void* d_ws, size_t ws_size,
                              hipStream_t stream) {
  (void)in_sizes; (void)n_in; (void)out_size;
  const float* x   = (const float*)d_in[0];
  const float* w1  = (const float*)d_in[1];
  const float* g1  = (const float*)d_in[2];
  const float* b1  = (const float*)d_in[3];
  const float* w2  = (const float*)d_in[4];
  const float* g2  = (const float*)d_in[5];
  const float* b2  = (const float*)d_in[6];
  const float* w3  = (const float*)d_in[7];
  const float* g3  = (const float*)d_in[8];
  const float* b3  = (const float*)d_in[9];
  const float* w4  = (const float*)d_in[10];
  const float* g4  = (const float*)d_in[11];
  const float* b4  = (const float*)d_in[12];
  const float* w5  = (const float*)d_in[13];
  const float* g5  = (const float*)d_in[14];
  const float* b5  = (const float*)d_in[15];
  const float* wl1 = (const float*)d_in[16];
  const float* g6  = (const float*)d_in[17];
  const float* b6  = (const float*)d_in[18];
  const float* wl2 = (const float*)d_in[19];
  const float* bl2 = (const float*)d_in[20];
  const float* g7  = (const float*)d_in[21];
  const float* b7  = (const float*)d_in[22];
  const float* wl3 = (const float*)d_in[23];
  const float* bl3 = (const float*)d_in[24];

  float* ws = (float*)d_ws;
  size_t off = 0;
  float* h0 = ws + off;   off += (size_t)NBATCH * NPTS * 3;
  float* x1 = ws + off;   off += (size_t)NBATCH * NPTS * 64;
  float* x2 = ws + off;   off += (size_t)NBATCH * NPTS * 64;
  float* x3 = ws + off;   off += (size_t)NBATCH * NPTS * 128;
  float* x4 = ws + off;   off += (size_t)NBATCH * NPTS * 256;
  int* knn = (int*)(ws + off); off += (size_t)NBATCH * NPTS * KNN;
  float* pmax = ws + off; off += (size_t)(NPTS / 128) * NBATCH * 1024;
  float* psum = ws + off; off += (size_t)(NPTS / 128) * NBATCH * 1024;
  float* pooled = ws + off; off += (size_t)NBATCH * 2048;
  float* t0buf = ws + off;  off += (size_t)NBATCH * NPTS * 256;  // max O
  unsigned short* w2h = (unsigned short*)(ws + off); off += 64 * 64 / 2 * 2;
  unsigned short* w2l = w2h + 64 * 64;
  unsigned short* w3h = (unsigned short*)(ws + off); off += 64 * 128 / 2 * 2;
  unsigned short* w3l = w3h + 64 * 128;
  unsigned short* w4h = (unsigned short*)(ws + off); off += 128 * 256 / 2 * 2;
  unsigned short* w4l = w4h + 128 * 256;
  unsigned short* w5h = (unsigned short*)(ws + off); off += 512 * 1024 / 2 * 2;
  unsigned short* w5l = w5h + 512 * 1024;
  unsigned short* a5h = (unsigned short*)(ws + off); off += (size_t)16384 * 512 / 2 * 2;
  unsigned short* a5l = a5h + (size_t)16384 * 512;
  float* dist = ws + off;  // adaptive: nb_grp * NPTS * NPTS floats, placed last

  size_t avail = ws_size / 4 - off;
  int nb_grp = 8;
  while (nb_grp > 1 && (size_t)nb_grp * NPTS * NPTS > avail) nb_grp >>= 1;

  k_transpose<<<(NBATCH * NPTS * 3 + 255) / 256, 256, 0, stream>>>(x, h0);

  // weight hi/lo fragment prep (depends only on inputs -- run up front)
  k_wprep<64, 64><<<(64 * 64 + 255) / 256, 256, 0, stream>>>(w2, w2h, w2l);
  k_wprep<64, 128><<<(64 * 128 + 255) / 256, 256, 0, stream>>>(w3, w3h, w3l);
  k_wprep<128, 256><<<(128 * 256 + 255) / 256, 256, 0, stream>>>(w4, w4h, w4l);
  k_wprep<512, 1024><<<(512 * 1024 + 255) / 256, 256, 0, stream>>>(w5, w5h, w5l);

  // ---- edge conv 1 (C=3 -> O=64): fused register kNN (wave/row) + fp32 edge
  k_knn3<<<dim3(NPTS / 4, NBATCH), 256, 0, stream>>>(h0, knn);
  k_edge<3, 64><<<NBATCH * NPTS / 4, 256, 0, stream>>>(h0, knn, w1, g1, b1, x1);

  // ---- edge conv 2 (C=64 -> O=64)
  for (int b0 = 0; b0 < NBATCH; b0 += nb_grp) {
    k_dist<64><<<dim3(NPTS / 128, NPTS / 128, nb_grp), 256, 0, stream>>>(
        x1 + (size_t)b0 * NPTS * 64, dist);
    k_topk<<<dim3(NPTS / 4, nb_grp), 256, 0, stream>>>(dist,
                                                       knn + (size_t)b0 * NPTS * KNN);
  }
  k_t0<64, 64><<<dim3(NBATCH * NPTS / 128, 1), 256, 0, stream>>>(x1, w2, t0buf);
  k_edge_mfma<64, 64><<<NBATCH * NPTS / 2, 256, 0, stream>>>(x1, knn, w2h, w2l, t0buf,
                                                             g2, b2, x2);

  // ---- edge conv 3 (C=64 -> O=128)
  for (int b0 = 0; b0 < NBATCH; b0 += nb_grp) {
    k_dist<64><<<dim3(NPTS / 128, NPTS / 128, nb_grp), 256, 0, stream>>>(
        x2 + (size_t)b0 * NPTS * 64, dist);
    k_topk<<<dim3(NPTS / 4, nb_grp), 256, 0, stream>>>(dist,
                                                       knn + (size_t)b0 * NPTS * KNN);
  }
  k_t0<64, 128><<<dim3(NBATCH * NPTS / 128, 2), 256, 0, stream>>>(x2, w3, t0buf);
  k_edge_mfma<64, 128><<<NBATCH * NPTS / 2, 256, 0, stream>>>(x2, knn, w3h, w3l, t0buf,
                                                              g3, b3, x3);

  // ---- edge conv 4 (C=128 -> O=256)
  for (int b0 = 0; b0 < NBATCH; b0 += nb_grp) {
    k_dist<128><<<dim3(NPTS / 128, NPTS / 128, nb_grp), 256, 0, stream>>>(
        x3 + (size_t)b0 * NPTS * 128, dist);
    k_topk<<<dim3(NPTS / 4, nb_grp), 256, 0, stream>>>(dist,
                                                       knn + (size_t)b0 * NPTS * KNN);
  }
  k_t0<128, 256><<<dim3(NBATCH * NPTS / 128, 4), 256, 0, stream>>>(x3, w4, t0buf);
  k_edge_mfma<128, 256><<<NBATCH * NPTS / 2, 256, 0, stream>>>(x3, knn, w4h, w4l, t0buf,
                                                               g4, b4, x4);

  // ---- point MLP (split-bf16 MFMA GEMM) + pooling + head
  k_aprep<<<(16 * 1024 * 64 + 255) / 256, 256, 0, stream>>>(x1, x2, x3, x4, a5h, a5l);
  k_mlp5<<<dim3(NBATCH * NPTS / 128, 8), 256, 0, stream>>>(a5h, a5l, w5h, w5l, g5, b5,
                                                           pmax, psum);
  k_pool<<<(NBATCH * 1024 + 255) / 256, 256, 0, stream>>>(pmax, psum, pooled);
  k_head<<<NBATCH, 256, 0, stream>>>(pooled, wl1, g6, b6, wl2, bl2, g7, b7, wl3, bl3,
                                     (float*)d_out);
}

// Round 14
// 1242.922 us; speedup vs baseline: 7.0189x; 2.4285x over previous
//
#include <hip/hip_runtime.h>
#include <cstddef>
#include <cstdint>

#define NBATCH 8
#define NPTS   2048
#define KNN    20

typedef __attribute__((ext_vector_type(8))) short short8;
typedef __attribute__((ext_vector_type(4))) float f32x4;

__device__ __forceinline__ unsigned short f2bf(float f) {
  unsigned u = __float_as_uint(f);
  u += 0x7fff + ((u >> 16) & 1);   // round-to-nearest-even
  return (unsigned short)(u >> 16);
}
__device__ __forceinline__ float bf2f(unsigned short h) {
  return __uint_as_float(((unsigned)h) << 16);
}

// ---------------------------------------------------------------------------
// wave-level exact top-20 over 2048 candidates: lane holds 32 values,
// global index of v[slot] on lane l is slot*64 + l. One wave per row.
// Tie-break: lowest index (ascending slot strict >, explicit idx compares).
// ---------------------------------------------------------------------------
__device__ __forceinline__ void wave_top20(float (&v)[32], int lane,
                                           int* __restrict__ row_out) {
  float bv = v[0];
  int bl = 0;
#pragma unroll
  for (int i = 1; i < 32; i++)
    if (v[i] > bv) { bv = v[i]; bl = i; }

  int keep = 0;
  for (int k = 0; k < KNN; k++) {
    float rv = bv;
    int ri = bl * 64 + lane;
#pragma unroll
    for (int off = 32; off > 0; off >>= 1) {
      float ov = __shfl_down(rv, off);
      int oi = __shfl_down(ri, off);
      if (ov > rv || (ov == rv && oi < ri)) { rv = ov; ri = oi; }
    }
    int wi = __shfl(ri, 0);
    if (lane == k) keep = wi;
    if ((wi & 63) == lane) {
      int slot = wi >> 6;
#pragma unroll
      for (int i = 0; i < 32; i++)
        if (i == slot) v[i] = -3.0e38f;
      bv = v[0]; bl = 0;
#pragma unroll
      for (int i = 1; i < 32; i++)
        if (v[i] > bv) { bv = v[i]; bl = i; }
    }
  }
  if (lane < KNN) row_out[lane] = keep;
}

// ---------------------------------------------------------------------------
// transpose (B,3,N) -> (B,N,3)
// ---------------------------------------------------------------------------
__global__ void k_transpose(const float* __restrict__ x, float* __restrict__ h0) {
  int i = blockIdx.x * 256 + threadIdx.x;
  if (i >= NBATCH * NPTS * 3) return;
  int c = i % 3;
  int n = (i / 3) % NPTS;
  int b = i / (3 * NPTS);
  h0[i] = x[((size_t)b * 3 + c) * NPTS + n];
}

// ---------------------------------------------------------------------------
// pairwise "distance" pd = 2*dot - sq_n - sq_m. blockIdx.z = batch in group.
// R11-proven 64x64 tile / 4x4 microtile (88 VGPR, 0 conflicts), now on the
// UPPER-TRIANGULAR tile grid only (528 of 1024 blocks): pd is symmetric and
// the computed value is bit-identical across the diagonal (commuted products,
// same c-ascending sum order, same sq terms), so off-diagonal blocks write
// the mirrored tile too via an LDS bounce through the then-dead rows buffer.
// NOTE (R12/R13 lesson): no 8x8 microtile, no waves/EU pin -- both spilled.
// ---------------------------------------------------------------------------
template <int C>
__global__ __launch_bounds__(256) void k_dist(const float* __restrict__ xg,
                                              float* __restrict__ dist) {
  constexpr int PAD = 4;
  constexpr int S = C + PAD;
  constexpr int TS = 67;   // transpose-bounce stride: gcd(67,32)=1 -> ~2-way
  __shared__ __attribute__((aligned(16))) float rows[64 * S];
  __shared__ __attribute__((aligned(16))) float cols[64 * S];
  __shared__ float sq[128];

  const float* xb = xg + (size_t)blockIdx.z * NPTS * C;
  float* db = dist + (size_t)blockIdx.z * NPTS * NPTS;

  // decode upper-triangular pair (rt <= ct) from linear block id
  constexpr int T = NPTS / 64;   // 32
  int bid = blockIdx.x;
  int rt = 0;
  while (bid >= T - rt) { bid -= T - rt; rt++; }
  const int ct = rt + bid;

  const int tid = threadIdx.x;

  for (int e = tid; e < 64 * C; e += 256) {
    int i = e / C, c = e - i * C;
    rows[i * S + c] = xb[(size_t)(rt * 64 + i) * C + c];
    cols[i * S + c] = xb[(size_t)(ct * 64 + i) * C + c];
  }
  __syncthreads();
  if (tid < 128) {
    const float* p = (tid < 64) ? (rows + tid * S) : (cols + (tid - 64) * S);
    float s = 0.f;
    for (int c = 0; c < C; c++) s += p[c] * p[c];
    sq[tid] = s;
  }
  __syncthreads();

  const int r0 = (tid >> 4) * 4;
  const int c0 = tid & 15;   // cols c0 + 16*j  (bank-spread)
  float acc[4][4] = {};

  for (int c = 0; c < C; c += 4) {
    float4 ra[4], cb[4];
#pragma unroll
    for (int i = 0; i < 4; i++) ra[i] = *(const float4*)&rows[(r0 + i) * S + c];
#pragma unroll
    for (int j = 0; j < 4; j++) cb[j] = *(const float4*)&cols[(c0 + 16 * j) * S + c];
#pragma unroll
    for (int i = 0; i < 4; i++)
#pragma unroll
      for (int j = 0; j < 4; j++)
        acc[i][j] += ra[i].x * cb[j].x + ra[i].y * cb[j].y +
                     ra[i].z * cb[j].z + ra[i].w * cb[j].w;
  }

  float pd[4][4];
#pragma unroll
  for (int i = 0; i < 4; i++) {
    float sr = sq[r0 + i];
#pragma unroll
    for (int j = 0; j < 4; j++)
      pd[i][j] = 2.f * acc[i][j] - sr - sq[64 + c0 + 16 * j];
  }

  // direct tile (R11 store pattern)
#pragma unroll
  for (int i = 0; i < 4; i++)
#pragma unroll
    for (int j = 0; j < 4; j++)
      db[(size_t)(rt * 64 + r0 + i) * NPTS + ct * 64 + c0 + 16 * j] = pd[i][j];

  if (rt != ct) {
    __syncthreads();              // rows[] dead after MAC loop -> reuse as tb
    float* tb = rows;
#pragma unroll
    for (int i = 0; i < 4; i++)
#pragma unroll
      for (int j = 0; j < 4; j++)
        tb[(c0 + 16 * j) * TS + r0 + i] = pd[i][j];
    __syncthreads();
#pragma unroll
    for (int i = 0; i < 4; i++)
#pragma unroll
      for (int j = 0; j < 4; j++)
        db[(size_t)(ct * 64 + r0 + i) * NPTS + rt * 64 + c0 + 16 * j] =
            tb[(r0 + i) * TS + c0 + 16 * j];
  }
}

// ---------------------------------------------------------------------------
// top-20 per row from materialized dist. One wave per row, 4 rows per block.
// ---------------------------------------------------------------------------
__global__ __launch_bounds__(256) void k_topk(const float* __restrict__ dist,
                                              int* __restrict__ idx_out) {
  const int wid = threadIdx.x >> 6;
  const int lane = threadIdx.x & 63;
  const int n = blockIdx.x * 4 + wid;
  const int z = blockIdx.y;
  const float* drow = dist + ((size_t)z * NPTS + n) * NPTS;
  int* row_out = idx_out + ((size_t)z * NPTS + n) * KNN;

  float v[32];
#pragma unroll
  for (int i = 0; i < 32; i++) v[i] = drow[i * 64 + lane];

  wave_top20(v, lane, row_out);
}

// ---------------------------------------------------------------------------
// conv1 fused kNN (C=3): one wave per row, register recompute + wave_top20.
// ---------------------------------------------------------------------------
__global__ __launch_bounds__(256) void k_knn3(const float* __restrict__ x,
                                              int* __restrict__ idx_out) {
  const int wid = threadIdx.x >> 6;
  const int lane = threadIdx.x & 63;
  const int n = blockIdx.x * 4 + wid;
  const int b = blockIdx.y;
  const float* xb = x + (size_t)b * NPTS * 3;
  int* row_out = idx_out + ((size_t)b * NPTS + n) * KNN;

  const float qx = xb[n * 3 + 0], qy = xb[n * 3 + 1], qz = xb[n * 3 + 2];
  float qsq = 0.f;
  qsq += qx * qx; qsq += qy * qy; qsq += qz * qz;

  float v[32];
#pragma unroll
  for (int i = 0; i < 32; i++) {
    int m = i * 64 + lane;
    float cx = xb[m * 3 + 0], cy = xb[m * 3 + 1], cz = xb[m * 3 + 2];
    float csq = 0.f;
    csq += cx * cx; csq += cy * cy; csq += cz * cz;
    float acc = 0.f;
    acc += qx * cx; acc += qy * cy; acc += qz * cz;
    v[i] = 2.f * acc - qsq - csq;
  }

  wave_top20(v, lane, row_out);
}

// ---------------------------------------------------------------------------
// t0 GEMM: t0buf[n, o] = sum_c x[n, c] * w[C+c, o]   (center @ w_hi)
// ---------------------------------------------------------------------------
template <int C, int O>
__global__ __launch_bounds__(256) void k_t0(const float* __restrict__ x,
                                            const float* __restrict__ w,
                                            float* __restrict__ t0buf) {
  constexpr int TM = 128, TN = 64, TK = 16;
  __shared__ __attribute__((aligned(16))) float As[TK][TM + 4];
  __shared__ __attribute__((aligned(16))) float Bs[TK][TN + 4];
  const int mt = blockIdx.x, nt = blockIdx.y;
  const int tid = threadIdx.x;
  const int tx = tid & 15, ty = tid >> 4;
  const size_t m0 = (size_t)mt * TM;
  const int n0 = nt * TN;
  float acc[8][4] = {};

  for (int kt = 0; kt < C; kt += TK) {
#pragma unroll
    for (int e = 0; e < 8; e++) {
      int idx = tid + e * 256;
      int m = idx >> 4, k = idx & 15;
      As[k][m] = x[(m0 + m) * C + kt + k];
    }
#pragma unroll
    for (int e = 0; e < 4; e++) {
      int idx = tid + e * 256;
      int k = idx >> 6, nn = idx & 63;
      Bs[k][nn] = w[(size_t)(C + kt + k) * O + n0 + nn];
    }
    __syncthreads();
#pragma unroll
    for (int kk = 0; kk < TK; kk++) {
      float4 a0 = *(const float4*)&As[kk][ty * 8];
      float4 a1 = *(const float4*)&As[kk][ty * 8 + 4];
      float4 b0 = *(const float4*)&Bs[kk][tx * 4];
      float av[8] = {a0.x, a0.y, a0.z, a0.w, a1.x, a1.y, a1.z, a1.w};
      float bb[4] = {b0.x, b0.y, b0.z, b0.w};
#pragma unroll
      for (int i = 0; i < 8; i++)
#pragma unroll
        for (int j = 0; j < 4; j++) acc[i][j] += av[i] * bb[j];
    }
    __syncthreads();
  }
#pragma unroll
  for (int i = 0; i < 8; i++)
#pragma unroll
    for (int j = 0; j < 4; j++)
      t0buf[(m0 + ty * 8 + i) * O + n0 + tx * 4 + j] = acc[i][j];
}

// ---------------------------------------------------------------------------
// weight -> bf16 hi/lo split in 16x16x32 B-fragment order.
// ---------------------------------------------------------------------------
template <int C, int O>
__global__ void k_wprep(const float* __restrict__ w,
                        unsigned short* __restrict__ whi,
                        unsigned short* __restrict__ wlo) {
  int e = blockIdx.x * 256 + threadIdx.x;
  if (e >= C * O) return;
  constexpr int NT = O / 16;
  int j = e & 7;
  int slot = e >> 3;
  int lane = slot & 63;
  int t2 = slot >> 6;
  int nt = t2 % NT, kb = t2 / NT;
  int k = kb * 32 + ((lane >> 4) & 3) * 8 + j;
  int n = nt * 16 + (lane & 15);
  float v = w[(size_t)k * O + n];
  unsigned short h = f2bf(v);
  unsigned short l = f2bf(v - bf2f(h));
  whi[e] = h;
  wlo[e] = l;
}

// ---------------------------------------------------------------------------
// feature matrix -> bf16 hi/lo split in 16x16x32 A-fragment order for mlp5.
// ---------------------------------------------------------------------------
__global__ void k_aprep(const float* __restrict__ x1, const float* __restrict__ x2,
                        const float* __restrict__ x3, const float* __restrict__ x4,
                        unsigned short* __restrict__ ah, unsigned short* __restrict__ al) {
  int e8 = blockIdx.x * 256 + threadIdx.x;   // 16 kb * 1024 mtg * 64 lanes
  if (e8 >= 16 * 1024 * 64) return;
  int lane = e8 & 63;
  int mtg = (e8 >> 6) & 1023;
  int kb = e8 >> 16;
  int m = mtg * 16 + (lane & 15);
  int k0 = kb * 32 + ((lane >> 4) & 3) * 8;
  const float* p;
  if (k0 < 64)       p = &x1[(size_t)m * 64 + k0];
  else if (k0 < 128) p = &x2[(size_t)m * 64 + (k0 - 64)];
  else if (k0 < 256) p = &x3[(size_t)m * 128 + (k0 - 128)];
  else               p = &x4[(size_t)m * 256 + (k0 - 256)];
  float4 f0 = *(const float4*)p;
  float4 f1 = *(const float4*)(p + 4);
  float fv[8] = {f0.x, f0.y, f0.z, f0.w, f1.x, f1.y, f1.z, f1.w};
  short8 h8, l8;
#pragma unroll
  for (int j = 0; j < 8; j++) {
    unsigned short h = f2bf(fv[j]);
    unsigned short l = f2bf(fv[j] - bf2f(h));
    h8[j] = (short)h;
    l8[j] = (short)l;
  }
  *(short8*)&ah[(size_t)e8 * 8] = h8;
  *(short8*)&al[(size_t)e8 * 8] = l8;
}

// ---------------------------------------------------------------------------
// MFMA edge conv (C in {64,128}): per block 2 points, 32 padded neighbor rows.
// Split bf16: D ~= AhBh + AhBl + AlBh.
// ---------------------------------------------------------------------------
template <int C, int O>
__global__ __launch_bounds__(256) void k_edge_mfma(
    const float* __restrict__ x, const int* __restrict__ knn,
    const unsigned short* __restrict__ whi, const unsigned short* __restrict__ wlo,
    const float* __restrict__ t0buf, const float* __restrict__ g,
    const float* __restrict__ bta, float* __restrict__ out) {
  constexpr int KB = C / 32;
  constexpr int NT = O / 16;
  constexpr int NTW = NT / 2;
  __shared__ unsigned short Ah[2 * 2 * KB * 512];
  __shared__ unsigned short Al[2 * 2 * KB * 512];

  const int blk = blockIdx.x;
  const int b = blk / (NPTS / 2);
  const int n0 = (blk % (NPTS / 2)) * 2;
  const int tid = threadIdx.x;
  const int lane = tid & 63;
  const int wid = tid >> 6;
  const int pt = wid >> 1;
  const int nsl = wid & 1;
  const int ptg = b * NPTS + n0 + pt;
  const float* xb = x + (size_t)b * NPTS * C;
  const int kbase = ptg * KNN;

  if constexpr (C == 128) {
    const float2 ctr2 = *(const float2*)&xb[(size_t)(n0 + pt) * C + lane * 2];
    const int kb = lane >> 4;
    const int q = (lane >> 2) & 3;
    const int j2 = 2 * (lane & 3);
#pragma unroll
    for (int i = 0; i < 16; i++) {
      int r = 2 * i + nsl;
      unsigned hp = 0, lp = 0;
      if (r < KNN) {
        int m = knn[kbase + r];
        float2 v = *(const float2*)&xb[(size_t)m * C + lane * 2];
        float d0 = v.x - ctr2.x, d1 = v.y - ctr2.y;
        unsigned short h0 = f2bf(d0), h1 = f2bf(d1);
        unsigned short l0 = f2bf(d0 - bf2f(h0)), l1 = f2bf(d1 - bf2f(h1));
        hp = (unsigned)h0 | ((unsigned)h1 << 16);
        lp = (unsigned)l0 | ((unsigned)l1 << 16);
      }
      int mt = r >> 4, row = r & 15;
      int L = row + 16 * q;
      int phys = L ^ ((4 * kb + q) & 15);
      int idx = ((pt * 2 + mt) * KB + kb) * 512 + phys * 8 + j2;
      *(unsigned*)&Ah[idx] = hp;
      *(unsigned*)&Al[idx] = lp;
    }
  } else {
    const float ctrv = xb[(size_t)(n0 + pt) * C + lane];
    const int kb = lane >> 5;
    const int q = (lane >> 3) & 3;
    const int j = lane & 7;
#pragma unroll
    for (int i = 0; i < 16; i++) {
      int r = 2 * i + nsl;
      unsigned short h = 0, l = 0;
      if (r < KNN) {
        int m = knn[kbase + r];
        float d = xb[(size_t)m * C + lane] - ctrv;
        h = f2bf(d);
        l = f2bf(d - bf2f(h));
      }
      int mt = r >> 4, row = r & 15;
      int L = row + 16 * q;
      int phys = L ^ ((4 * kb + q) & 15);
      int idx = ((pt * 2 + mt) * KB + kb) * 512 + phys * 8 + j;
      Ah[idx] = h;
      Al[idx] = l;
    }
  }
  __syncthreads();

  f32x4 acc[2][NTW];
#pragma unroll
  for (int mt = 0; mt < 2; mt++)
#pragma unroll
    for (int t = 0; t < NTW; t++) acc[mt][t] = (f32x4){0.f, 0.f, 0.f, 0.f};

#pragma unroll
  for (int kb = 0; kb < KB; kb++) {
    int phys = lane ^ ((4 * kb + (lane >> 4)) & 15);
    short8 ah[2], al[2];
#pragma unroll
    for (int mt = 0; mt < 2; mt++) {
      int idx = ((pt * 2 + mt) * KB + kb) * 512 + phys * 8;
      ah[mt] = *(const short8*)&Ah[idx];
      al[mt] = *(const short8*)&Al[idx];
    }
#pragma unroll
    for (int t = 0; t < NTW; t++) {
      int nt = nsl * NTW + t;
      size_t widx = ((size_t)(kb * NT + nt) * 64 + lane) * 8;
      short8 bh = *(const short8*)&whi[widx];
      short8 bl = *(const short8*)&wlo[widx];
#pragma unroll
      for (int mt = 0; mt < 2; mt++) {
        acc[mt][t] = __builtin_amdgcn_mfma_f32_16x16x32_bf16(ah[mt], bh, acc[mt][t], 0, 0, 0);
        acc[mt][t] = __builtin_amdgcn_mfma_f32_16x16x32_bf16(ah[mt], bl, acc[mt][t], 0, 0, 0);
        acc[mt][t] = __builtin_amdgcn_mfma_f32_16x16x32_bf16(al[mt], bh, acc[mt][t], 0, 0, 0);
      }
    }
  }

#pragma unroll
  for (int t = 0; t < NTW; t++) {
    int o = (nsl * NTW + t) * 16 + (lane & 15);
    float tv = t0buf[(size_t)ptg * O + o];
    float gv = g[o], bv = bta[o];
    float m = -3.0e38f;
#pragma unroll
    for (int mt = 0; mt < 2; mt++)
#pragma unroll
      for (int r = 0; r < 4; r++) {
        float h = (acc[mt][t][r] + tv) * gv + bv;
        h = (h >= 0.f) ? h : 0.2f * h;
        m = fmaxf(m, h);
      }
    m = fmaxf(m, __shfl_xor(m, 16));
    m = fmaxf(m, __shfl_xor(m, 32));
    if (lane < 16) out[(size_t)ptg * O + o] = m;
  }
}

// ---------------------------------------------------------------------------
// fp32 edge conv -- retained for conv1 (C=3) only.
// ---------------------------------------------------------------------------
template <int C, int O>
__global__ __launch_bounds__(256) void k_edge(const float* __restrict__ x,
                                              const int* __restrict__ knn,
                                              const float* __restrict__ w,
                                              const float* __restrict__ g,
                                              const float* __restrict__ bta,
                                              float* __restrict__ out) {
  constexpr int JO = O / 64;
  constexpr int NPB = 4;
  __shared__ __attribute__((aligned(16))) float nbd[NPB * KNN * C];

  const int blk = blockIdx.x;
  const int b = blk / (NPTS / NPB);
  const int n0 = (blk % (NPTS / NPB)) * NPB;
  const int tid = threadIdx.x;
  const int lane = tid & 63;
  const int p = tid >> 6;
  const float* xb = x + (size_t)b * NPTS * C;

  const int kbase = (b * NPTS + n0 + p) * KNN;
  float* nb_p = nbd + p * KNN * C;
  int midx[KNN];
#pragma unroll
  for (int k = 0; k < KNN; k++) midx[k] = knn[kbase + k];

  float cv0 = 0.f;
  if (lane < C) cv0 = xb[(size_t)(n0 + p) * C + lane];
  float vv[KNN];
#pragma unroll
  for (int k = 0; k < KNN; k++)
    vv[k] = (lane < C) ? xb[(size_t)midx[k] * C + lane] : 0.f;
#pragma unroll
  for (int k = 0; k < KNN; k++)
    if (lane < C) nb_p[k * C + lane] = vv[k] - cv0;

  float acc[KNN][JO];
  {
    float t0[JO];
#pragma unroll
    for (int j = 0; j < JO; j++) t0[j] = 0.f;
    for (int c = 0; c < C; c++) {
      float cc = __shfl(cv0, c);
#pragma unroll
      for (int j = 0; j < JO; j++)
        t0[j] += cc * w[(size_t)(C + c) * O + j * 64 + lane];
    }
#pragma unroll
    for (int k = 0; k < KNN; k++)
#pragma unroll
      for (int j = 0; j < JO; j++) acc[k][j] = t0[j];
  }

  for (int c = 0; c < C; c++) {
    float wv[JO];
#pragma unroll
    for (int j = 0; j < JO; j++) wv[j] = w[(size_t)c * O + j * 64 + lane];
#pragma unroll
    for (int k = 0; k < KNN; k++) {
      float f = nb_p[k * C + c];
#pragma unroll
      for (int j = 0; j < JO; j++) acc[k][j] += f * wv[j];
    }
  }

#pragma unroll
  for (int j = 0; j < JO; j++) {
    const float gv = g[j * 64 + lane], bv = bta[j * 64 + lane];
    float mx = -3.0e38f;
#pragma unroll
    for (int k = 0; k < KNN; k++) {
      float h = acc[k][j] * gv + bv;
      h = (h >= 0.f) ? h : 0.2f * h;
      mx = fmaxf(mx, h);
    }
    out[(size_t)(b * NPTS + n0 + p) * O + j * 64 + lane] = mx;
  }
}

// ---------------------------------------------------------------------------
// point MLP 512->1024 as split-bf16 MFMA GEMM, no LDS, no barriers.
// ---------------------------------------------------------------------------
__global__ __launch_bounds__(256) void k_mlp5(const unsigned short* __restrict__ a5h,
                                              const unsigned short* __restrict__ a5l,
                                              const unsigned short* __restrict__ w5h,
                                              const unsigned short* __restrict__ w5l,
                                              const float* __restrict__ g5,
                                              const float* __restrict__ b5,
                                              float* __restrict__ pmax,
                                              float* __restrict__ psum) {
  const int mtb = blockIdx.x;   // 0..127
  const int ntb = blockIdx.y;   // 0..7
  const int tid = threadIdx.x;
  const int lane = tid & 63;
  const int nsl = tid >> 6;     // wave id 0..3

  f32x4 acc[8][2];
#pragma unroll
  for (int mt = 0; mt < 8; mt++)
#pragma unroll
    for (int t = 0; t < 2; t++) acc[mt][t] = (f32x4){0.f, 0.f, 0.f, 0.f};

  for (int kb = 0; kb < 16; kb++) {
    short8 bh[2], bl[2];
#pragma unroll
    for (int t = 0; t < 2; t++) {
      int ntg = ntb * 8 + nsl * 2 + t;
      size_t widx = ((size_t)(kb * 64 + ntg) * 64 + lane) * 8;
      bh[t] = *(const short8*)&w5h[widx];
      bl[t] = *(const short8*)&w5l[widx];
    }
#pragma unroll
    for (int mt = 0; mt < 8; mt++) {
      size_t aidx = (((size_t)kb * 1024 + mtb * 8 + mt) * 64 + lane) * 8;
      short8 ah = *(const short8*)&a5h[aidx];
      short8 al = *(const short8*)&a5l[aidx];
#pragma unroll
      for (int t = 0; t < 2; t++) {
        acc[mt][t] = __builtin_amdgcn_mfma_f32_16x16x32_bf16(ah, bh[t], acc[mt][t], 0, 0, 0);
        acc[mt][t] = __builtin_amdgcn_mfma_f32_16x16x32_bf16(ah, bl[t], acc[mt][t], 0, 0, 0);
        acc[mt][t] = __builtin_amdgcn_mfma_f32_16x16x32_bf16(al, bh[t], acc[mt][t], 0, 0, 0);
      }
    }
  }

#pragma unroll
  for (int t = 0; t < 2; t++) {
    int o = ntb * 128 + (nsl * 2 + t) * 16 + (lane & 15);
    float gv = g5[o], bv = b5[o];
    float mx = -3.0e38f, sm = 0.f;
#pragma unroll
    for (int mt = 0; mt < 8; mt++)
#pragma unroll
      for (int r = 0; r < 4; r++) {
        float h = acc[mt][t][r] * gv + bv;
        h = (h >= 0.f) ? h : 0.2f * h;
        mx = fmaxf(mx, h);
        sm += h;
      }
    mx = fmaxf(mx, __shfl_xor(mx, 16));
    mx = fmaxf(mx, __shfl_xor(mx, 32));
    sm += __shfl_xor(sm, 16);
    sm += __shfl_xor(sm, 32);
    if (lane < 16) {
      pmax[(size_t)mtb * 1024 + o] = mx;
      psum[(size_t)mtb * 1024 + o] = sm;
    }
  }
}

// ---------------------------------------------------------------------------
// reduce tile partials -> pooled (B, 2048) = [max(1024), mean(1024)]
// ---------------------------------------------------------------------------
__global__ void k_pool(const float* __restrict__ pmax, const float* __restrict__ psum,
                       float* __restrict__ pooled) {
  int i = blockIdx.x * 256 + threadIdx.x;
  if (i >= NBATCH * 1024) return;
  int b = i / 1024, e = i - b * 1024;
  constexpr int NT = NPTS / 128;
  float mx = -3.0e38f, sm = 0.f;
  for (int t = 0; t < NT; t++) {
    mx = fmaxf(mx, pmax[((size_t)b * NT + t) * 1024 + e]);
    sm += psum[((size_t)b * NT + t) * 1024 + e];
  }
  pooled[(size_t)b * 2048 + e] = mx;
  pooled[(size_t)b * 2048 + 1024 + e] = sm * (1.0f / NPTS);
}

// ---------------------------------------------------------------------------
// FC head: 2048->512 (leaky, affine) -> 256 (bias, leaky, affine) -> 40 (+bias)
// ---------------------------------------------------------------------------
__global__ __launch_bounds__(256) void k_head(const float* __restrict__ pooled,
                                              const float* __restrict__ wl1,
                                              const float* __restrict__ g6,
                                              const float* __restrict__ b6,
                                              const float* __restrict__ wl2,
                                              const float* __restrict__ bl2,
                                              const float* __restrict__ g7,
                                              const float* __restrict__ b7,
                                              const float* __restrict__ wl3,
                                              const float* __restrict__ bl3,
                                              float* __restrict__ out) {
  const int b = blockIdx.x;
  const int tid = threadIdx.x;
  __shared__ float pl[2048];
  __shared__ float h1[512];
  __shared__ float h2[256];

  for (int i = tid; i < 2048; i += 256) pl[i] = pooled[(size_t)b * 2048 + i];
  __syncthreads();

  for (int o = tid; o < 512; o += 256) {
    float a = 0.f;
    for (int c = 0; c < 2048; c++) a += pl[c] * wl1[(size_t)c * 512 + o];
    a = a * g6[o] + b6[o];
    h1[o] = (a >= 0.f) ? a : 0.2f * a;
  }
  __syncthreads();

  {
    float a = 0.f;
    for (int c = 0; c < 512; c++) a += h1[c] * wl2[(size_t)c * 256 + tid];
    a = (a + bl2[tid]) * g7[tid] + b7[tid];
    h2[tid] = (a >= 0.f) ? a : 0.2f * a;
  }
  __syncthreads();

  if (tid < 40) {
    float a = bl3[tid];
    for (int c = 0; c < 256; c++) a += h2[c] * wl3[(size_t)c * 40 + tid];
    out[(size_t)b * 40 + tid] = a;
  }
}

// ---------------------------------------------------------------------------
extern "C" void kernel_launch(void* const* d_in, const int* in_sizes, int n_in,
                              void* d_out, int out_size, void* d_ws, size_t ws_size,
                              hipStream_t stream) {
  (void)in_sizes; (void)n_in; (void)out_size;
  const float* x   = (const float*)d_in[0];
  const float* w1  = (const float*)d_in[1];
  const float* g1  = (const float*)d_in[2];
  const float* b1  = (const float*)d_in[3];
  const float* w2  = (const float*)d_in[4];
  const float* g2  = (const float*)d_in[5];
  const float* b2  = (const float*)d_in[6];
  const float* w3  = (const float*)d_in[7];
  const float* g3  = (const float*)d_in[8];
  const float* b3  = (const float*)d_in[9];
  const float* w4  = (const float*)d_in[10];
  const float* g4  = (const float*)d_in[11];
  const float* b4  = (const float*)d_in[12];
  const float* w5  = (const float*)d_in[13];
  const float* g5  = (const float*)d_in[14];
  const float* b5  = (const float*)d_in[15];
  const float* wl1 = (const float*)d_in[16];
  const float* g6  = (const float*)d_in[17];
  const float* b6  = (const float*)d_in[18];
  const float* wl2 = (const float*)d_in[19];
  const float* bl2 = (const float*)d_in[20];
  const float* g7  = (const float*)d_in[21];
  const float* b7  = (const float*)d_in[22];
  const float* wl3 = (const float*)d_in[23];
  const float* bl3 = (const float*)d_in[24];

  float* ws = (float*)d_ws;
  size_t off = 0;
  float* h0 = ws + off;   off += (size_t)NBATCH * NPTS * 3;
  float* x1 = ws + off;   off += (size_t)NBATCH * NPTS * 64;
  float* x2 = ws + off;   off += (size_t)NBATCH * NPTS * 64;
  float* x3 = ws + off;   off += (size_t)NBATCH * NPTS * 128;
  float* x4 = ws + off;   off += (size_t)NBATCH * NPTS * 256;
  int* knn = (int*)(ws + off); off += (size_t)NBATCH * NPTS * KNN;
  float* pmax = ws + off; off += (size_t)(NPTS / 128) * NBATCH * 1024;
  float* psum = ws + off; off += (size_t)(NPTS / 128) * NBATCH * 1024;
  float* pooled = ws + off; off += (size_t)NBATCH * 2048;
  float* t0buf = ws + off;  off += (size_t)NBATCH * NPTS * 256;  // max O
  unsigned short* w2h = (unsigned short*)(ws + off); off += 64 * 64 / 2 * 2;
  unsigned short* w2l = w2h + 64 * 64;
  unsigned short* w3h = (unsigned short*)(ws + off); off += 64 * 128 / 2 * 2;
  unsigned short* w3l = w3h + 64 * 128;
  unsigned short* w4h = (unsigned short*)(ws + off); off += 128 * 256 / 2 * 2;
  unsigned short* w4l = w4h + 128 * 256;
  unsigned short* w5h = (unsigned short*)(ws + off); off += 512 * 1024 / 2 * 2;
  unsigned short* w5l = w5h + 512 * 1024;
  unsigned short* a5h = (unsigned short*)(ws + off); off += (size_t)16384 * 512 / 2 * 2;
  unsigned short* a5l = a5h + (size_t)16384 * 512;
  float* dist = ws + off;  // adaptive: nb_grp * NPTS * NPTS floats, placed last

  size_t avail = ws_size / 4 - off;
  int nb_grp = 8;
  while (nb_grp > 1 && (size_t)nb_grp * NPTS * NPTS > avail) nb_grp >>= 1;

  constexpr int NTRI = (NPTS / 64) * (NPTS / 64 + 1) / 2;  // 528

  k_transpose<<<(NBATCH * NPTS * 3 + 255) / 256, 256, 0, stream>>>(x, h0);

  // weight hi/lo fragment prep (depends only on inputs -- run up front)
  k_wprep<64, 64><<<(64 * 64 + 255) / 256, 256, 0, stream>>>(w2, w2h, w2l);
  k_wprep<64, 128><<<(64 * 128 + 255) / 256, 256, 0, stream>>>(w3, w3h, w3l);
  k_wprep<128, 256><<<(128 * 256 + 255) / 256, 256, 0, stream>>>(w4, w4h, w4l);
  k_wprep<512, 1024><<<(512 * 1024 + 255) / 256, 256, 0, stream>>>(w5, w5h, w5l);

  // ---- edge conv 1 (C=3 -> O=64): fused register kNN (wave/row) + fp32 edge
  k_knn3<<<dim3(NPTS / 4, NBATCH), 256, 0, stream>>>(h0, knn);
  k_edge<3, 64><<<NBATCH * NPTS / 4, 256, 0, stream>>>(h0, knn, w1, g1, b1, x1);

  // ---- edge conv 2 (C=64 -> O=64)
  for (int b0 = 0; b0 < NBATCH; b0 += nb_grp) {
    k_dist<64><<<dim3(NTRI, 1, nb_grp), 256, 0, stream>>>(
        x1 + (size_t)b0 * NPTS * 64, dist);
    k_topk<<<dim3(NPTS / 4, nb_grp), 256, 0, stream>>>(dist,
                                                       knn + (size_t)b0 * NPTS * KNN);
  }
  k_t0<64, 64><<<dim3(NBATCH * NPTS / 128, 1), 256, 0, stream>>>(x1, w2, t0buf);
  k_edge_mfma<64, 64><<<NBATCH * NPTS / 2, 256, 0, stream>>>(x1, knn, w2h, w2l, t0buf,
                                                             g2, b2, x2);

  // ---- edge conv 3 (C=64 -> O=128)
  for (int b0 = 0; b0 < NBATCH; b0 += nb_grp) {
    k_dist<64><<<dim3(NTRI, 1, nb_grp), 256, 0, stream>>>(
        x2 + (size_t)b0 * NPTS * 64, dist);
    k_topk<<<dim3(NPTS / 4, nb_grp), 256, 0, stream>>>(dist,
                                                       knn + (size_t)b0 * NPTS * KNN);
  }
  k_t0<64, 128><<<dim3(NBATCH * NPTS / 128, 2), 256, 0, stream>>>(x2, w3, t0buf);
  k_edge_mfma<64, 128><<<NBATCH * NPTS / 2, 256, 0, stream>>>(x2, knn, w3h, w3l, t0buf,
                                                              g3, b3, x3);

  // ---- edge conv 4 (C=128 -> O=256)
  for (int b0 = 0; b0 < NBATCH; b0 += nb_grp) {
    k_dist<128><<<dim3(NTRI, 1, nb_grp), 256, 0, stream>>>(
        x3 + (size_t)b0 * NPTS * 128, dist);
    k_topk<<<dim3(NPTS / 4, nb_grp), 256, 0, stream>>>(dist,
                                                       knn + (size_t)b0 * NPTS * KNN);
  }
  k_t0<128, 256><<<dim3(NBATCH * NPTS / 128, 4), 256, 0, stream>>>(x3, w4, t0buf);
  k_edge_mfma<128, 256><<<NBATCH * NPTS / 2, 256, 0, stream>>>(x3, knn, w4h, w4l, t0buf,
                                                               g4, b4, x4);

  // ---- point MLP (split-bf16 MFMA GEMM) + pooling + head
  k_aprep<<<(16 * 1024 * 64 + 255) / 256, 256, 0, stream>>>(x1, x2, x3, x4, a5h, a5l);
  k_mlp5<<<dim3(NBATCH * NPTS / 128, 8), 256, 0, stream>>>(a5h, a5l, w5h, w5l, g5, b5,
                                                           pmax, psum);
  k_pool<<<(NBATCH * 1024 + 255) / 256, 256, 0, stream>>>(pmax, psum, pooled);
  k_head<<<NBATCH, 256, 0, stream>>>(pooled, wl1, g6, b6, wl2, bl2, g7, b7, wl3, bl3,
                                     (float*)d_out);
}

// Round 15
// 1172.988 us; speedup vs baseline: 7.4373x; 1.0596x over previous
//
#include <hip/hip_runtime.h>
#include <cstddef>
#include <cstdint>

#define NBATCH 8
#define NPTS   2048
#define KNN    20

typedef __attribute__((ext_vector_type(8))) short short8;
typedef __attribute__((ext_vector_type(4))) float f32x4;

__device__ __forceinline__ unsigned short f2bf(float f) {
  unsigned u = __float_as_uint(f);
  u += 0x7fff + ((u >> 16) & 1);   // round-to-nearest-even
  return (unsigned short)(u >> 16);
}
__device__ __forceinline__ float bf2f(unsigned short h) {
  return __uint_as_float(((unsigned)h) << 16);
}

// ---------------------------------------------------------------------------
// wave-level exact top-20 over 2048 candidates: lane holds 32 values,
// global index of v[slot] on lane l is slot*64 + l. One wave per row.
// Per-lane TOP-2 CACHE with lazy refill: a win promotes the cached 2nd in
// O(1); the 32-slot rescan runs only when the same lane wins twice since its
// last refill (expected ~3x/row vs 20x full rescans before -- the rescan
// executes exec-masked across the whole wave, so it costs issue slots even
// with one active lane). Tie-break identical to full-rescan: ascending-slot
// strict > keeps lowest index per lane; cross-lane (value desc, index asc).
// ---------------------------------------------------------------------------
__device__ __forceinline__ void wave_top20(float (&v)[32], int lane,
                                           int* __restrict__ row_out) {
  float m1 = -3.0e38f, m2 = -3.0e38f;
  int i1 = 0, i2 = 0;
#pragma unroll
  for (int i = 0; i < 32; i++) {
    float x = v[i];
    if (x > m1) { m2 = m1; i2 = i1; m1 = x; i1 = i; }
    else if (x > m2) { m2 = x; i2 = i; }
  }

  unsigned dm = 0;   // deleted-slot mask (this lane's consumed winners)
  int cnt = 2;       // valid cached entries
  int keep = 0;
  for (int k = 0; k < KNN; k++) {
    float rv = m1;
    int ri = i1 * 64 + lane;
#pragma unroll
    for (int off = 32; off > 0; off >>= 1) {
      float ov = __shfl_down(rv, off);
      int oi = __shfl_down(ri, off);
      if (ov > rv || (ov == rv && oi < ri)) { rv = ov; ri = oi; }
    }
    int wi = __shfl(ri, 0);
    if (lane == k) keep = wi;
    if ((wi & 63) == lane) {
      dm |= 1u << (wi >> 6);
      if (cnt == 2) {          // promote cached second (true new max)
        m1 = m2; i1 = i2; cnt = 1;
      } else {                 // cache empty: refill top-2 of survivors
        m1 = -3.0e38f; i1 = 0; m2 = -3.0e38f; i2 = 0;
#pragma unroll
        for (int i = 0; i < 32; i++)
          if (!((dm >> i) & 1)) {
            float x = v[i];
            if (x > m1) { m2 = m1; i2 = i1; m1 = x; i1 = i; }
            else if (x > m2) { m2 = x; i2 = i; }
          }
        cnt = 2;
      }
    }
  }
  if (lane < KNN) row_out[lane] = keep;
}

// ---------------------------------------------------------------------------
// transpose (B,3,N) -> (B,N,3)
// ---------------------------------------------------------------------------
__global__ void k_transpose(const float* __restrict__ x, float* __restrict__ h0) {
  int i = blockIdx.x * 256 + threadIdx.x;
  if (i >= NBATCH * NPTS * 3) return;
  int c = i % 3;
  int n = (i / 3) % NPTS;
  int b = i / (3 * NPTS);
  h0[i] = x[((size_t)b * 3 + c) * NPTS + n];
}

// ---------------------------------------------------------------------------
// pairwise "distance" pd = 2*dot - sq_n - sq_m. blockIdx.z = batch in group.
// R11-proven 64x64 tile / 4x4 microtile (88 VGPR, 0 conflicts), upper-
// triangular tile grid (528 blocks); off-diagonal blocks mirror their tile
// via an LDS bounce through the then-dead rows buffer (bit-identical values).
// NOTE (R12/R13 lesson): no 8x8 microtile, no waves/EU pin -- both spilled.
// ---------------------------------------------------------------------------
template <int C>
__global__ __launch_bounds__(256) void k_dist(const float* __restrict__ xg,
                                              float* __restrict__ dist) {
  constexpr int PAD = 4;
  constexpr int S = C + PAD;
  constexpr int TS = 67;
  __shared__ __attribute__((aligned(16))) float rows[64 * S];
  __shared__ __attribute__((aligned(16))) float cols[64 * S];
  __shared__ float sq[128];

  const float* xb = xg + (size_t)blockIdx.z * NPTS * C;
  float* db = dist + (size_t)blockIdx.z * NPTS * NPTS;

  constexpr int T = NPTS / 64;   // 32
  int bid = blockIdx.x;
  int rt = 0;
  while (bid >= T - rt) { bid -= T - rt; rt++; }
  const int ct = rt + bid;

  const int tid = threadIdx.x;

  for (int e = tid; e < 64 * C; e += 256) {
    int i = e / C, c = e - i * C;
    rows[i * S + c] = xb[(size_t)(rt * 64 + i) * C + c];
    cols[i * S + c] = xb[(size_t)(ct * 64 + i) * C + c];
  }
  __syncthreads();
  if (tid < 128) {
    const float* p = (tid < 64) ? (rows + tid * S) : (cols + (tid - 64) * S);
    float s = 0.f;
    for (int c = 0; c < C; c++) s += p[c] * p[c];
    sq[tid] = s;
  }
  __syncthreads();

  const int r0 = (tid >> 4) * 4;
  const int c0 = tid & 15;
  float acc[4][4] = {};

  for (int c = 0; c < C; c += 4) {
    float4 ra[4], cb[4];
#pragma unroll
    for (int i = 0; i < 4; i++) ra[i] = *(const float4*)&rows[(r0 + i) * S + c];
#pragma unroll
    for (int j = 0; j < 4; j++) cb[j] = *(const float4*)&cols[(c0 + 16 * j) * S + c];
#pragma unroll
    for (int i = 0; i < 4; i++)
#pragma unroll
      for (int j = 0; j < 4; j++)
        acc[i][j] += ra[i].x * cb[j].x + ra[i].y * cb[j].y +
                     ra[i].z * cb[j].z + ra[i].w * cb[j].w;
  }

  float pd[4][4];
#pragma unroll
  for (int i = 0; i < 4; i++) {
    float sr = sq[r0 + i];
#pragma unroll
    for (int j = 0; j < 4; j++)
      pd[i][j] = 2.f * acc[i][j] - sr - sq[64 + c0 + 16 * j];
  }

#pragma unroll
  for (int i = 0; i < 4; i++)
#pragma unroll
    for (int j = 0; j < 4; j++)
      db[(size_t)(rt * 64 + r0 + i) * NPTS + ct * 64 + c0 + 16 * j] = pd[i][j];

  if (rt != ct) {
    __syncthreads();
    float* tb = rows;
#pragma unroll
    for (int i = 0; i < 4; i++)
#pragma unroll
      for (int j = 0; j < 4; j++)
        tb[(c0 + 16 * j) * TS + r0 + i] = pd[i][j];
    __syncthreads();
#pragma unroll
    for (int i = 0; i < 4; i++)
#pragma unroll
      for (int j = 0; j < 4; j++)
        db[(size_t)(ct * 64 + r0 + i) * NPTS + rt * 64 + c0 + 16 * j] =
            tb[(r0 + i) * TS + c0 + 16 * j];
  }
}

// ---------------------------------------------------------------------------
// top-20 per row from materialized dist. One wave per row, 4 rows per block.
// ---------------------------------------------------------------------------
__global__ __launch_bounds__(256) void k_topk(const float* __restrict__ dist,
                                              int* __restrict__ idx_out) {
  const int wid = threadIdx.x >> 6;
  const int lane = threadIdx.x & 63;
  const int n = blockIdx.x * 4 + wid;
  const int z = blockIdx.y;
  const float* drow = dist + ((size_t)z * NPTS + n) * NPTS;
  int* row_out = idx_out + ((size_t)z * NPTS + n) * KNN;

  float v[32];
#pragma unroll
  for (int i = 0; i < 32; i++) v[i] = drow[i * 64 + lane];

  wave_top20(v, lane, row_out);
}

// ---------------------------------------------------------------------------
// conv1 fused kNN (C=3): one wave per row, register recompute + wave_top20.
// ---------------------------------------------------------------------------
__global__ __launch_bounds__(256) void k_knn3(const float* __restrict__ x,
                                              int* __restrict__ idx_out) {
  const int wid = threadIdx.x >> 6;
  const int lane = threadIdx.x & 63;
  const int n = blockIdx.x * 4 + wid;
  const int b = blockIdx.y;
  const float* xb = x + (size_t)b * NPTS * 3;
  int* row_out = idx_out + ((size_t)b * NPTS + n) * KNN;

  const float qx = xb[n * 3 + 0], qy = xb[n * 3 + 1], qz = xb[n * 3 + 2];
  float qsq = 0.f;
  qsq += qx * qx; qsq += qy * qy; qsq += qz * qz;

  float v[32];
#pragma unroll
  for (int i = 0; i < 32; i++) {
    int m = i * 64 + lane;
    float cx = xb[m * 3 + 0], cy = xb[m * 3 + 1], cz = xb[m * 3 + 2];
    float csq = 0.f;
    csq += cx * cx; csq += cy * cy; csq += cz * cz;
    float acc = 0.f;
    acc += qx * cx; acc += qy * cy; acc += qz * cz;
    v[i] = 2.f * acc - qsq - csq;
  }

  wave_top20(v, lane, row_out);
}

// ---------------------------------------------------------------------------
// t0 GEMM: t0buf[n, o] = sum_c x[n, c] * w[C+c, o]   (center @ w_hi)
// ---------------------------------------------------------------------------
template <int C, int O>
__global__ __launch_bounds__(256) void k_t0(const float* __restrict__ x,
                                            const float* __restrict__ w,
                                            float* __restrict__ t0buf) {
  constexpr int TM = 128, TN = 64, TK = 16;
  __shared__ __attribute__((aligned(16))) float As[TK][TM + 4];
  __shared__ __attribute__((aligned(16))) float Bs[TK][TN + 4];
  const int mt = blockIdx.x, nt = blockIdx.y;
  const int tid = threadIdx.x;
  const int tx = tid & 15, ty = tid >> 4;
  const size_t m0 = (size_t)mt * TM;
  const int n0 = nt * TN;
  float acc[8][4] = {};

  for (int kt = 0; kt < C; kt += TK) {
#pragma unroll
    for (int e = 0; e < 8; e++) {
      int idx = tid + e * 256;
      int m = idx >> 4, k = idx & 15;
      As[k][m] = x[(m0 + m) * C + kt + k];
    }
#pragma unroll
    for (int e = 0; e < 4; e++) {
      int idx = tid + e * 256;
      int k = idx >> 6, nn = idx & 63;
      Bs[k][nn] = w[(size_t)(C + kt + k) * O + n0 + nn];
    }
    __syncthreads();
#pragma unroll
    for (int kk = 0; kk < TK; kk++) {
      float4 a0 = *(const float4*)&As[kk][ty * 8];
      float4 a1 = *(const float4*)&As[kk][ty * 8 + 4];
      float4 b0 = *(const float4*)&Bs[kk][tx * 4];
      float av[8] = {a0.x, a0.y, a0.z, a0.w, a1.x, a1.y, a1.z, a1.w};
      float bb[4] = {b0.x, b0.y, b0.z, b0.w};
#pragma unroll
      for (int i = 0; i < 8; i++)
#pragma unroll
        for (int j = 0; j < 4; j++) acc[i][j] += av[i] * bb[j];
    }
    __syncthreads();
  }
#pragma unroll
  for (int i = 0; i < 8; i++)
#pragma unroll
    for (int j = 0; j < 4; j++)
      t0buf[(m0 + ty * 8 + i) * O + n0 + tx * 4 + j] = acc[i][j];
}

// ---------------------------------------------------------------------------
// weight -> bf16 hi/lo split in 16x16x32 B-fragment order.
// ---------------------------------------------------------------------------
template <int C, int O>
__global__ void k_wprep(const float* __restrict__ w,
                        unsigned short* __restrict__ whi,
                        unsigned short* __restrict__ wlo) {
  int e = blockIdx.x * 256 + threadIdx.x;
  if (e >= C * O) return;
  constexpr int NT = O / 16;
  int j = e & 7;
  int slot = e >> 3;
  int lane = slot & 63;
  int t2 = slot >> 6;
  int nt = t2 % NT, kb = t2 / NT;
  int k = kb * 32 + ((lane >> 4) & 3) * 8 + j;
  int n = nt * 16 + (lane & 15);
  float v = w[(size_t)k * O + n];
  unsigned short h = f2bf(v);
  unsigned short l = f2bf(v - bf2f(h));
  whi[e] = h;
  wlo[e] = l;
}

// ---------------------------------------------------------------------------
// feature matrix -> bf16 hi/lo split in 16x16x32 A-fragment order for mlp5.
// ---------------------------------------------------------------------------
__global__ void k_aprep(const float* __restrict__ x1, const float* __restrict__ x2,
                        const float* __restrict__ x3, const float* __restrict__ x4,
                        unsigned short* __restrict__ ah, unsigned short* __restrict__ al) {
  int e8 = blockIdx.x * 256 + threadIdx.x;   // 16 kb * 1024 mtg * 64 lanes
  if (e8 >= 16 * 1024 * 64) return;
  int lane = e8 & 63;
  int mtg = (e8 >> 6) & 1023;
  int kb = e8 >> 16;
  int m = mtg * 16 + (lane & 15);
  int k0 = kb * 32 + ((lane >> 4) & 3) * 8;
  const float* p;
  if (k0 < 64)       p = &x1[(size_t)m * 64 + k0];
  else if (k0 < 128) p = &x2[(size_t)m * 64 + (k0 - 64)];
  else if (k0 < 256) p = &x3[(size_t)m * 128 + (k0 - 128)];
  else               p = &x4[(size_t)m * 256 + (k0 - 256)];
  float4 f0 = *(const float4*)p;
  float4 f1 = *(const float4*)(p + 4);
  float fv[8] = {f0.x, f0.y, f0.z, f0.w, f1.x, f1.y, f1.z, f1.w};
  short8 h8, l8;
#pragma unroll
  for (int j = 0; j < 8; j++) {
    unsigned short h = f2bf(fv[j]);
    unsigned short l = f2bf(fv[j] - bf2f(h));
    h8[j] = (short)h;
    l8[j] = (short)l;
  }
  *(short8*)&ah[(size_t)e8 * 8] = h8;
  *(short8*)&al[(size_t)e8 * 8] = l8;
}

// ---------------------------------------------------------------------------
// MFMA edge conv (C in {64,128}): per block 2 points, 32 padded neighbor rows.
// Split bf16: D ~= AhBh + AhBl + AlBh.
// ---------------------------------------------------------------------------
template <int C, int O>
__global__ __launch_bounds__(256) void k_edge_mfma(
    const float* __restrict__ x, const int* __restrict__ knn,
    const unsigned short* __restrict__ whi, const unsigned short* __restrict__ wlo,
    const float* __restrict__ t0buf, const float* __restrict__ g,
    const float* __restrict__ bta, float* __restrict__ out) {
  constexpr int KB = C / 32;
  constexpr int NT = O / 16;
  constexpr int NTW = NT / 2;
  __shared__ unsigned short Ah[2 * 2 * KB * 512];
  __shared__ unsigned short Al[2 * 2 * KB * 512];

  const int blk = blockIdx.x;
  const int b = blk / (NPTS / 2);
  const int n0 = (blk % (NPTS / 2)) * 2;
  const int tid = threadIdx.x;
  const int lane = tid & 63;
  const int wid = tid >> 6;
  const int pt = wid >> 1;
  const int nsl = wid & 1;
  const int ptg = b * NPTS + n0 + pt;
  const float* xb = x + (size_t)b * NPTS * C;
  const int kbase = ptg * KNN;

  if constexpr (C == 128) {
    const float2 ctr2 = *(const float2*)&xb[(size_t)(n0 + pt) * C + lane * 2];
    const int kb = lane >> 4;
    const int q = (lane >> 2) & 3;
    const int j2 = 2 * (lane & 3);
#pragma unroll
    for (int i = 0; i < 16; i++) {
      int r = 2 * i + nsl;
      unsigned hp = 0, lp = 0;
      if (r < KNN) {
        int m = knn[kbase + r];
        float2 v = *(const float2*)&xb[(size_t)m * C + lane * 2];
        float d0 = v.x - ctr2.x, d1 = v.y - ctr2.y;
        unsigned short h0 = f2bf(d0), h1 = f2bf(d1);
        unsigned short l0 = f2bf(d0 - bf2f(h0)), l1 = f2bf(d1 - bf2f(h1));
        hp = (unsigned)h0 | ((unsigned)h1 << 16);
        lp = (unsigned)l0 | ((unsigned)l1 << 16);
      }
      int mt = r >> 4, row = r & 15;
      int L = row + 16 * q;
      int phys = L ^ ((4 * kb + q) & 15);
      int idx = ((pt * 2 + mt) * KB + kb) * 512 + phys * 8 + j2;
      *(unsigned*)&Ah[idx] = hp;
      *(unsigned*)&Al[idx] = lp;
    }
  } else {
    const float ctrv = xb[(size_t)(n0 + pt) * C + lane];
    const int kb = lane >> 5;
    const int q = (lane >> 3) & 3;
    const int j = lane & 7;
#pragma unroll
    for (int i = 0; i < 16; i++) {
      int r = 2 * i + nsl;
      unsigned short h = 0, l = 0;
      if (r < KNN) {
        int m = knn[kbase + r];
        float d = xb[(size_t)m * C + lane] - ctrv;
        h = f2bf(d);
        l = f2bf(d - bf2f(h));
      }
      int mt = r >> 4, row = r & 15;
      int L = row + 16 * q;
      int phys = L ^ ((4 * kb + q) & 15);
      int idx = ((pt * 2 + mt) * KB + kb) * 512 + phys * 8 + j;
      Ah[idx] = h;
      Al[idx] = l;
    }
  }
  __syncthreads();

  f32x4 acc[2][NTW];
#pragma unroll
  for (int mt = 0; mt < 2; mt++)
#pragma unroll
    for (int t = 0; t < NTW; t++) acc[mt][t] = (f32x4){0.f, 0.f, 0.f, 0.f};

#pragma unroll
  for (int kb = 0; kb < KB; kb++) {
    int phys = lane ^ ((4 * kb + (lane >> 4)) & 15);
    short8 ah[2], al[2];
#pragma unroll
    for (int mt = 0; mt < 2; mt++) {
      int idx = ((pt * 2 + mt) * KB + kb) * 512 + phys * 8;
      ah[mt] = *(const short8*)&Ah[idx];
      al[mt] = *(const short8*)&Al[idx];
    }
#pragma unroll
    for (int t = 0; t < NTW; t++) {
      int nt = nsl * NTW + t;
      size_t widx = ((size_t)(kb * NT + nt) * 64 + lane) * 8;
      short8 bh = *(const short8*)&whi[widx];
      short8 bl = *(const short8*)&wlo[widx];
#pragma unroll
      for (int mt = 0; mt < 2; mt++) {
        acc[mt][t] = __builtin_amdgcn_mfma_f32_16x16x32_bf16(ah[mt], bh, acc[mt][t], 0, 0, 0);
        acc[mt][t] = __builtin_amdgcn_mfma_f32_16x16x32_bf16(ah[mt], bl, acc[mt][t], 0, 0, 0);
        acc[mt][t] = __builtin_amdgcn_mfma_f32_16x16x32_bf16(al[mt], bh, acc[mt][t], 0, 0, 0);
      }
    }
  }

#pragma unroll
  for (int t = 0; t < NTW; t++) {
    int o = (nsl * NTW + t) * 16 + (lane & 15);
    float tv = t0buf[(size_t)ptg * O + o];
    float gv = g[o], bv = bta[o];
    float m = -3.0e38f;
#pragma unroll
    for (int mt = 0; mt < 2; mt++)
#pragma unroll
      for (int r = 0; r < 4; r++) {
        float h = (acc[mt][t][r] + tv) * gv + bv;
        h = (h >= 0.f) ? h : 0.2f * h;
        m = fmaxf(m, h);
      }
    m = fmaxf(m, __shfl_xor(m, 16));
    m = fmaxf(m, __shfl_xor(m, 32));
    if (lane < 16) out[(size_t)ptg * O + o] = m;
  }
}

// ---------------------------------------------------------------------------
// fp32 edge conv -- retained for conv1 (C=3) only.
// ---------------------------------------------------------------------------
template <int C, int O>
__global__ __launch_bounds__(256) void k_edge(const float* __restrict__ x,
                                              const int* __restrict__ knn,
                                              const float* __restrict__ w,
                                              const float* __restrict__ g,
                                              const float* __restrict__ bta,
                                              float* __restrict__ out) {
  constexpr int JO = O / 64;
  constexpr int NPB = 4;
  __shared__ __attribute__((aligned(16))) float nbd[NPB * KNN * C];

  const int blk = blockIdx.x;
  const int b = blk / (NPTS / NPB);
  const int n0 = (blk % (NPTS / NPB)) * NPB;
  const int tid = threadIdx.x;
  const int lane = tid & 63;
  const int p = tid >> 6;
  const float* xb = x + (size_t)b * NPTS * C;

  const int kbase = (b * NPTS + n0 + p) * KNN;
  float* nb_p = nbd + p * KNN * C;
  int midx[KNN];
#pragma unroll
  for (int k = 0; k < KNN; k++) midx[k] = knn[kbase + k];

  float cv0 = 0.f;
  if (lane < C) cv0 = xb[(size_t)(n0 + p) * C + lane];
  float vv[KNN];
#pragma unroll
  for (int k = 0; k < KNN; k++)
    vv[k] = (lane < C) ? xb[(size_t)midx[k] * C + lane] : 0.f;
#pragma unroll
  for (int k = 0; k < KNN; k++)
    if (lane < C) nb_p[k * C + lane] = vv[k] - cv0;

  float acc[KNN][JO];
  {
    float t0[JO];
#pragma unroll
    for (int j = 0; j < JO; j++) t0[j] = 0.f;
    for (int c = 0; c < C; c++) {
      float cc = __shfl(cv0, c);
#pragma unroll
      for (int j = 0; j < JO; j++)
        t0[j] += cc * w[(size_t)(C + c) * O + j * 64 + lane];
    }
#pragma unroll
    for (int k = 0; k < KNN; k++)
#pragma unroll
      for (int j = 0; j < JO; j++) acc[k][j] = t0[j];
  }

  for (int c = 0; c < C; c++) {
    float wv[JO];
#pragma unroll
    for (int j = 0; j < JO; j++) wv[j] = w[(size_t)c * O + j * 64 + lane];
#pragma unroll
    for (int k = 0; k < KNN; k++) {
      float f = nb_p[k * C + c];
#pragma unroll
      for (int j = 0; j < JO; j++) acc[k][j] += f * wv[j];
    }
  }

#pragma unroll
  for (int j = 0; j < JO; j++) {
    const float gv = g[j * 64 + lane], bv = bta[j * 64 + lane];
    float mx = -3.0e38f;
#pragma unroll
    for (int k = 0; k < KNN; k++) {
      float h = acc[k][j] * gv + bv;
      h = (h >= 0.f) ? h : 0.2f * h;
      mx = fmaxf(mx, h);
    }
    out[(size_t)(b * NPTS + n0 + p) * O + j * 64 + lane] = mx;
  }
}

// ---------------------------------------------------------------------------
// point MLP 512->1024 as split-bf16 MFMA GEMM, no LDS, no barriers.
// ---------------------------------------------------------------------------
__global__ __launch_bounds__(256) void k_mlp5(const unsigned short* __restrict__ a5h,
                                              const unsigned short* __restrict__ a5l,
                                              const unsigned short* __restrict__ w5h,
                                              const unsigned short* __restrict__ w5l,
                                              const float* __restrict__ g5,
                                              const float* __restrict__ b5,
                                              float* __restrict__ pmax,
                                              float* __restrict__ psum) {
  const int mtb = blockIdx.x;   // 0..127
  const int ntb = blockIdx.y;   // 0..7
  const int tid = threadIdx.x;
  const int lane = tid & 63;
  const int nsl = tid >> 6;     // wave id 0..3

  f32x4 acc[8][2];
#pragma unroll
  for (int mt = 0; mt < 8; mt++)
#pragma unroll
    for (int t = 0; t < 2; t++) acc[mt][t] = (f32x4){0.f, 0.f, 0.f, 0.f};

  for (int kb = 0; kb < 16; kb++) {
    short8 bh[2], bl[2];
#pragma unroll
    for (int t = 0; t < 2; t++) {
      int ntg = ntb * 8 + nsl * 2 + t;
      size_t widx = ((size_t)(kb * 64 + ntg) * 64 + lane) * 8;
      bh[t] = *(const short8*)&w5h[widx];
      bl[t] = *(const short8*)&w5l[widx];
    }
#pragma unroll
    for (int mt = 0; mt < 8; mt++) {
      size_t aidx = (((size_t)kb * 1024 + mtb * 8 + mt) * 64 + lane) * 8;
      short8 ah = *(const short8*)&a5h[aidx];
      short8 al = *(const short8*)&a5l[aidx];
#pragma unroll
      for (int t = 0; t < 2; t++) {
        acc[mt][t] = __builtin_amdgcn_mfma_f32_16x16x32_bf16(ah, bh[t], acc[mt][t], 0, 0, 0);
        acc[mt][t] = __builtin_amdgcn_mfma_f32_16x16x32_bf16(ah, bl[t], acc[mt][t], 0, 0, 0);
        acc[mt][t] = __builtin_amdgcn_mfma_f32_16x16x32_bf16(al, bh[t], acc[mt][t], 0, 0, 0);
      }
    }
  }

#pragma unroll
  for (int t = 0; t < 2; t++) {
    int o = ntb * 128 + (nsl * 2 + t) * 16 + (lane & 15);
    float gv = g5[o], bv = b5[o];
    float mx = -3.0e38f, sm = 0.f;
#pragma unroll
    for (int mt = 0; mt < 8; mt++)
#pragma unroll
      for (int r = 0; r < 4; r++) {
        float h = acc[mt][t][r] * gv + bv;
        h = (h >= 0.f) ? h : 0.2f * h;
        mx = fmaxf(mx, h);
        sm += h;
      }
    mx = fmaxf(mx, __shfl_xor(mx, 16));
    mx = fmaxf(mx, __shfl_xor(mx, 32));
    sm += __shfl_xor(sm, 16);
    sm += __shfl_xor(sm, 32);
    if (lane < 16) {
      pmax[(size_t)mtb * 1024 + o] = mx;
      psum[(size_t)mtb * 1024 + o] = sm;
    }
  }
}

// ---------------------------------------------------------------------------
// reduce tile partials -> pooled (B, 2048) = [max(1024), mean(1024)]
// ---------------------------------------------------------------------------
__global__ void k_pool(const float* __restrict__ pmax, const float* __restrict__ psum,
                       float* __restrict__ pooled) {
  int i = blockIdx.x * 256 + threadIdx.x;
  if (i >= NBATCH * 1024) return;
  int b = i / 1024, e = i - b * 1024;
  constexpr int NT = NPTS / 128;
  float mx = -3.0e38f, sm = 0.f;
  for (int t = 0; t < NT; t++) {
    mx = fmaxf(mx, pmax[((size_t)b * NT + t) * 1024 + e]);
    sm += psum[((size_t)b * NT + t) * 1024 + e];
  }
  pooled[(size_t)b * 2048 + e] = mx;
  pooled[(size_t)b * 2048 + 1024 + e] = sm * (1.0f / NPTS);
}

// ---------------------------------------------------------------------------
// FC head: 2048->512 (leaky, affine) -> 256 (bias, leaky, affine) -> 40 (+bias)
// ---------------------------------------------------------------------------
__global__ __launch_bounds__(256) void k_head(const float* __restrict__ pooled,
                                              const float* __restrict__ wl1,
                                              const float* __restrict__ g6,
                                              const float* __restrict__ b6,
                                              const float* __restrict__ wl2,
                                              const float* __restrict__ bl2,
                                              const float* __restrict__ g7,
                                              const float* __restrict__ b7,
                                              const float* __restrict__ wl3,
                                              const float* __restrict__ bl3,
                                              float* __restrict__ out) {
  const int b = blockIdx.x;
  const int tid = threadIdx.x;
  __shared__ float pl[2048];
  __shared__ float h1[512];
  __shared__ float h2[256];

  for (int i = tid; i < 2048; i += 256) pl[i] = pooled[(size_t)b * 2048 + i];
  __syncthreads();

  for (int o = tid; o < 512; o += 256) {
    float a = 0.f;
    for (int c = 0; c < 2048; c++) a += pl[c] * wl1[(size_t)c * 512 + o];
    a = a * g6[o] + b6[o];
    h1[o] = (a >= 0.f) ? a : 0.2f * a;
  }
  __syncthreads();

  {
    float a = 0.f;
    for (int c = 0; c < 512; c++) a += h1[c] * wl2[(size_t)c * 256 + tid];
    a = (a + bl2[tid]) * g7[tid] + b7[tid];
    h2[tid] = (a >= 0.f) ? a : 0.2f * a;
  }
  __syncthreads();

  if (tid < 40) {
    float a = bl3[tid];
    for (int c = 0; c < 256; c++) a += h2[c] * wl3[(size_t)c * 40 + tid];
    out[(size_t)b * 40 + tid] = a;
  }
}

// ---------------------------------------------------------------------------
extern "C" void kernel_launch(void* const* d_in, const int* in_sizes, int n_in,
                              void* d_out, int out_size, void* d_ws, size_t ws_size,
                              hipStream_t stream) {
  (void)in_sizes; (void)n_in; (void)out_size;
  const float* x   = (const float*)d_in[0];
  const float* w1  = (const float*)d_in[1];
  const float* g1  = (const float*)d_in[2];
  const float* b1  = (const float*)d_in[3];
  const float* w2  = (const float*)d_in[4];
  const float* g2  = (const float*)d_in[5];
  const float* b2  = (const float*)d_in[6];
  const float* w3  = (const float*)d_in[7];
  const float* g3  = (const float*)d_in[8];
  const float* b3  = (const float*)d_in[9];
  const float* w4  = (const float*)d_in[10];
  const float* g4  = (const float*)d_in[11];
  const float* b4  = (const float*)d_in[12];
  const float* w5  = (const float*)d_in[13];
  const float* g5  = (const float*)d_in[14];
  const float* b5  = (const float*)d_in[15];
  const float* wl1 = (const float*)d_in[16];
  const float* g6  = (const float*)d_in[17];
  const float* b6  = (const float*)d_in[18];
  const float* wl2 = (const float*)d_in[19];
  const float* bl2 = (const float*)d_in[20];
  const float* g7  = (const float*)d_in[21];
  const float* b7  = (const float*)d_in[22];
  const float* wl3 = (const float*)d_in[23];
  const float* bl3 = (const float*)d_in[24];

  float* ws = (float*)d_ws;
  size_t off = 0;
  float* h0 = ws + off;   off += (size_t)NBATCH * NPTS * 3;
  float* x1 = ws + off;   off += (size_t)NBATCH * NPTS * 64;
  float* x2 = ws + off;   off += (size_t)NBATCH * NPTS * 64;
  float* x3 = ws + off;   off += (size_t)NBATCH * NPTS * 128;
  float* x4 = ws + off;   off += (size_t)NBATCH * NPTS * 256;
  int* knn = (int*)(ws + off); off += (size_t)NBATCH * NPTS * KNN;
  float* pmax = ws + off; off += (size_t)(NPTS / 128) * NBATCH * 1024;
  float* psum = ws + off; off += (size_t)(NPTS / 128) * NBATCH * 1024;
  float* pooled = ws + off; off += (size_t)NBATCH * 2048;
  float* t0buf = ws + off;  off += (size_t)NBATCH * NPTS * 256;  // max O
  unsigned short* w2h = (unsigned short*)(ws + off); off += 64 * 64 / 2 * 2;
  unsigned short* w2l = w2h + 64 * 64;
  unsigned short* w3h = (unsigned short*)(ws + off); off += 64 * 128 / 2 * 2;
  unsigned short* w3l = w3h + 64 * 128;
  unsigned short* w4h = (unsigned short*)(ws + off); off += 128 * 256 / 2 * 2;
  unsigned short* w4l = w4h + 128 * 256;
  unsigned short* w5h = (unsigned short*)(ws + off); off += 512 * 1024 / 2 * 2;
  unsigned short* w5l = w5h + 512 * 1024;
  unsigned short* a5h = (unsigned short*)(ws + off); off += (size_t)16384 * 512 / 2 * 2;
  unsigned short* a5l = a5h + (size_t)16384 * 512;
  float* dist = ws + off;  // adaptive: nb_grp * NPTS * NPTS floats, placed last

  size_t avail = ws_size / 4 - off;
  int nb_grp = 8;
  while (nb_grp > 1 && (size_t)nb_grp * NPTS * NPTS > avail) nb_grp >>= 1;

  constexpr int NTRI = (NPTS / 64) * (NPTS / 64 + 1) / 2;  // 528

  k_transpose<<<(NBATCH * NPTS * 3 + 255) / 256, 256, 0, stream>>>(x, h0);

  // weight hi/lo fragment prep (depends only on inputs -- run up front)
  k_wprep<64, 64><<<(64 * 64 + 255) / 256, 256, 0, stream>>>(w2, w2h, w2l);
  k_wprep<64, 128><<<(64 * 128 + 255) / 256, 256, 0, stream>>>(w3, w3h, w3l);
  k_wprep<128, 256><<<(128 * 256 + 255) / 256, 256, 0, stream>>>(w4, w4h, w4l);
  k_wprep<512, 1024><<<(512 * 1024 + 255) / 256, 256, 0, stream>>>(w5, w5h, w5l);

  // ---- edge conv 1 (C=3 -> O=64): fused register kNN (wave/row) + fp32 edge
  k_knn3<<<dim3(NPTS / 4, NBATCH), 256, 0, stream>>>(h0, knn);
  k_edge<3, 64><<<NBATCH * NPTS / 4, 256, 0, stream>>>(h0, knn, w1, g1, b1, x1);

  // ---- edge conv 2 (C=64 -> O=64)
  for (int b0 = 0; b0 < NBATCH; b0 += nb_grp) {
    k_dist<64><<<dim3(NTRI, 1, nb_grp), 256, 0, stream>>>(
        x1 + (size_t)b0 * NPTS * 64, dist);
    k_topk<<<dim3(NPTS / 4, nb_grp), 256, 0, stream>>>(dist,
                                                       knn + (size_t)b0 * NPTS * KNN);
  }
  k_t0<64, 64><<<dim3(NBATCH * NPTS / 128, 1), 256, 0, stream>>>(x1, w2, t0buf);
  k_edge_mfma<64, 64><<<NBATCH * NPTS / 2, 256, 0, stream>>>(x1, knn, w2h, w2l, t0buf,
                                                             g2, b2, x2);

  // ---- edge conv 3 (C=64 -> O=128)
  for (int b0 = 0; b0 < NBATCH; b0 += nb_grp) {
    k_dist<64><<<dim3(NTRI, 1, nb_grp), 256, 0, stream>>>(
        x2 + (size_t)b0 * NPTS * 64, dist);
    k_topk<<<dim3(NPTS / 4, nb_grp), 256, 0, stream>>>(dist,
                                                       knn + (size_t)b0 * NPTS * KNN);
  }
  k_t0<64, 128><<<dim3(NBATCH * NPTS / 128, 2), 256, 0, stream>>>(x2, w3, t0buf);
  k_edge_mfma<64, 128><<<NBATCH * NPTS / 2, 256, 0, stream>>>(x2, knn, w3h, w3l, t0buf,
                                                              g3, b3, x3);

  // ---- edge conv 4 (C=128 -> O=256)
  for (int b0 = 0; b0 < NBATCH; b0 += nb_grp) {
    k_dist<128><<<dim3(NTRI, 1, nb_grp), 256, 0, stream>>>(
        x3 + (size_t)b0 * NPTS * 128, dist);
    k_topk<<<dim3(NPTS / 4, nb_grp), 256, 0, stream>>>(dist,
                                                       knn + (size_t)b0 * NPTS * KNN);
  }
  k_t0<128, 256><<<dim3(NBATCH * NPTS / 128, 4), 256, 0, stream>>>(x3, w4, t0buf);
  k_edge_mfma<128, 256><<<NBATCH * NPTS / 2, 256, 0, stream>>>(x3, knn, w4h, w4l, t0buf,
                                                               g4, b4, x4);

  // ---- point MLP (split-bf16 MFMA GEMM) + pooling + head
  k_aprep<<<(16 * 1024 * 64 + 255) / 256, 256, 0, stream>>>(x1, x2, x3, x4, a5h, a5l);
  k_mlp5<<<dim3(NBATCH * NPTS / 128, 8), 256, 0, stream>>>(a5h, a5l, w5h, w5l, g5, b5,
                                                           pmax, psum);
  k_pool<<<(NBATCH * 1024 + 255) / 256, 256, 0, stream>>>(pmax, psum, pooled);
  k_head<<<NBATCH, 256, 0, stream>>>(pooled, wl1, g6, b6, wl2, bl2, g7, b7, wl3, bl3,
                                     (float*)d_out);
}

// Round 16
// 1067.778 us; speedup vs baseline: 8.1702x; 1.0985x over previous
//
#include <hip/hip_runtime.h>
#include <cstddef>
#include <cstdint>

#define NBATCH 8
#define NPTS   2048
#define KNN    20

typedef __attribute__((ext_vector_type(8))) short short8;
typedef __attribute__((ext_vector_type(4))) float f32x4;

__device__ __forceinline__ unsigned short f2bf(float f) {
  unsigned u = __float_as_uint(f);
  u += 0x7fff + ((u >> 16) & 1);   // round-to-nearest-even
  return (unsigned short)(u >> 16);
}
__device__ __forceinline__ float bf2f(unsigned short h) {
  return __uint_as_float(((unsigned)h) << 16);
}

// ---------------------------------------------------------------------------
// wave-level exact top-20 over 2048 candidates: lane holds 32 values,
// global index of v[slot] on lane l is slot*64 + l. One wave per row.
// Per-lane TOP-2 CACHE with lazy refill (R15: ~2x fewer issue slots than the
// full-rescan variant). Tie-break identical: ascending-slot strict > keeps
// lowest index per lane; cross-lane (value desc, index asc).
// ---------------------------------------------------------------------------
__device__ __forceinline__ void wave_top20(float (&v)[32], int lane,
                                           int* __restrict__ row_out) {
  float m1 = -3.0e38f, m2 = -3.0e38f;
  int i1 = 0, i2 = 0;
#pragma unroll
  for (int i = 0; i < 32; i++) {
    float x = v[i];
    if (x > m1) { m2 = m1; i2 = i1; m1 = x; i1 = i; }
    else if (x > m2) { m2 = x; i2 = i; }
  }

  unsigned dm = 0;
  int cnt = 2;
  int keep = 0;
  for (int k = 0; k < KNN; k++) {
    float rv = m1;
    int ri = i1 * 64 + lane;
#pragma unroll
    for (int off = 32; off > 0; off >>= 1) {
      float ov = __shfl_down(rv, off);
      int oi = __shfl_down(ri, off);
      if (ov > rv || (ov == rv && oi < ri)) { rv = ov; ri = oi; }
    }
    int wi = __shfl(ri, 0);
    if (lane == k) keep = wi;
    if ((wi & 63) == lane) {
      dm |= 1u << (wi >> 6);
      if (cnt == 2) {
        m1 = m2; i1 = i2; cnt = 1;
      } else {
        m1 = -3.0e38f; i1 = 0; m2 = -3.0e38f; i2 = 0;
#pragma unroll
        for (int i = 0; i < 32; i++)
          if (!((dm >> i) & 1)) {
            float x = v[i];
            if (x > m1) { m2 = m1; i2 = i1; m1 = x; i1 = i; }
            else if (x > m2) { m2 = x; i2 = i; }
          }
        cnt = 2;
      }
    }
  }
  if (lane < KNN) row_out[lane] = keep;
}

// ---------------------------------------------------------------------------
// transpose (B,3,N) -> (B,N,3)
// ---------------------------------------------------------------------------
__global__ void k_transpose(const float* __restrict__ x, float* __restrict__ h0) {
  int i = blockIdx.x * 256 + threadIdx.x;
  if (i >= NBATCH * NPTS * 3) return;
  int c = i % 3;
  int n = (i / 3) % NPTS;
  int b = i / (3 * NPTS);
  h0[i] = x[((size_t)b * 3 + c) * NPTS + n];
}

// ---------------------------------------------------------------------------
// pairwise "distance" pd = 2*dot - sq_n - sq_m. blockIdx.z = batch in group.
// R11-proven 64x64 tile / 4x4 microtile, upper-triangular grid (528 blocks);
// off-diagonal blocks mirror their tile via an LDS bounce (bit-identical).
// NOTE (R12/R13 lesson): no 8x8 microtile, no waves/EU pin -- both spilled.
// ---------------------------------------------------------------------------
template <int C>
__global__ __launch_bounds__(256) void k_dist(const float* __restrict__ xg,
                                              float* __restrict__ dist) {
  constexpr int PAD = 4;
  constexpr int S = C + PAD;
  constexpr int TS = 67;
  __shared__ __attribute__((aligned(16))) float rows[64 * S];
  __shared__ __attribute__((aligned(16))) float cols[64 * S];
  __shared__ float sq[128];

  const float* xb = xg + (size_t)blockIdx.z * NPTS * C;
  float* db = dist + (size_t)blockIdx.z * NPTS * NPTS;

  constexpr int T = NPTS / 64;
  int bid = blockIdx.x;
  int rt = 0;
  while (bid >= T - rt) { bid -= T - rt; rt++; }
  const int ct = rt + bid;

  const int tid = threadIdx.x;

  for (int e = tid; e < 64 * C; e += 256) {
    int i = e / C, c = e - i * C;
    rows[i * S + c] = xb[(size_t)(rt * 64 + i) * C + c];
    cols[i * S + c] = xb[(size_t)(ct * 64 + i) * C + c];
  }
  __syncthreads();
  if (tid < 128) {
    const float* p = (tid < 64) ? (rows + tid * S) : (cols + (tid - 64) * S);
    float s = 0.f;
    for (int c = 0; c < C; c++) s += p[c] * p[c];
    sq[tid] = s;
  }
  __syncthreads();

  const int r0 = (tid >> 4) * 4;
  const int c0 = tid & 15;
  float acc[4][4] = {};

  for (int c = 0; c < C; c += 4) {
    float4 ra[4], cb[4];
#pragma unroll
    for (int i = 0; i < 4; i++) ra[i] = *(const float4*)&rows[(r0 + i) * S + c];
#pragma unroll
    for (int j = 0; j < 4; j++) cb[j] = *(const float4*)&cols[(c0 + 16 * j) * S + c];
#pragma unroll
    for (int i = 0; i < 4; i++)
#pragma unroll
      for (int j = 0; j < 4; j++)
        acc[i][j] += ra[i].x * cb[j].x + ra[i].y * cb[j].y +
                     ra[i].z * cb[j].z + ra[i].w * cb[j].w;
  }

  float pd[4][4];
#pragma unroll
  for (int i = 0; i < 4; i++) {
    float sr = sq[r0 + i];
#pragma unroll
    for (int j = 0; j < 4; j++)
      pd[i][j] = 2.f * acc[i][j] - sr - sq[64 + c0 + 16 * j];
  }

#pragma unroll
  for (int i = 0; i < 4; i++)
#pragma unroll
    for (int j = 0; j < 4; j++)
      db[(size_t)(rt * 64 + r0 + i) * NPTS + ct * 64 + c0 + 16 * j] = pd[i][j];

  if (rt != ct) {
    __syncthreads();
    float* tb = rows;
#pragma unroll
    for (int i = 0; i < 4; i++)
#pragma unroll
      for (int j = 0; j < 4; j++)
        tb[(c0 + 16 * j) * TS + r0 + i] = pd[i][j];
    __syncthreads();
#pragma unroll
    for (int i = 0; i < 4; i++)
#pragma unroll
      for (int j = 0; j < 4; j++)
        db[(size_t)(ct * 64 + r0 + i) * NPTS + rt * 64 + c0 + 16 * j] =
            tb[(r0 + i) * TS + c0 + 16 * j];
  }
}

// ---------------------------------------------------------------------------
// top-20 per row from materialized dist. One wave per row, 4 rows per block.
// ---------------------------------------------------------------------------
__global__ __launch_bounds__(256) void k_topk(const float* __restrict__ dist,
                                              int* __restrict__ idx_out) {
  const int wid = threadIdx.x >> 6;
  const int lane = threadIdx.x & 63;
  const int n = blockIdx.x * 4 + wid;
  const int z = blockIdx.y;
  const float* drow = dist + ((size_t)z * NPTS + n) * NPTS;
  int* row_out = idx_out + ((size_t)z * NPTS + n) * KNN;

  float v[32];
#pragma unroll
  for (int i = 0; i < 32; i++) v[i] = drow[i * 64 + lane];

  wave_top20(v, lane, row_out);
}

// ---------------------------------------------------------------------------
// conv1 fused kNN (C=3): one wave per row, register recompute + wave_top20.
// ---------------------------------------------------------------------------
__global__ __launch_bounds__(256) void k_knn3(const float* __restrict__ x,
                                              int* __restrict__ idx_out) {
  const int wid = threadIdx.x >> 6;
  const int lane = threadIdx.x & 63;
  const int n = blockIdx.x * 4 + wid;
  const int b = blockIdx.y;
  const float* xb = x + (size_t)b * NPTS * 3;
  int* row_out = idx_out + ((size_t)b * NPTS + n) * KNN;

  const float qx = xb[n * 3 + 0], qy = xb[n * 3 + 1], qz = xb[n * 3 + 2];
  float qsq = 0.f;
  qsq += qx * qx; qsq += qy * qy; qsq += qz * qz;

  float v[32];
#pragma unroll
  for (int i = 0; i < 32; i++) {
    int m = i * 64 + lane;
    float cx = xb[m * 3 + 0], cy = xb[m * 3 + 1], cz = xb[m * 3 + 2];
    float csq = 0.f;
    csq += cx * cx; csq += cy * cy; csq += cz * cz;
    float acc = 0.f;
    acc += qx * cx; acc += qy * cy; acc += qz * cz;
    v[i] = 2.f * acc - qsq - csq;
  }

  wave_top20(v, lane, row_out);
}

// ---------------------------------------------------------------------------
// t0 GEMM: t0buf[n, o] = sum_c x[n, c] * w[C+c, o]   (center @ w_hi)
// ---------------------------------------------------------------------------
template <int C, int O>
__global__ __launch_bounds__(256) void k_t0(const float* __restrict__ x,
                                            const float* __restrict__ w,
                                            float* __restrict__ t0buf) {
  constexpr int TM = 128, TN = 64, TK = 16;
  __shared__ __attribute__((aligned(16))) float As[TK][TM + 4];
  __shared__ __attribute__((aligned(16))) float Bs[TK][TN + 4];
  const int mt = blockIdx.x, nt = blockIdx.y;
  const int tid = threadIdx.x;
  const int tx = tid & 15, ty = tid >> 4;
  const size_t m0 = (size_t)mt * TM;
  const int n0 = nt * TN;
  float acc[8][4] = {};

  for (int kt = 0; kt < C; kt += TK) {
#pragma unroll
    for (int e = 0; e < 8; e++) {
      int idx = tid + e * 256;
      int m = idx >> 4, k = idx & 15;
      As[k][m] = x[(m0 + m) * C + kt + k];
    }
#pragma unroll
    for (int e = 0; e < 4; e++) {
      int idx = tid + e * 256;
      int k = idx >> 6, nn = idx & 63;
      Bs[k][nn] = w[(size_t)(C + kt + k) * O + n0 + nn];
    }
    __syncthreads();
#pragma unroll
    for (int kk = 0; kk < TK; kk++) {
      float4 a0 = *(const float4*)&As[kk][ty * 8];
      float4 a1 = *(const float4*)&As[kk][ty * 8 + 4];
      float4 b0 = *(const float4*)&Bs[kk][tx * 4];
      float av[8] = {a0.x, a0.y, a0.z, a0.w, a1.x, a1.y, a1.z, a1.w};
      float bb[4] = {b0.x, b0.y, b0.z, b0.w};
#pragma unroll
      for (int i = 0; i < 8; i++)
#pragma unroll
        for (int j = 0; j < 4; j++) acc[i][j] += av[i] * bb[j];
    }
    __syncthreads();
  }
#pragma unroll
  for (int i = 0; i < 8; i++)
#pragma unroll
    for (int j = 0; j < 4; j++)
      t0buf[(m0 + ty * 8 + i) * O + n0 + tx * 4 + j] = acc[i][j];
}

// ---------------------------------------------------------------------------
// weight -> bf16 hi/lo split in 16x16x32 B-fragment order.
// ---------------------------------------------------------------------------
template <int C, int O>
__global__ void k_wprep(const float* __restrict__ w,
                        unsigned short* __restrict__ whi,
                        unsigned short* __restrict__ wlo) {
  int e = blockIdx.x * 256 + threadIdx.x;
  if (e >= C * O) return;
  constexpr int NT = O / 16;
  int j = e & 7;
  int slot = e >> 3;
  int lane = slot & 63;
  int t2 = slot >> 6;
  int nt = t2 % NT, kb = t2 / NT;
  int k = kb * 32 + ((lane >> 4) & 3) * 8 + j;
  int n = nt * 16 + (lane & 15);
  float v = w[(size_t)k * O + n];
  unsigned short h = f2bf(v);
  unsigned short l = f2bf(v - bf2f(h));
  whi[e] = h;
  wlo[e] = l;
}

// ---------------------------------------------------------------------------
// feature matrix -> bf16 hi/lo split in 16x16x32 A-fragment order for mlp5.
// ---------------------------------------------------------------------------
__global__ void k_aprep(const float* __restrict__ x1, const float* __restrict__ x2,
                        const float* __restrict__ x3, const float* __restrict__ x4,
                        unsigned short* __restrict__ ah, unsigned short* __restrict__ al) {
  int e8 = blockIdx.x * 256 + threadIdx.x;
  if (e8 >= 16 * 1024 * 64) return;
  int lane = e8 & 63;
  int mtg = (e8 >> 6) & 1023;
  int kb = e8 >> 16;
  int m = mtg * 16 + (lane & 15);
  int k0 = kb * 32 + ((lane >> 4) & 3) * 8;
  const float* p;
  if (k0 < 64)       p = &x1[(size_t)m * 64 + k0];
  else if (k0 < 128) p = &x2[(size_t)m * 64 + (k0 - 64)];
  else if (k0 < 256) p = &x3[(size_t)m * 128 + (k0 - 128)];
  else               p = &x4[(size_t)m * 256 + (k0 - 256)];
  float4 f0 = *(const float4*)p;
  float4 f1 = *(const float4*)(p + 4);
  float fv[8] = {f0.x, f0.y, f0.z, f0.w, f1.x, f1.y, f1.z, f1.w};
  short8 h8, l8;
#pragma unroll
  for (int j = 0; j < 8; j++) {
    unsigned short h = f2bf(fv[j]);
    unsigned short l = f2bf(fv[j] - bf2f(h));
    h8[j] = (short)h;
    l8[j] = (short)l;
  }
  *(short8*)&ah[(size_t)e8 * 8] = h8;
  *(short8*)&al[(size_t)e8 * 8] = l8;
}

// ---------------------------------------------------------------------------
// MFMA edge conv (C in {64,128}): per block 2 points, 32 padded neighbor rows.
// Split bf16: D ~= AhBh + AhBl + AlBh.
// ---------------------------------------------------------------------------
template <int C, int O>
__global__ __launch_bounds__(256) void k_edge_mfma(
    const float* __restrict__ x, const int* __restrict__ knn,
    const unsigned short* __restrict__ whi, const unsigned short* __restrict__ wlo,
    const float* __restrict__ t0buf, const float* __restrict__ g,
    const float* __restrict__ bta, float* __restrict__ out) {
  constexpr int KB = C / 32;
  constexpr int NT = O / 16;
  constexpr int NTW = NT / 2;
  __shared__ unsigned short Ah[2 * 2 * KB * 512];
  __shared__ unsigned short Al[2 * 2 * KB * 512];

  const int blk = blockIdx.x;
  const int b = blk / (NPTS / 2);
  const int n0 = (blk % (NPTS / 2)) * 2;
  const int tid = threadIdx.x;
  const int lane = tid & 63;
  const int wid = tid >> 6;
  const int pt = wid >> 1;
  const int nsl = wid & 1;
  const int ptg = b * NPTS + n0 + pt;
  const float* xb = x + (size_t)b * NPTS * C;
  const int kbase = ptg * KNN;

  if constexpr (C == 128) {
    const float2 ctr2 = *(const float2*)&xb[(size_t)(n0 + pt) * C + lane * 2];
    const int kb = lane >> 4;
    const int q = (lane >> 2) & 3;
    const int j2 = 2 * (lane & 3);
#pragma unroll
    for (int i = 0; i < 16; i++) {
      int r = 2 * i + nsl;
      unsigned hp = 0, lp = 0;
      if (r < KNN) {
        int m = knn[kbase + r];
        float2 v = *(const float2*)&xb[(size_t)m * C + lane * 2];
        float d0 = v.x - ctr2.x, d1 = v.y - ctr2.y;
        unsigned short h0 = f2bf(d0), h1 = f2bf(d1);
        unsigned short l0 = f2bf(d0 - bf2f(h0)), l1 = f2bf(d1 - bf2f(h1));
        hp = (unsigned)h0 | ((unsigned)h1 << 16);
        lp = (unsigned)l0 | ((unsigned)l1 << 16);
      }
      int mt = r >> 4, row = r & 15;
      int L = row + 16 * q;
      int phys = L ^ ((4 * kb + q) & 15);
      int idx = ((pt * 2 + mt) * KB + kb) * 512 + phys * 8 + j2;
      *(unsigned*)&Ah[idx] = hp;
      *(unsigned*)&Al[idx] = lp;
    }
  } else {
    const float ctrv = xb[(size_t)(n0 + pt) * C + lane];
    const int kb = lane >> 5;
    const int q = (lane >> 3) & 3;
    const int j = lane & 7;
#pragma unroll
    for (int i = 0; i < 16; i++) {
      int r = 2 * i + nsl;
      unsigned short h = 0, l = 0;
      if (r < KNN) {
        int m = knn[kbase + r];
        float d = xb[(size_t)m * C + lane] - ctrv;
        h = f2bf(d);
        l = f2bf(d - bf2f(h));
      }
      int mt = r >> 4, row = r & 15;
      int L = row + 16 * q;
      int phys = L ^ ((4 * kb + q) & 15);
      int idx = ((pt * 2 + mt) * KB + kb) * 512 + phys * 8 + j;
      Ah[idx] = h;
      Al[idx] = l;
    }
  }
  __syncthreads();

  f32x4 acc[2][NTW];
#pragma unroll
  for (int mt = 0; mt < 2; mt++)
#pragma unroll
    for (int t = 0; t < NTW; t++) acc[mt][t] = (f32x4){0.f, 0.f, 0.f, 0.f};

#pragma unroll
  for (int kb = 0; kb < KB; kb++) {
    int phys = lane ^ ((4 * kb + (lane >> 4)) & 15);
    short8 ah[2], al[2];
#pragma unroll
    for (int mt = 0; mt < 2; mt++) {
      int idx = ((pt * 2 + mt) * KB + kb) * 512 + phys * 8;
      ah[mt] = *(const short8*)&Ah[idx];
      al[mt] = *(const short8*)&Al[idx];
    }
#pragma unroll
    for (int t = 0; t < NTW; t++) {
      int nt = nsl * NTW + t;
      size_t widx = ((size_t)(kb * NT + nt) * 64 + lane) * 8;
      short8 bh = *(const short8*)&whi[widx];
      short8 bl = *(const short8*)&wlo[widx];
#pragma unroll
      for (int mt = 0; mt < 2; mt++) {
        acc[mt][t] = __builtin_amdgcn_mfma_f32_16x16x32_bf16(ah[mt], bh, acc[mt][t], 0, 0, 0);
        acc[mt][t] = __builtin_amdgcn_mfma_f32_16x16x32_bf16(ah[mt], bl, acc[mt][t], 0, 0, 0);
        acc[mt][t] = __builtin_amdgcn_mfma_f32_16x16x32_bf16(al[mt], bh, acc[mt][t], 0, 0, 0);
      }
    }
  }

#pragma unroll
  for (int t = 0; t < NTW; t++) {
    int o = (nsl * NTW + t) * 16 + (lane & 15);
    float tv = t0buf[(size_t)ptg * O + o];
    float gv = g[o], bv = bta[o];
    float m = -3.0e38f;
#pragma unroll
    for (int mt = 0; mt < 2; mt++)
#pragma unroll
      for (int r = 0; r < 4; r++) {
        float h = (acc[mt][t][r] + tv) * gv + bv;
        h = (h >= 0.f) ? h : 0.2f * h;
        m = fmaxf(m, h);
      }
    m = fmaxf(m, __shfl_xor(m, 16));
    m = fmaxf(m, __shfl_xor(m, 32));
    if (lane < 16) out[(size_t)ptg * O + o] = m;
  }
}

// ---------------------------------------------------------------------------
// fp32 edge conv -- retained for conv1 (C=3) only.
// ---------------------------------------------------------------------------
template <int C, int O>
__global__ __launch_bounds__(256) void k_edge(const float* __restrict__ x,
                                              const int* __restrict__ knn,
                                              const float* __restrict__ w,
                                              const float* __restrict__ g,
                                              const float* __restrict__ bta,
                                              float* __restrict__ out) {
  constexpr int JO = O / 64;
  constexpr int NPB = 4;
  __shared__ __attribute__((aligned(16))) float nbd[NPB * KNN * C];

  const int blk = blockIdx.x;
  const int b = blk / (NPTS / NPB);
  const int n0 = (blk % (NPTS / NPB)) * NPB;
  const int tid = threadIdx.x;
  const int lane = tid & 63;
  const int p = tid >> 6;
  const float* xb = x + (size_t)b * NPTS * C;

  const int kbase = (b * NPTS + n0 + p) * KNN;
  float* nb_p = nbd + p * KNN * C;
  int midx[KNN];
#pragma unroll
  for (int k = 0; k < KNN; k++) midx[k] = knn[kbase + k];

  float cv0 = 0.f;
  if (lane < C) cv0 = xb[(size_t)(n0 + p) * C + lane];
  float vv[KNN];
#pragma unroll
  for (int k = 0; k < KNN; k++)
    vv[k] = (lane < C) ? xb[(size_t)midx[k] * C + lane] : 0.f;
#pragma unroll
  for (int k = 0; k < KNN; k++)
    if (lane < C) nb_p[k * C + lane] = vv[k] - cv0;

  float acc[KNN][JO];
  {
    float t0[JO];
#pragma unroll
    for (int j = 0; j < JO; j++) t0[j] = 0.f;
    for (int c = 0; c < C; c++) {
      float cc = __shfl(cv0, c);
#pragma unroll
      for (int j = 0; j < JO; j++)
        t0[j] += cc * w[(size_t)(C + c) * O + j * 64 + lane];
    }
#pragma unroll
    for (int k = 0; k < KNN; k++)
#pragma unroll
      for (int j = 0; j < JO; j++) acc[k][j] = t0[j];
  }

  for (int c = 0; c < C; c++) {
    float wv[JO];
#pragma unroll
    for (int j = 0; j < JO; j++) wv[j] = w[(size_t)c * O + j * 64 + lane];
#pragma unroll
    for (int k = 0; k < KNN; k++) {
      float f = nb_p[k * C + c];
#pragma unroll
      for (int j = 0; j < JO; j++) acc[k][j] += f * wv[j];
    }
  }

#pragma unroll
  for (int j = 0; j < JO; j++) {
    const float gv = g[j * 64 + lane], bv = bta[j * 64 + lane];
    float mx = -3.0e38f;
#pragma unroll
    for (int k = 0; k < KNN; k++) {
      float h = acc[k][j] * gv + bv;
      h = (h >= 0.f) ? h : 0.2f * h;
      mx = fmaxf(mx, h);
    }
    out[(size_t)(b * NPTS + n0 + p) * O + j * 64 + lane] = mx;
  }
}

// ---------------------------------------------------------------------------
// point MLP 512->1024 as split-bf16 MFMA GEMM, no LDS, no barriers.
// ---------------------------------------------------------------------------
__global__ __launch_bounds__(256) void k_mlp5(const unsigned short* __restrict__ a5h,
                                              const unsigned short* __restrict__ a5l,
                                              const unsigned short* __restrict__ w5h,
                                              const unsigned short* __restrict__ w5l,
                                              const float* __restrict__ g5,
                                              const float* __restrict__ b5,
                                              float* __restrict__ pmax,
                                              float* __restrict__ psum) {
  const int mtb = blockIdx.x;
  const int ntb = blockIdx.y;
  const int tid = threadIdx.x;
  const int lane = tid & 63;
  const int nsl = tid >> 6;

  f32x4 acc[8][2];
#pragma unroll
  for (int mt = 0; mt < 8; mt++)
#pragma unroll
    for (int t = 0; t < 2; t++) acc[mt][t] = (f32x4){0.f, 0.f, 0.f, 0.f};

  for (int kb = 0; kb < 16; kb++) {
    short8 bh[2], bl[2];
#pragma unroll
    for (int t = 0; t < 2; t++) {
      int ntg = ntb * 8 + nsl * 2 + t;
      size_t widx = ((size_t)(kb * 64 + ntg) * 64 + lane) * 8;
      bh[t] = *(const short8*)&w5h[widx];
      bl[t] = *(const short8*)&w5l[widx];
    }
#pragma unroll
    for (int mt = 0; mt < 8; mt++) {
      size_t aidx = (((size_t)kb * 1024 + mtb * 8 + mt) * 64 + lane) * 8;
      short8 ah = *(const short8*)&a5h[aidx];
      short8 al = *(const short8*)&a5l[aidx];
#pragma unroll
      for (int t = 0; t < 2; t++) {
        acc[mt][t] = __builtin_amdgcn_mfma_f32_16x16x32_bf16(ah, bh[t], acc[mt][t], 0, 0, 0);
        acc[mt][t] = __builtin_amdgcn_mfma_f32_16x16x32_bf16(ah, bl[t], acc[mt][t], 0, 0, 0);
        acc[mt][t] = __builtin_amdgcn_mfma_f32_16x16x32_bf16(al, bh[t], acc[mt][t], 0, 0, 0);
      }
    }
  }

#pragma unroll
  for (int t = 0; t < 2; t++) {
    int o = ntb * 128 + (nsl * 2 + t) * 16 + (lane & 15);
    float gv = g5[o], bv = b5[o];
    float mx = -3.0e38f, sm = 0.f;
#pragma unroll
    for (int mt = 0; mt < 8; mt++)
#pragma unroll
      for (int r = 0; r < 4; r++) {
        float h = acc[mt][t][r] * gv + bv;
        h = (h >= 0.f) ? h : 0.2f * h;
        mx = fmaxf(mx, h);
        sm += h;
      }
    mx = fmaxf(mx, __shfl_xor(mx, 16));
    mx = fmaxf(mx, __shfl_xor(mx, 32));
    sm += __shfl_xor(sm, 16);
    sm += __shfl_xor(sm, 32);
    if (lane < 16) {
      pmax[(size_t)mtb * 1024 + o] = mx;
      psum[(size_t)mtb * 1024 + o] = sm;
    }
  }
}

// ---------------------------------------------------------------------------
// reduce tile partials -> pooled (B, 2048) = [max(1024), mean(1024)]
// ---------------------------------------------------------------------------
__global__ void k_pool(const float* __restrict__ pmax, const float* __restrict__ psum,
                       float* __restrict__ pooled) {
  int i = blockIdx.x * 256 + threadIdx.x;
  if (i >= NBATCH * 1024) return;
  int b = i / 1024, e = i - b * 1024;
  constexpr int NT = NPTS / 128;
  float mx = -3.0e38f, sm = 0.f;
  for (int t = 0; t < NT; t++) {
    mx = fmaxf(mx, pmax[((size_t)b * NT + t) * 1024 + e]);
    sm += psum[((size_t)b * NT + t) * 1024 + e];
  }
  pooled[(size_t)b * 2048 + e] = mx;
  pooled[(size_t)b * 2048 + 1024 + e] = sm * (1.0f / NPTS);
}

// ---------------------------------------------------------------------------
// head layer 1: h1g[b,o] = leaky((pooled[b,:] @ wl1)[o] * g6[o] + b6[o]).
// grid (8 o-chunks, NBATCH), 256 thr: wave ks (0..3) covers k-slice
// [ks*512,(ks+1)*512) for 64 consecutive outputs -> coalesced wl1 reads.
// Partials reduced in ascending-ks (= ascending-c) order.
// (R15 fix: old single-kernel head ran 8 blocks -> 0.36% occupancy, 178 us.)
// ---------------------------------------------------------------------------
__global__ __launch_bounds__(256) void k_head1(const float* __restrict__ pooled,
                                               const float* __restrict__ wl1,
                                               const float* __restrict__ g6,
                                               const float* __restrict__ b6,
                                               float* __restrict__ h1g) {
  const int os = blockIdx.x;         // output chunk 0..7
  const int b = blockIdx.y;
  const int tid = threadIdx.x;
  const int lane = tid & 63;
  const int ks = tid >> 6;           // k-slice 0..3
  const int o = os * 64 + lane;
  __shared__ float pl[2048];
  __shared__ float part[4][64];

  for (int i = tid; i < 2048; i += 256) pl[i] = pooled[(size_t)b * 2048 + i];
  __syncthreads();

  float a = 0.f;
  const int c0 = ks * 512;
  for (int c = 0; c < 512; c++)
    a += pl[c0 + c] * wl1[(size_t)(c0 + c) * 512 + o];
  part[ks][lane] = a;
  __syncthreads();

  if (ks == 0) {
    float s = part[0][lane];
    s += part[1][lane];
    s += part[2][lane];
    s += part[3][lane];
    s = s * g6[o] + b6[o];
    h1g[(size_t)b * 512 + o] = (s >= 0.f) ? s : 0.2f * s;
  }
}

// ---------------------------------------------------------------------------
// head layers 2+3: 512 ->(bias,affine,leaky) 256 -> 40 (+bias).
// ---------------------------------------------------------------------------
__global__ __launch_bounds__(256) void k_head23(const float* __restrict__ h1g,
                                                const float* __restrict__ wl2,
                                                const float* __restrict__ bl2,
                                                const float* __restrict__ g7,
                                                const float* __restrict__ b7,
                                                const float* __restrict__ wl3,
                                                const float* __restrict__ bl3,
                                                float* __restrict__ out) {
  const int b = blockIdx.x;
  const int tid = threadIdx.x;
  __shared__ float h1[512];
  __shared__ float h2[256];

  for (int i = tid; i < 512; i += 256) h1[i] = h1g[(size_t)b * 512 + i];
  __syncthreads();

  {
    float a = 0.f;
    for (int c = 0; c < 512; c++) a += h1[c] * wl2[(size_t)c * 256 + tid];
    a = (a + bl2[tid]) * g7[tid] + b7[tid];
    h2[tid] = (a >= 0.f) ? a : 0.2f * a;
  }
  __syncthreads();

  if (tid < 40) {
    float a = bl3[tid];
    for (int c = 0; c < 256; c++) a += h2[c] * wl3[(size_t)c * 40 + tid];
    out[(size_t)b * 40 + tid] = a;
  }
}

// ---------------------------------------------------------------------------
extern "C" void kernel_launch(void* const* d_in, const int* in_sizes, int n_in,
                              void* d_out, int out_size, void* d_ws, size_t ws_size,
                              hipStream_t stream) {
  (void)in_sizes; (void)n_in; (void)out_size;
  const float* x   = (const float*)d_in[0];
  const float* w1  = (const float*)d_in[1];
  const float* g1  = (const float*)d_in[2];
  const float* b1  = (const float*)d_in[3];
  const float* w2  = (const float*)d_in[4];
  const float* g2  = (const float*)d_in[5];
  const float* b2  = (const float*)d_in[6];
  const float* w3  = (const float*)d_in[7];
  const float* g3  = (const float*)d_in[8];
  const float* b3  = (const float*)d_in[9];
  const float* w4  = (const float*)d_in[10];
  const float* g4  = (const float*)d_in[11];
  const float* b4  = (const float*)d_in[12];
  const float* w5  = (const float*)d_in[13];
  const float* g5  = (const float*)d_in[14];
  const float* b5  = (const float*)d_in[15];
  const float* wl1 = (const float*)d_in[16];
  const float* g6  = (const float*)d_in[17];
  const float* b6  = (const float*)d_in[18];
  const float* wl2 = (const float*)d_in[19];
  const float* bl2 = (const float*)d_in[20];
  const float* g7  = (const float*)d_in[21];
  const float* b7  = (const float*)d_in[22];
  const float* wl3 = (const float*)d_in[23];
  const float* bl3 = (const float*)d_in[24];

  float* ws = (float*)d_ws;
  size_t off = 0;
  float* h0 = ws + off;   off += (size_t)NBATCH * NPTS * 3;
  float* x1 = ws + off;   off += (size_t)NBATCH * NPTS * 64;
  float* x2 = ws + off;   off += (size_t)NBATCH * NPTS * 64;
  float* x3 = ws + off;   off += (size_t)NBATCH * NPTS * 128;
  float* x4 = ws + off;   off += (size_t)NBATCH * NPTS * 256;
  int* knn = (int*)(ws + off); off += (size_t)NBATCH * NPTS * KNN;
  float* pmax = ws + off; off += (size_t)(NPTS / 128) * NBATCH * 1024;
  float* psum = ws + off; off += (size_t)(NPTS / 128) * NBATCH * 1024;
  float* pooled = ws + off; off += (size_t)NBATCH * 2048;
  float* h1g = ws + off;  off += (size_t)NBATCH * 512;
  float* t0buf = ws + off;  off += (size_t)NBATCH * NPTS * 256;  // max O
  unsigned short* w2h = (unsigned short*)(ws + off); off += 64 * 64 / 2 * 2;
  unsigned short* w2l = w2h + 64 * 64;
  unsigned short* w3h = (unsigned short*)(ws + off); off += 64 * 128 / 2 * 2;
  unsigned short* w3l = w3h + 64 * 128;
  unsigned short* w4h = (unsigned short*)(ws + off); off += 128 * 256 / 2 * 2;
  unsigned short* w4l = w4h + 128 * 256;
  unsigned short* w5h = (unsigned short*)(ws + off); off += 512 * 1024 / 2 * 2;
  unsigned short* w5l = w5h + 512 * 1024;
  unsigned short* a5h = (unsigned short*)(ws + off); off += (size_t)16384 * 512 / 2 * 2;
  unsigned short* a5l = a5h + (size_t)16384 * 512;
  float* dist = ws + off;  // adaptive: nb_grp * NPTS * NPTS floats, placed last

  size_t avail = ws_size / 4 - off;
  int nb_grp = 8;
  while (nb_grp > 1 && (size_t)nb_grp * NPTS * NPTS > avail) nb_grp >>= 1;

  constexpr int NTRI = (NPTS / 64) * (NPTS / 64 + 1) / 2;  // 528

  k_transpose<<<(NBATCH * NPTS * 3 + 255) / 256, 256, 0, stream>>>(x, h0);

  // weight hi/lo fragment prep (depends only on inputs -- run up front)
  k_wprep<64, 64><<<(64 * 64 + 255) / 256, 256, 0, stream>>>(w2, w2h, w2l);
  k_wprep<64, 128><<<(64 * 128 + 255) / 256, 256, 0, stream>>>(w3, w3h, w3l);
  k_wprep<128, 256><<<(128 * 256 + 255) / 256, 256, 0, stream>>>(w4, w4h, w4l);
  k_wprep<512, 1024><<<(512 * 1024 + 255) / 256, 256, 0, stream>>>(w5, w5h, w5l);

  // ---- edge conv 1 (C=3 -> O=64): fused register kNN (wave/row) + fp32 edge
  k_knn3<<<dim3(NPTS / 4, NBATCH), 256, 0, stream>>>(h0, knn);
  k_edge<3, 64><<<NBATCH * NPTS / 4, 256, 0, stream>>>(h0, knn, w1, g1, b1, x1);

  // ---- edge conv 2 (C=64 -> O=64)
  for (int b0 = 0; b0 < NBATCH; b0 += nb_grp) {
    k_dist<64><<<dim3(NTRI, 1, nb_grp), 256, 0, stream>>>(
        x1 + (size_t)b0 * NPTS * 64, dist);
    k_topk<<<dim3(NPTS / 4, nb_grp), 256, 0, stream>>>(dist,
                                                       knn + (size_t)b0 * NPTS * KNN);
  }
  k_t0<64, 64><<<dim3(NBATCH * NPTS / 128, 1), 256, 0, stream>>>(x1, w2, t0buf);
  k_edge_mfma<64, 64><<<NBATCH * NPTS / 2, 256, 0, stream>>>(x1, knn, w2h, w2l, t0buf,
                                                             g2, b2, x2);

  // ---- edge conv 3 (C=64 -> O=128)
  for (int b0 = 0; b0 < NBATCH; b0 += nb_grp) {
    k_dist<64><<<dim3(NTRI, 1, nb_grp), 256, 0, stream>>>(
        x2 + (size_t)b0 * NPTS * 64, dist);
    k_topk<<<dim3(NPTS / 4, nb_grp), 256, 0, stream>>>(dist,
                                                       knn + (size_t)b0 * NPTS * KNN);
  }
  k_t0<64, 128><<<dim3(NBATCH * NPTS / 128, 2), 256, 0, stream>>>(x2, w3, t0buf);
  k_edge_mfma<64, 128><<<NBATCH * NPTS / 2, 256, 0, stream>>>(x2, knn, w3h, w3l, t0buf,
                                                              g3, b3, x3);

  // ---- edge conv 4 (C=128 -> O=256)
  for (int b0 = 0; b0 < NBATCH; b0 += nb_grp) {
    k_dist<128><<<dim3(NTRI, 1, nb_grp), 256, 0, stream>>>(
        x3 + (size_t)b0 * NPTS * 128, dist);
    k_topk<<<dim3(NPTS / 4, nb_grp), 256, 0, stream>>>(dist,
                                                       knn + (size_t)b0 * NPTS * KNN);
  }
  k_t0<128, 256><<<dim3(NBATCH * NPTS / 128, 4), 256, 0, stream>>>(x3, w4, t0buf);
  k_edge_mfma<128, 256><<<NBATCH * NPTS / 2, 256, 0, stream>>>(x3, knn, w4h, w4l, t0buf,
                                                               g4, b4, x4);

  // ---- point MLP (split-bf16 MFMA GEMM) + pooling + head
  k_aprep<<<(16 * 1024 * 64 + 255) / 256, 256, 0, stream>>>(x1, x2, x3, x4, a5h, a5l);
  k_mlp5<<<dim3(NBATCH * NPTS / 128, 8), 256, 0, stream>>>(a5h, a5l, w5h, w5l, g5, b5,
                                                           pmax, psum);
  k_pool<<<(NBATCH * 1024 + 255) / 256, 256, 0, stream>>>(pmax, psum, pooled);
  k_head1<<<dim3(8, NBATCH), 256, 0, stream>>>(pooled, wl1, g6, b6, h1g);
  k_head23<<<NBATCH, 256, 0, stream>>>(h1g, wl2, bl2, g7, b7, wl3, bl3,
                                       (float*)d_out);
}

// Round 17
// 1019.355 us; speedup vs baseline: 8.5583x; 1.0475x over previous
//
#include <hip/hip_runtime.h>
#include <cstddef>
#include <cstdint>

#define NBATCH 8
#define NPTS   2048
#define KNN    20

typedef __attribute__((ext_vector_type(8))) short short8;
typedef __attribute__((ext_vector_type(4))) float f32x4;

__device__ __forceinline__ unsigned short f2bf(float f) {
  unsigned u = __float_as_uint(f);
  u += 0x7fff + ((u >> 16) & 1);   // round-to-nearest-even
  return (unsigned short)(u >> 16);
}
__device__ __forceinline__ float bf2f(unsigned short h) {
  return __uint_as_float(((unsigned)h) << 16);
}

// ---------------------------------------------------------------------------
// wave-level exact top-20 over 2048 candidates: lane holds 32 values,
// global index of v[slot] on lane l is slot*64 + l. One wave per row.
// Per-lane TOP-2 CACHE with lazy refill (R15). Tie-break: lowest index.
// ---------------------------------------------------------------------------
__device__ __forceinline__ void wave_top20(float (&v)[32], int lane,
                                           int* __restrict__ row_out) {
  float m1 = -3.0e38f, m2 = -3.0e38f;
  int i1 = 0, i2 = 0;
#pragma unroll
  for (int i = 0; i < 32; i++) {
    float x = v[i];
    if (x > m1) { m2 = m1; i2 = i1; m1 = x; i1 = i; }
    else if (x > m2) { m2 = x; i2 = i; }
  }

  unsigned dm = 0;
  int cnt = 2;
  int keep = 0;
  for (int k = 0; k < KNN; k++) {
    float rv = m1;
    int ri = i1 * 64 + lane;
#pragma unroll
    for (int off = 32; off > 0; off >>= 1) {
      float ov = __shfl_down(rv, off);
      int oi = __shfl_down(ri, off);
      if (ov > rv || (ov == rv && oi < ri)) { rv = ov; ri = oi; }
    }
    int wi = __shfl(ri, 0);
    if (lane == k) keep = wi;
    if ((wi & 63) == lane) {
      dm |= 1u << (wi >> 6);
      if (cnt == 2) {
        m1 = m2; i1 = i2; cnt = 1;
      } else {
        m1 = -3.0e38f; i1 = 0; m2 = -3.0e38f; i2 = 0;
#pragma unroll
        for (int i = 0; i < 32; i++)
          if (!((dm >> i) & 1)) {
            float x = v[i];
            if (x > m1) { m2 = m1; i2 = i1; m1 = x; i1 = i; }
            else if (x > m2) { m2 = x; i2 = i; }
          }
        cnt = 2;
      }
    }
  }
  if (lane < KNN) row_out[lane] = keep;
}

// ---------------------------------------------------------------------------
// transpose (B,3,N) -> (B,N,3)
// ---------------------------------------------------------------------------
__global__ void k_transpose(const float* __restrict__ x, float* __restrict__ h0) {
  int i = blockIdx.x * 256 + threadIdx.x;
  if (i >= NBATCH * NPTS * 3) return;
  int c = i % 3;
  int n = (i / 3) % NPTS;
  int b = i / (3 * NPTS);
  h0[i] = x[((size_t)b * 3 + c) * NPTS + n];
}

// ---------------------------------------------------------------------------
// pairwise "distance" pd = 2*dot - sq_n - sq_m. blockIdx.z = batch in group.
// R11-proven 64x64 tile / 4x4 microtile, upper-triangular grid (528 blocks);
// off-diagonal blocks mirror their tile via an LDS bounce (bit-identical).
// NOTE (R12/R13 lesson): no 8x8 microtile, no waves/EU pin -- both spilled.
// ---------------------------------------------------------------------------
template <int C>
__global__ __launch_bounds__(256) void k_dist(const float* __restrict__ xg,
                                              float* __restrict__ dist) {
  constexpr int PAD = 4;
  constexpr int S = C + PAD;
  constexpr int TS = 67;
  __shared__ __attribute__((aligned(16))) float rows[64 * S];
  __shared__ __attribute__((aligned(16))) float cols[64 * S];
  __shared__ float sq[128];

  const float* xb = xg + (size_t)blockIdx.z * NPTS * C;
  float* db = dist + (size_t)blockIdx.z * NPTS * NPTS;

  constexpr int T = NPTS / 64;
  int bid = blockIdx.x;
  int rt = 0;
  while (bid >= T - rt) { bid -= T - rt; rt++; }
  const int ct = rt + bid;

  const int tid = threadIdx.x;

  for (int e = tid; e < 64 * C; e += 256) {
    int i = e / C, c = e - i * C;
    rows[i * S + c] = xb[(size_t)(rt * 64 + i) * C + c];
    cols[i * S + c] = xb[(size_t)(ct * 64 + i) * C + c];
  }
  __syncthreads();
  if (tid < 128) {
    const float* p = (tid < 64) ? (rows + tid * S) : (cols + (tid - 64) * S);
    float s = 0.f;
    for (int c = 0; c < C; c++) s += p[c] * p[c];
    sq[tid] = s;
  }
  __syncthreads();

  const int r0 = (tid >> 4) * 4;
  const int c0 = tid & 15;
  float acc[4][4] = {};

  for (int c = 0; c < C; c += 4) {
    float4 ra[4], cb[4];
#pragma unroll
    for (int i = 0; i < 4; i++) ra[i] = *(const float4*)&rows[(r0 + i) * S + c];
#pragma unroll
    for (int j = 0; j < 4; j++) cb[j] = *(const float4*)&cols[(c0 + 16 * j) * S + c];
#pragma unroll
    for (int i = 0; i < 4; i++)
#pragma unroll
      for (int j = 0; j < 4; j++)
        acc[i][j] += ra[i].x * cb[j].x + ra[i].y * cb[j].y +
                     ra[i].z * cb[j].z + ra[i].w * cb[j].w;
  }

  float pd[4][4];
#pragma unroll
  for (int i = 0; i < 4; i++) {
    float sr = sq[r0 + i];
#pragma unroll
    for (int j = 0; j < 4; j++)
      pd[i][j] = 2.f * acc[i][j] - sr - sq[64 + c0 + 16 * j];
  }

#pragma unroll
  for (int i = 0; i < 4; i++)
#pragma unroll
    for (int j = 0; j < 4; j++)
      db[(size_t)(rt * 64 + r0 + i) * NPTS + ct * 64 + c0 + 16 * j] = pd[i][j];

  if (rt != ct) {
    __syncthreads();
    float* tb = rows;
#pragma unroll
    for (int i = 0; i < 4; i++)
#pragma unroll
      for (int j = 0; j < 4; j++)
        tb[(c0 + 16 * j) * TS + r0 + i] = pd[i][j];
    __syncthreads();
#pragma unroll
    for (int i = 0; i < 4; i++)
#pragma unroll
      for (int j = 0; j < 4; j++)
        db[(size_t)(ct * 64 + r0 + i) * NPTS + rt * 64 + c0 + 16 * j] =
            tb[(r0 + i) * TS + c0 + 16 * j];
  }
}

// ---------------------------------------------------------------------------
// top-20 per row from materialized dist. One wave per row, 4 rows per block.
// ---------------------------------------------------------------------------
__global__ __launch_bounds__(256) void k_topk(const float* __restrict__ dist,
                                              int* __restrict__ idx_out) {
  const int wid = threadIdx.x >> 6;
  const int lane = threadIdx.x & 63;
  const int n = blockIdx.x * 4 + wid;
  const int z = blockIdx.y;
  const float* drow = dist + ((size_t)z * NPTS + n) * NPTS;
  int* row_out = idx_out + ((size_t)z * NPTS + n) * KNN;

  float v[32];
#pragma unroll
  for (int i = 0; i < 32; i++) v[i] = drow[i * 64 + lane];

  wave_top20(v, lane, row_out);
}

// ---------------------------------------------------------------------------
// conv1 fused kNN (C=3): one wave per row, register recompute + wave_top20.
// ---------------------------------------------------------------------------
__global__ __launch_bounds__(256) void k_knn3(const float* __restrict__ x,
                                              int* __restrict__ idx_out) {
  const int wid = threadIdx.x >> 6;
  const int lane = threadIdx.x & 63;
  const int n = blockIdx.x * 4 + wid;
  const int b = blockIdx.y;
  const float* xb = x + (size_t)b * NPTS * 3;
  int* row_out = idx_out + ((size_t)b * NPTS + n) * KNN;

  const float qx = xb[n * 3 + 0], qy = xb[n * 3 + 1], qz = xb[n * 3 + 2];
  float qsq = 0.f;
  qsq += qx * qx; qsq += qy * qy; qsq += qz * qz;

  float v[32];
#pragma unroll
  for (int i = 0; i < 32; i++) {
    int m = i * 64 + lane;
    float cx = xb[m * 3 + 0], cy = xb[m * 3 + 1], cz = xb[m * 3 + 2];
    float csq = 0.f;
    csq += cx * cx; csq += cy * cy; csq += cz * cz;
    float acc = 0.f;
    acc += qx * cx; acc += qy * cy; acc += qz * cz;
    v[i] = 2.f * acc - qsq - csq;
  }

  wave_top20(v, lane, row_out);
}

// ---------------------------------------------------------------------------
// t0 GEMM: t0buf[n, o] = sum_c x[n, c] * w[C+c, o]   (center @ w_hi)
// ---------------------------------------------------------------------------
template <int C, int O>
__global__ __launch_bounds__(256) void k_t0(const float* __restrict__ x,
                                            const float* __restrict__ w,
                                            float* __restrict__ t0buf) {
  constexpr int TM = 128, TN = 64, TK = 16;
  __shared__ __attribute__((aligned(16))) float As[TK][TM + 4];
  __shared__ __attribute__((aligned(16))) float Bs[TK][TN + 4];
  const int mt = blockIdx.x, nt = blockIdx.y;
  const int tid = threadIdx.x;
  const int tx = tid & 15, ty = tid >> 4;
  const size_t m0 = (size_t)mt * TM;
  const int n0 = nt * TN;
  float acc[8][4] = {};

  for (int kt = 0; kt < C; kt += TK) {
#pragma unroll
    for (int e = 0; e < 8; e++) {
      int idx = tid + e * 256;
      int m = idx >> 4, k = idx & 15;
      As[k][m] = x[(m0 + m) * C + kt + k];
    }
#pragma unroll
    for (int e = 0; e < 4; e++) {
      int idx = tid + e * 256;
      int k = idx >> 6, nn = idx & 63;
      Bs[k][nn] = w[(size_t)(C + kt + k) * O + n0 + nn];
    }
    __syncthreads();
#pragma unroll
    for (int kk = 0; kk < TK; kk++) {
      float4 a0 = *(const float4*)&As[kk][ty * 8];
      float4 a1 = *(const float4*)&As[kk][ty * 8 + 4];
      float4 b0 = *(const float4*)&Bs[kk][tx * 4];
      float av[8] = {a0.x, a0.y, a0.z, a0.w, a1.x, a1.y, a1.z, a1.w};
      float bb[4] = {b0.x, b0.y, b0.z, b0.w};
#pragma unroll
      for (int i = 0; i < 8; i++)
#pragma unroll
        for (int j = 0; j < 4; j++) acc[i][j] += av[i] * bb[j];
    }
    __syncthreads();
  }
#pragma unroll
  for (int i = 0; i < 8; i++)
#pragma unroll
    for (int j = 0; j < 4; j++)
      t0buf[(m0 + ty * 8 + i) * O + n0 + tx * 4 + j] = acc[i][j];
}

// ---------------------------------------------------------------------------
// weight -> bf16 hi/lo split in 16x16x32 B-fragment order.
// ---------------------------------------------------------------------------
template <int C, int O>
__global__ void k_wprep(const float* __restrict__ w,
                        unsigned short* __restrict__ whi,
                        unsigned short* __restrict__ wlo) {
  int e = blockIdx.x * 256 + threadIdx.x;
  if (e >= C * O) return;
  constexpr int NT = O / 16;
  int j = e & 7;
  int slot = e >> 3;
  int lane = slot & 63;
  int t2 = slot >> 6;
  int nt = t2 % NT, kb = t2 / NT;
  int k = kb * 32 + ((lane >> 4) & 3) * 8 + j;
  int n = nt * 16 + (lane & 15);
  float v = w[(size_t)k * O + n];
  unsigned short h = f2bf(v);
  unsigned short l = f2bf(v - bf2f(h));
  whi[e] = h;
  wlo[e] = l;
}

// ---------------------------------------------------------------------------
// feature matrix -> bf16 hi/lo split in 16x16x32 A-fragment order for mlp5.
// ---------------------------------------------------------------------------
__global__ void k_aprep(const float* __restrict__ x1, const float* __restrict__ x2,
                        const float* __restrict__ x3, const float* __restrict__ x4,
                        unsigned short* __restrict__ ah, unsigned short* __restrict__ al) {
  int e8 = blockIdx.x * 256 + threadIdx.x;
  if (e8 >= 16 * 1024 * 64) return;
  int lane = e8 & 63;
  int mtg = (e8 >> 6) & 1023;
  int kb = e8 >> 16;
  int m = mtg * 16 + (lane & 15);
  int k0 = kb * 32 + ((lane >> 4) & 3) * 8;
  const float* p;
  if (k0 < 64)       p = &x1[(size_t)m * 64 + k0];
  else if (k0 < 128) p = &x2[(size_t)m * 64 + (k0 - 64)];
  else if (k0 < 256) p = &x3[(size_t)m * 128 + (k0 - 128)];
  else               p = &x4[(size_t)m * 256 + (k0 - 256)];
  float4 f0 = *(const float4*)p;
  float4 f1 = *(const float4*)(p + 4);
  float fv[8] = {f0.x, f0.y, f0.z, f0.w, f1.x, f1.y, f1.z, f1.w};
  short8 h8, l8;
#pragma unroll
  for (int j = 0; j < 8; j++) {
    unsigned short h = f2bf(fv[j]);
    unsigned short l = f2bf(fv[j] - bf2f(h));
    h8[j] = (short)h;
    l8[j] = (short)l;
  }
  *(short8*)&ah[(size_t)e8 * 8] = h8;
  *(short8*)&al[(size_t)e8 * 8] = l8;
}

// ---------------------------------------------------------------------------
// MFMA edge conv (C in {64,128}): per block 2 points, 32 padded neighbor rows.
// Split bf16: D ~= AhBh + AhBl + AlBh.
// R16: staging restructured into flat phases (all indices -> all gathers ->
// convert/store). Pad rows gather the CENTER point: d = ctr - ctr = 0.0
// exactly (bit-identical to the old zero-fill) -> no branch, and all 16
// gathers sit in flight instead of serializing at 68 VGPRs.
// ---------------------------------------------------------------------------
template <int C, int O>
__global__ __launch_bounds__(256) void k_edge_mfma(
    const float* __restrict__ x, const int* __restrict__ knn,
    const unsigned short* __restrict__ whi, const unsigned short* __restrict__ wlo,
    const float* __restrict__ t0buf, const float* __restrict__ g,
    const float* __restrict__ bta, float* __restrict__ out) {
  constexpr int KB = C / 32;
  constexpr int NT = O / 16;
  constexpr int NTW = NT / 2;
  __shared__ unsigned short Ah[2 * 2 * KB * 512];
  __shared__ unsigned short Al[2 * 2 * KB * 512];

  const int blk = blockIdx.x;
  const int b = blk / (NPTS / 2);
  const int n0 = (blk % (NPTS / 2)) * 2;
  const int tid = threadIdx.x;
  const int lane = tid & 63;
  const int wid = tid >> 6;
  const int pt = wid >> 1;
  const int nsl = wid & 1;
  const int ptg = b * NPTS + n0 + pt;
  const float* xb = x + (size_t)b * NPTS * C;
  const int kbase = ptg * KNN;

  // phase 1: all neighbor indices (pad rows -> center; diff is exactly 0)
  int midx[16];
#pragma unroll
  for (int i = 0; i < 16; i++) {
    int r = 2 * i + nsl;
    midx[i] = (r < KNN) ? knn[kbase + r] : (n0 + pt);
  }

  if constexpr (C == 128) {
    const float2 ctr2 = *(const float2*)&xb[(size_t)(n0 + pt) * C + lane * 2];
    const int kb = lane >> 4;
    const int q = (lane >> 2) & 3;
    const int j2 = 2 * (lane & 3);
    // phase 2: all gathers in flight
    float2 vv[16];
#pragma unroll
    for (int i = 0; i < 16; i++)
      vv[i] = *(const float2*)&xb[(size_t)midx[i] * C + lane * 2];
    // phase 3: convert + swizzled LDS store
#pragma unroll
    for (int i = 0; i < 16; i++) {
      int r = 2 * i + nsl;
      float d0 = vv[i].x - ctr2.x, d1 = vv[i].y - ctr2.y;
      unsigned short h0 = f2bf(d0), h1 = f2bf(d1);
      unsigned short l0 = f2bf(d0 - bf2f(h0)), l1 = f2bf(d1 - bf2f(h1));
      unsigned hp = (unsigned)h0 | ((unsigned)h1 << 16);
      unsigned lp = (unsigned)l0 | ((unsigned)l1 << 16);
      int mt = r >> 4, row = r & 15;
      int L = row + 16 * q;
      int phys = L ^ ((4 * kb + q) & 15);
      int idx = ((pt * 2 + mt) * KB + kb) * 512 + phys * 8 + j2;
      *(unsigned*)&Ah[idx] = hp;
      *(unsigned*)&Al[idx] = lp;
    }
  } else {  // C == 64
    const float ctrv = xb[(size_t)(n0 + pt) * C + lane];
    const int kb = lane >> 5;
    const int q = (lane >> 3) & 3;
    const int j = lane & 7;
    float vv[16];
#pragma unroll
    for (int i = 0; i < 16; i++)
      vv[i] = xb[(size_t)midx[i] * C + lane];
#pragma unroll
    for (int i = 0; i < 16; i++) {
      int r = 2 * i + nsl;
      float d = vv[i] - ctrv;
      unsigned short h = f2bf(d);
      unsigned short l = f2bf(d - bf2f(h));
      int mt = r >> 4, row = r & 15;
      int L = row + 16 * q;
      int phys = L ^ ((4 * kb + q) & 15);
      int idx = ((pt * 2 + mt) * KB + kb) * 512 + phys * 8 + j;
      Ah[idx] = h;
      Al[idx] = l;
    }
  }
  __syncthreads();

  f32x4 acc[2][NTW];
#pragma unroll
  for (int mt = 0; mt < 2; mt++)
#pragma unroll
    for (int t = 0; t < NTW; t++) acc[mt][t] = (f32x4){0.f, 0.f, 0.f, 0.f};

#pragma unroll
  for (int kb = 0; kb < KB; kb++) {
    int phys = lane ^ ((4 * kb + (lane >> 4)) & 15);
    short8 ah[2], al[2];
#pragma unroll
    for (int mt = 0; mt < 2; mt++) {
      int idx = ((pt * 2 + mt) * KB + kb) * 512 + phys * 8;
      ah[mt] = *(const short8*)&Ah[idx];
      al[mt] = *(const short8*)&Al[idx];
    }
#pragma unroll
    for (int t = 0; t < NTW; t++) {
      int nt = nsl * NTW + t;
      size_t widx = ((size_t)(kb * NT + nt) * 64 + lane) * 8;
      short8 bh = *(const short8*)&whi[widx];
      short8 bl = *(const short8*)&wlo[widx];
#pragma unroll
      for (int mt = 0; mt < 2; mt++) {
        acc[mt][t] = __builtin_amdgcn_mfma_f32_16x16x32_bf16(ah[mt], bh, acc[mt][t], 0, 0, 0);
        acc[mt][t] = __builtin_amdgcn_mfma_f32_16x16x32_bf16(ah[mt], bl, acc[mt][t], 0, 0, 0);
        acc[mt][t] = __builtin_amdgcn_mfma_f32_16x16x32_bf16(al[mt], bh, acc[mt][t], 0, 0, 0);
      }
    }
  }

#pragma unroll
  for (int t = 0; t < NTW; t++) {
    int o = (nsl * NTW + t) * 16 + (lane & 15);
    float tv = t0buf[(size_t)ptg * O + o];
    float gv = g[o], bv = bta[o];
    float m = -3.0e38f;
#pragma unroll
    for (int mt = 0; mt < 2; mt++)
#pragma unroll
      for (int r = 0; r < 4; r++) {
        float h = (acc[mt][t][r] + tv) * gv + bv;
        h = (h >= 0.f) ? h : 0.2f * h;
        m = fmaxf(m, h);
      }
    m = fmaxf(m, __shfl_xor(m, 16));
    m = fmaxf(m, __shfl_xor(m, 32));
    if (lane < 16) out[(size_t)ptg * O + o] = m;
  }
}

// ---------------------------------------------------------------------------
// fp32 edge conv -- retained for conv1 (C=3) only.
// ---------------------------------------------------------------------------
template <int C, int O>
__global__ __launch_bounds__(256) void k_edge(const float* __restrict__ x,
                                              const int* __restrict__ knn,
                                              const float* __restrict__ w,
                                              const float* __restrict__ g,
                                              const float* __restrict__ bta,
                                              float* __restrict__ out) {
  constexpr int JO = O / 64;
  constexpr int NPB = 4;
  __shared__ __attribute__((aligned(16))) float nbd[NPB * KNN * C];

  const int blk = blockIdx.x;
  const int b = blk / (NPTS / NPB);
  const int n0 = (blk % (NPTS / NPB)) * NPB;
  const int tid = threadIdx.x;
  const int lane = tid & 63;
  const int p = tid >> 6;
  const float* xb = x + (size_t)b * NPTS * C;

  const int kbase = (b * NPTS + n0 + p) * KNN;
  float* nb_p = nbd + p * KNN * C;
  int midx[KNN];
#pragma unroll
  for (int k = 0; k < KNN; k++) midx[k] = knn[kbase + k];

  float cv0 = 0.f;
  if (lane < C) cv0 = xb[(size_t)(n0 + p) * C + lane];
  float vv[KNN];
#pragma unroll
  for (int k = 0; k < KNN; k++)
    vv[k] = (lane < C) ? xb[(size_t)midx[k] * C + lane] : 0.f;
#pragma unroll
  for (int k = 0; k < KNN; k++)
    if (lane < C) nb_p[k * C + lane] = vv[k] - cv0;

  float acc[KNN][JO];
  {
    float t0[JO];
#pragma unroll
    for (int j = 0; j < JO; j++) t0[j] = 0.f;
    for (int c = 0; c < C; c++) {
      float cc = __shfl(cv0, c);
#pragma unroll
      for (int j = 0; j < JO; j++)
        t0[j] += cc * w[(size_t)(C + c) * O + j * 64 + lane];
    }
#pragma unroll
    for (int k = 0; k < KNN; k++)
#pragma unroll
      for (int j = 0; j < JO; j++) acc[k][j] = t0[j];
  }

  for (int c = 0; c < C; c++) {
    float wv[JO];
#pragma unroll
    for (int j = 0; j < JO; j++) wv[j] = w[(size_t)c * O + j * 64 + lane];
#pragma unroll
    for (int k = 0; k < KNN; k++) {
      float f = nb_p[k * C + c];
#pragma unroll
      for (int j = 0; j < JO; j++) acc[k][j] += f * wv[j];
    }
  }

#pragma unroll
  for (int j = 0; j < JO; j++) {
    const float gv = g[j * 64 + lane], bv = bta[j * 64 + lane];
    float mx = -3.0e38f;
#pragma unroll
    for (int k = 0; k < KNN; k++) {
      float h = acc[k][j] * gv + bv;
      h = (h >= 0.f) ? h : 0.2f * h;
      mx = fmaxf(mx, h);
    }
    out[(size_t)(b * NPTS + n0 + p) * O + j * 64 + lane] = mx;
  }
}

// ---------------------------------------------------------------------------
// point MLP 512->1024 as split-bf16 MFMA GEMM, no LDS, no barriers.
// ---------------------------------------------------------------------------
__global__ __launch_bounds__(256) void k_mlp5(const unsigned short* __restrict__ a5h,
                                              const unsigned short* __restrict__ a5l,
                                              const unsigned short* __restrict__ w5h,
                                              const unsigned short* __restrict__ w5l,
                                              const float* __restrict__ g5,
                                              const float* __restrict__ b5,
                                              float* __restrict__ pmax,
                                              float* __restrict__ psum) {
  const int mtb = blockIdx.x;
  const int ntb = blockIdx.y;
  const int tid = threadIdx.x;
  const int lane = tid & 63;
  const int nsl = tid >> 6;

  f32x4 acc[8][2];
#pragma unroll
  for (int mt = 0; mt < 8; mt++)
#pragma unroll
    for (int t = 0; t < 2; t++) acc[mt][t] = (f32x4){0.f, 0.f, 0.f, 0.f};

  for (int kb = 0; kb < 16; kb++) {
    short8 bh[2], bl[2];
#pragma unroll
    for (int t = 0; t < 2; t++) {
      int ntg = ntb * 8 + nsl * 2 + t;
      size_t widx = ((size_t)(kb * 64 + ntg) * 64 + lane) * 8;
      bh[t] = *(const short8*)&w5h[widx];
      bl[t] = *(const short8*)&w5l[widx];
    }
#pragma unroll
    for (int mt = 0; mt < 8; mt++) {
      size_t aidx = (((size_t)kb * 1024 + mtb * 8 + mt) * 64 + lane) * 8;
      short8 ah = *(const short8*)&a5h[aidx];
      short8 al = *(const short8*)&a5l[aidx];
#pragma unroll
      for (int t = 0; t < 2; t++) {
        acc[mt][t] = __builtin_amdgcn_mfma_f32_16x16x32_bf16(ah, bh[t], acc[mt][t], 0, 0, 0);
        acc[mt][t] = __builtin_amdgcn_mfma_f32_16x16x32_bf16(ah, bl[t], acc[mt][t], 0, 0, 0);
        acc[mt][t] = __builtin_amdgcn_mfma_f32_16x16x32_bf16(al, bh[t], acc[mt][t], 0, 0, 0);
      }
    }
  }

#pragma unroll
  for (int t = 0; t < 2; t++) {
    int o = ntb * 128 + (nsl * 2 + t) * 16 + (lane & 15);
    float gv = g5[o], bv = b5[o];
    float mx = -3.0e38f, sm = 0.f;
#pragma unroll
    for (int mt = 0; mt < 8; mt++)
#pragma unroll
      for (int r = 0; r < 4; r++) {
        float h = acc[mt][t][r] * gv + bv;
        h = (h >= 0.f) ? h : 0.2f * h;
        mx = fmaxf(mx, h);
        sm += h;
      }
    mx = fmaxf(mx, __shfl_xor(mx, 16));
    mx = fmaxf(mx, __shfl_xor(mx, 32));
    sm += __shfl_xor(sm, 16);
    sm += __shfl_xor(sm, 32);
    if (lane < 16) {
      pmax[(size_t)mtb * 1024 + o] = mx;
      psum[(size_t)mtb * 1024 + o] = sm;
    }
  }
}

// ---------------------------------------------------------------------------
// reduce tile partials -> pooled (B, 2048) = [max(1024), mean(1024)]
// ---------------------------------------------------------------------------
__global__ void k_pool(const float* __restrict__ pmax, const float* __restrict__ psum,
                       float* __restrict__ pooled) {
  int i = blockIdx.x * 256 + threadIdx.x;
  if (i >= NBATCH * 1024) return;
  int b = i / 1024, e = i - b * 1024;
  constexpr int NT = NPTS / 128;
  float mx = -3.0e38f, sm = 0.f;
  for (int t = 0; t < NT; t++) {
    mx = fmaxf(mx, pmax[((size_t)b * NT + t) * 1024 + e]);
    sm += psum[((size_t)b * NT + t) * 1024 + e];
  }
  pooled[(size_t)b * 2048 + e] = mx;
  pooled[(size_t)b * 2048 + 1024 + e] = sm * (1.0f / NPTS);
}

// ---------------------------------------------------------------------------
// head layer 1: h1g[b,o] = leaky((pooled[b,:] @ wl1)[o] * g6[o] + b6[o]).
// grid (8 o-chunks, NBATCH); wave ks covers k-slice [ks*512,(ks+1)*512).
// ---------------------------------------------------------------------------
__global__ __launch_bounds__(256) void k_head1(const float* __restrict__ pooled,
                                               const float* __restrict__ wl1,
                                               const float* __restrict__ g6,
                                               const float* __restrict__ b6,
                                               float* __restrict__ h1g) {
  const int os = blockIdx.x;
  const int b = blockIdx.y;
  const int tid = threadIdx.x;
  const int lane = tid & 63;
  const int ks = tid >> 6;
  const int o = os * 64 + lane;
  __shared__ float pl[2048];
  __shared__ float part[4][64];

  for (int i = tid; i < 2048; i += 256) pl[i] = pooled[(size_t)b * 2048 + i];
  __syncthreads();

  float a = 0.f;
  const int c0 = ks * 512;
  for (int c = 0; c < 512; c++)
    a += pl[c0 + c] * wl1[(size_t)(c0 + c) * 512 + o];
  part[ks][lane] = a;
  __syncthreads();

  if (ks == 0) {
    float s = part[0][lane];
    s += part[1][lane];
    s += part[2][lane];
    s += part[3][lane];
    s = s * g6[o] + b6[o];
    h1g[(size_t)b * 512 + o] = (s >= 0.f) ? s : 0.2f * s;
  }
}

// ---------------------------------------------------------------------------
// head layers 2+3: 512 ->(bias,affine,leaky) 256 -> 40 (+bias).
// ---------------------------------------------------------------------------
__global__ __launch_bounds__(256) void k_head23(const float* __restrict__ h1g,
                                                const float* __restrict__ wl2,
                                                const float* __restrict__ bl2,
                                                const float* __restrict__ g7,
                                                const float* __restrict__ b7,
                                                const float* __restrict__ wl3,
                                                const float* __restrict__ bl3,
                                                float* __restrict__ out) {
  const int b = blockIdx.x;
  const int tid = threadIdx.x;
  __shared__ float h1[512];
  __shared__ float h2[256];

  for (int i = tid; i < 512; i += 256) h1[i] = h1g[(size_t)b * 512 + i];
  __syncthreads();

  {
    float a = 0.f;
    for (int c = 0; c < 512; c++) a += h1[c] * wl2[(size_t)c * 256 + tid];
    a = (a + bl2[tid]) * g7[tid] + b7[tid];
    h2[tid] = (a >= 0.f) ? a : 0.2f * a;
  }
  __syncthreads();

  if (tid < 40) {
    float a = bl3[tid];
    for (int c = 0; c < 256; c++) a += h2[c] * wl3[(size_t)c * 40 + tid];
    out[(size_t)b * 40 + tid] = a;
  }
}

// ---------------------------------------------------------------------------
extern "C" void kernel_launch(void* const* d_in, const int* in_sizes, int n_in,
                              void* d_out, int out_size, void* d_ws, size_t ws_size,
                              hipStream_t stream) {
  (void)in_sizes; (void)n_in; (void)out_size;
  const float* x   = (const float*)d_in[0];
  const float* w1  = (const float*)d_in[1];
  const float* g1  = (const float*)d_in[2];
  const float* b1  = (const float*)d_in[3];
  const float* w2  = (const float*)d_in[4];
  const float* g2  = (const float*)d_in[5];
  const float* b2  = (const float*)d_in[6];
  const float* w3  = (const float*)d_in[7];
  const float* g3  = (const float*)d_in[8];
  const float* b3  = (const float*)d_in[9];
  const float* w4  = (const float*)d_in[10];
  const float* g4  = (const float*)d_in[11];
  const float* b4  = (const float*)d_in[12];
  const float* w5  = (const float*)d_in[13];
  const float* g5  = (const float*)d_in[14];
  const float* b5  = (const float*)d_in[15];
  const float* wl1 = (const float*)d_in[16];
  const float* g6  = (const float*)d_in[17];
  const float* b6  = (const float*)d_in[18];
  const float* wl2 = (const float*)d_in[19];
  const float* bl2 = (const float*)d_in[20];
  const float* g7  = (const float*)d_in[21];
  const float* b7  = (const float*)d_in[22];
  const float* wl3 = (const float*)d_in[23];
  const float* bl3 = (const float*)d_in[24];

  float* ws = (float*)d_ws;
  size_t off = 0;
  float* h0 = ws + off;   off += (size_t)NBATCH * NPTS * 3;
  float* x1 = ws + off;   off += (size_t)NBATCH * NPTS * 64;
  float* x2 = ws + off;   off += (size_t)NBATCH * NPTS * 64;
  float* x3 = ws + off;   off += (size_t)NBATCH * NPTS * 128;
  float* x4 = ws + off;   off += (size_t)NBATCH * NPTS * 256;
  int* knn = (int*)(ws + off); off += (size_t)NBATCH * NPTS * KNN;
  float* pmax = ws + off; off += (size_t)(NPTS / 128) * NBATCH * 1024;
  float* psum = ws + off; off += (size_t)(NPTS / 128) * NBATCH * 1024;
  float* pooled = ws + off; off += (size_t)NBATCH * 2048;
  float* h1g = ws + off;  off += (size_t)NBATCH * 512;
  float* t0buf = ws + off;  off += (size_t)NBATCH * NPTS * 256;  // max O
  unsigned short* w2h = (unsigned short*)(ws + off); off += 64 * 64 / 2 * 2;
  unsigned short* w2l = w2h + 64 * 64;
  unsigned short* w3h = (unsigned short*)(ws + off); off += 64 * 128 / 2 * 2;
  unsigned short* w3l = w3h + 64 * 128;
  unsigned short* w4h = (unsigned short*)(ws + off); off += 128 * 256 / 2 * 2;
  unsigned short* w4l = w4h + 128 * 256;
  unsigned short* w5h = (unsigned short*)(ws + off); off += 512 * 1024 / 2 * 2;
  unsigned short* w5l = w5h + 512 * 1024;
  unsigned short* a5h = (unsigned short*)(ws + off); off += (size_t)16384 * 512 / 2 * 2;
  unsigned short* a5l = a5h + (size_t)16384 * 512;
  float* dist = ws + off;  // adaptive: nb_grp * NPTS * NPTS floats, placed last

  size_t avail = ws_size / 4 - off;
  int nb_grp = 8;
  while (nb_grp > 1 && (size_t)nb_grp * NPTS * NPTS > avail) nb_grp >>= 1;

  constexpr int NTRI = (NPTS / 64) * (NPTS / 64 + 1) / 2;  // 528

  k_transpose<<<(NBATCH * NPTS * 3 + 255) / 256, 256, 0, stream>>>(x, h0);

  // weight hi/lo fragment prep (depends only on inputs -- run up front)
  k_wprep<64, 64><<<(64 * 64 + 255) / 256, 256, 0, stream>>>(w2, w2h, w2l);
  k_wprep<64, 128><<<(64 * 128 + 255) / 256, 256, 0, stream>>>(w3, w3h, w3l);
  k_wprep<128, 256><<<(128 * 256 + 255) / 256, 256, 0, stream>>>(w4, w4h, w4l);
  k_wprep<512, 1024><<<(512 * 1024 + 255) / 256, 256, 0, stream>>>(w5, w5h, w5l);

  // ---- edge conv 1 (C=3 -> O=64): fused register kNN (wave/row) + fp32 edge
  k_knn3<<<dim3(NPTS / 4, NBATCH), 256, 0, stream>>>(h0, knn);
  k_edge<3, 64><<<NBATCH * NPTS / 4, 256, 0, stream>>>(h0, knn, w1, g1, b1, x1);

  // ---- edge conv 2 (C=64 -> O=64)
  for (int b0 = 0; b0 < NBATCH; b0 += nb_grp) {
    k_dist<64><<<dim3(NTRI, 1, nb_grp), 256, 0, stream>>>(
        x1 + (size_t)b0 * NPTS * 64, dist);
    k_topk<<<dim3(NPTS / 4, nb_grp), 256, 0, stream>>>(dist,
                                                       knn + (size_t)b0 * NPTS * KNN);
  }
  k_t0<64, 64><<<dim3(NBATCH * NPTS / 128, 1), 256, 0, stream>>>(x1, w2, t0buf);
  k_edge_mfma<64, 64><<<NBATCH * NPTS / 2, 256, 0, stream>>>(x1, knn, w2h, w2l, t0buf,
                                                             g2, b2, x2);

  // ---- edge conv 3 (C=64 -> O=128)
  for (int b0 = 0; b0 < NBATCH; b0 += nb_grp) {
    k_dist<64><<<dim3(NTRI, 1, nb_grp), 256, 0, stream>>>(
        x2 + (size_t)b0 * NPTS * 64, dist);
    k_topk<<<dim3(NPTS / 4, nb_grp), 256, 0, stream>>>(dist,
                                                       knn + (size_t)b0 * NPTS * KNN);
  }
  k_t0<64, 128><<<dim3(NBATCH * NPTS / 128, 2), 256, 0, stream>>>(x2, w3, t0buf);
  k_edge_mfma<64, 128><<<NBATCH * NPTS / 2, 256, 0, stream>>>(x2, knn, w3h, w3l, t0buf,
                                                              g3, b3, x3);

  // ---- edge conv 4 (C=128 -> O=256)
  for (int b0 = 0; b0 < NBATCH; b0 += nb_grp) {
    k_dist<128><<<dim3(NTRI, 1, nb_grp), 256, 0, stream>>>(
        x3 + (size_t)b0 * NPTS * 128, dist);
    k_topk<<<dim3(NPTS / 4, nb_grp), 256, 0, stream>>>(dist,
                                                       knn + (size_t)b0 * NPTS * KNN);
  }
  k_t0<128, 256><<<dim3(NBATCH * NPTS / 128, 4), 256, 0, stream>>>(x3, w4, t0buf);
  k_edge_mfma<128, 256><<<NBATCH * NPTS / 2, 256, 0, stream>>>(x3, knn, w4h, w4l, t0buf,
                                                               g4, b4, x4);

  // ---- point MLP (split-bf16 MFMA GEMM) + pooling + head
  k_aprep<<<(16 * 1024 * 64 + 255) / 256, 256, 0, stream>>>(x1, x2, x3, x4, a5h, a5l);
  k_mlp5<<<dim3(NBATCH * NPTS / 128, 8), 256, 0, stream>>>(a5h, a5l, w5h, w5l, g5, b5,
                                                           pmax, psum);
  k_pool<<<(NBATCH * 1024 + 255) / 256, 256, 0, stream>>>(pmax, psum, pooled);
  k_head1<<<dim3(8, NBATCH), 256, 0, stream>>>(pooled, wl1, g6, b6, h1g);
  k_head23<<<NBATCH, 256, 0, stream>>>(h1g, wl2, bl2, g7, b7, wl3, bl3,
                                       (float*)d_out);
}